// Round 1
// baseline (4861.595 us; speedup 1.0000x reference)
//
#include <hip/hip_runtime.h>

constexpr int FN   = 64;   // node / edge / glob feature width
constexpr int HIDN = 32;   // hidden width of both MLPs
constexpr int FMSG = 64;   // message width
constexpr int FOUT = 128;  // output width

// ---------------------------------------------------------------------------
// Edge MLP + scatter(sum, count, max-as-int-bits) onto destination nodes.
// One thread per edge. Weights are read through uniform (scalar) loads.
// ---------------------------------------------------------------------------
__global__ __launch_bounds__(256) void edge_mlp_scatter(
    const float* __restrict__ x,
    const int*   __restrict__ ei,      // [2, E] flat: rows then cols
    const float* __restrict__ ea,      // [E, 64]
    const float* __restrict__ W1,      // [192, 32]
    const float* __restrict__ b1,      // [32]
    const float* __restrict__ W2,      // [32, 64]
    const float* __restrict__ b2,      // [64]
    float* __restrict__ agg_sum,       // [N, 64]
    int*   __restrict__ agg_maxb,      // [N, 64] float bits (all values >= 0)
    int*   __restrict__ cnt,           // [N]
    int E)
{
    const int e = blockIdx.x * 256 + threadIdx.x;
    if (e >= E) return;
    const int row = ei[e];
    const int col = ei[E + e];

    float h[HIDN];
#pragma unroll
    for (int j = 0; j < HIDN; ++j) h[j] = b1[j];

    const float* seg_src[3] = {
        x + (size_t)row * FN,
        x + (size_t)col * FN,
        ea + (size_t)e * FN
    };

#pragma unroll
    for (int seg = 0; seg < 3; ++seg) {
        const float* src   = seg_src[seg];
        const float* wbase = W1 + (size_t)seg * FN * HIDN;
#pragma unroll 4
        for (int k = 0; k < FN; k += 4) {
            const float4 v = *reinterpret_cast<const float4*>(src + k);
            const float* w = wbase + k * HIDN;
#pragma unroll
            for (int j = 0; j < HIDN; ++j) {
                float hj = h[j];
                hj = fmaf(v.x, w[j], hj);
                hj = fmaf(v.y, w[HIDN + j], hj);
                hj = fmaf(v.z, w[2 * HIDN + j], hj);
                hj = fmaf(v.w, w[3 * HIDN + j], hj);
                h[j] = hj;
            }
        }
    }
#pragma unroll
    for (int j = 0; j < HIDN; ++j) h[j] = fmaxf(h[j], 0.0f);

    float* sdst = agg_sum  + (size_t)col * FMSG;
    int*   mdst = agg_maxb + (size_t)col * FMSG;
#pragma unroll 8
    for (int j = 0; j < FMSG; ++j) {
        float acc = b2[j];
#pragma unroll
        for (int k = 0; k < HIDN; ++k) acc = fmaf(h[k], W2[k * FMSG + j], acc);
        acc = fmaxf(acc, 0.0f);
        unsafeAtomicAdd(sdst + j, acc);                 // native global_atomic_add_f32
        atomicMax(mdst + j, __float_as_int(acc));       // valid: acc >= 0
    }
    atomicAdd(cnt + col, 1);
}

// ---------------------------------------------------------------------------
// Node MLP: concat[x, agg_mean, agg_max, u[batch]] -> 32 -> 128, ReLU both.
// One thread per node.
// ---------------------------------------------------------------------------
__global__ __launch_bounds__(256) void node_mlp(
    const float* __restrict__ x,
    const float* __restrict__ u,       // [G, 64]
    const int*   __restrict__ batch,   // [N]
    const float* __restrict__ W3,      // [256, 32]
    const float* __restrict__ b3,      // [32]
    const float* __restrict__ W4,      // [32, 128]
    const float* __restrict__ b4,      // [128]
    const float* __restrict__ agg_sum,
    const int*   __restrict__ agg_maxb,
    const int*   __restrict__ cnt,
    float* __restrict__ out,           // [N, 128]
    int N)
{
    const int n = blockIdx.x * 256 + threadIdx.x;
    if (n >= N) return;
    const float inv = 1.0f / fmaxf((float)cnt[n], 1.0f);

    float h[HIDN];
#pragma unroll
    for (int j = 0; j < HIDN; ++j) h[j] = b3[j];

    const float* seg_src[4] = {
        x + (size_t)n * FN,
        agg_sum + (size_t)n * FMSG,                              // scaled by inv
        reinterpret_cast<const float*>(agg_maxb) + (size_t)n * FMSG,
        u + (size_t)batch[n] * FN
    };

#pragma unroll
    for (int seg = 0; seg < 4; ++seg) {
        const float* src   = seg_src[seg];
        const float  sc    = (seg == 1) ? inv : 1.0f;
        const float* wbase = W3 + (size_t)seg * FN * HIDN;
#pragma unroll 4
        for (int k = 0; k < FN; k += 4) {
            float4 v = *reinterpret_cast<const float4*>(src + k);
            v.x *= sc; v.y *= sc; v.z *= sc; v.w *= sc;
            const float* w = wbase + k * HIDN;
#pragma unroll
            for (int j = 0; j < HIDN; ++j) {
                float hj = h[j];
                hj = fmaf(v.x, w[j], hj);
                hj = fmaf(v.y, w[HIDN + j], hj);
                hj = fmaf(v.z, w[2 * HIDN + j], hj);
                hj = fmaf(v.w, w[3 * HIDN + j], hj);
                h[j] = hj;
            }
        }
    }
#pragma unroll
    for (int j = 0; j < HIDN; ++j) h[j] = fmaxf(h[j], 0.0f);

    float* o = out + (size_t)n * FOUT;
#pragma unroll 4
    for (int j = 0; j < FOUT; j += 4) {
        float4 acc = make_float4(b4[j], b4[j + 1], b4[j + 2], b4[j + 3]);
#pragma unroll
        for (int k = 0; k < HIDN; ++k) {
            const float hk = h[k];
            acc.x = fmaf(hk, W4[k * FOUT + j],     acc.x);
            acc.y = fmaf(hk, W4[k * FOUT + j + 1], acc.y);
            acc.z = fmaf(hk, W4[k * FOUT + j + 2], acc.z);
            acc.w = fmaf(hk, W4[k * FOUT + j + 3], acc.w);
        }
        acc.x = fmaxf(acc.x, 0.0f);
        acc.y = fmaxf(acc.y, 0.0f);
        acc.z = fmaxf(acc.z, 0.0f);
        acc.w = fmaxf(acc.w, 0.0f);
        *reinterpret_cast<float4*>(o + j) = acc;
    }
}

// ---------------------------------------------------------------------------
extern "C" void kernel_launch(void* const* d_in, const int* in_sizes, int n_in,
                              void* d_out, int out_size, void* d_ws, size_t ws_size,
                              hipStream_t stream)
{
    const float* x     = (const float*)d_in[0];
    const int*   ei    = (const int*)  d_in[1];
    const float* ea    = (const float*)d_in[2];
    const float* u     = (const float*)d_in[3];
    const int*   batch = (const int*)  d_in[4];
    const float* W1    = (const float*)d_in[5];
    const float* b1    = (const float*)d_in[6];
    const float* W2    = (const float*)d_in[7];
    const float* b2    = (const float*)d_in[8];
    const float* W3    = (const float*)d_in[9];
    const float* b3    = (const float*)d_in[10];
    const float* W4    = (const float*)d_in[11];
    const float* b4    = (const float*)d_in[12];
    float* out = (float*)d_out;

    const int N = in_sizes[0] / FN;   // 50000
    const int E = in_sizes[1] / 2;    // 800000

    // Workspace layout: agg_sum [N*64 f32] | agg_maxb [N*64 i32] | cnt [N i32]
    float* agg_sum  = (float*)d_ws;
    int*   agg_maxb = (int*)((char*)d_ws + (size_t)N * FMSG * 4);
    int*   cnt      = (int*)((char*)d_ws + (size_t)N * FMSG * 8);
    const size_t zero_bytes = (size_t)N * FMSG * 8 + (size_t)N * 4;
    hipMemsetAsync(d_ws, 0, zero_bytes, stream);

    edge_mlp_scatter<<<(E + 255) / 256, 256, 0, stream>>>(
        x, ei, ea, W1, b1, W2, b2, agg_sum, agg_maxb, cnt, E);
    node_mlp<<<(N + 255) / 256, 256, 0, stream>>>(
        x, u, batch, W3, b3, W4, b4, agg_sum, agg_maxb, cnt, out, N);
}

// Round 2
// 862.475 us; speedup vs baseline: 5.6368x; 5.6368x over previous
//
#include <hip/hip_runtime.h>

constexpr int FN   = 64;   // node / edge / glob feature width
constexpr int HIDN = 32;   // hidden width of both MLPs
constexpr int FMSG = 64;   // message width
constexpr int FOUT = 128;  // output width

// ===========================================================================
// Sorted (CSR) path
// ===========================================================================

__global__ __launch_bounds__(256) void hist_kernel(
    const int* __restrict__ ei, int* __restrict__ cnt, int E)
{
    const int e = blockIdx.x * 256 + threadIdx.x;
    if (e >= E) return;
    atomicAdd(cnt + ei[E + e], 1);
}

// Single-block exclusive scan: offs[0..N-1] exclusive, offs[N] = total.
__global__ __launch_bounds__(1024) void scan_kernel(
    const int* __restrict__ cnt, int* __restrict__ offs, int N)
{
    __shared__ int buf[1024];
    __shared__ int s_carry;
    if (threadIdx.x == 0) s_carry = 0;
    __syncthreads();
    for (int base = 0; base < N; base += 1024) {
        const int i = base + (int)threadIdx.x;
        const int v = (i < N) ? cnt[i] : 0;
        int acc = v;
        buf[threadIdx.x] = v;
        __syncthreads();
        for (int d = 1; d < 1024; d <<= 1) {
            const int t = (threadIdx.x >= (unsigned)d) ? buf[threadIdx.x - d] : 0;
            __syncthreads();
            acc += t;
            buf[threadIdx.x] = acc;
            __syncthreads();
        }
        const int excl = s_carry + acc - v;
        if (i < N) offs[i] = excl;
        __syncthreads();
        if (threadIdx.x == 1023) s_carry = excl + v;
        __syncthreads();
    }
    if (threadIdx.x == 0) offs[N] = s_carry;
}

__global__ __launch_bounds__(256) void scatter_kernel(
    const int* __restrict__ ei, const int* __restrict__ offs,
    int* __restrict__ cursor, int* __restrict__ perm, int E)
{
    const int e = blockIdx.x * 256 + threadIdx.x;
    if (e >= E) return;
    const int col = ei[E + e];
    const int pos = offs[col] + atomicAdd(cursor + col, 1);
    perm[pos] = e;
}

// Edge MLP in destination-sorted order; contiguous float4 message stores.
__global__ __launch_bounds__(256) void edge_mlp_sorted(
    const float* __restrict__ x,
    const int*   __restrict__ ei,
    const float* __restrict__ ea,
    const float* __restrict__ W1,   // [192, 32]
    const float* __restrict__ b1,
    const float* __restrict__ W2,   // [32, 64]
    const float* __restrict__ b2,
    const int*   __restrict__ perm,
    float* __restrict__ msg,        // [E, 64] in sorted order
    int E)
{
    const int p = blockIdx.x * 256 + threadIdx.x;
    if (p >= E) return;
    const int e   = perm[p];
    const int row = ei[e];
    const int col = ei[E + e];

    float h[HIDN];
#pragma unroll
    for (int j = 0; j < HIDN; ++j) h[j] = b1[j];

    const float* seg_src[3] = {
        x + (size_t)row * FN,
        x + (size_t)col * FN,
        ea + (size_t)e * FN
    };

#pragma unroll
    for (int seg = 0; seg < 3; ++seg) {
        const float* src   = seg_src[seg];
        const float* wbase = W1 + (size_t)seg * FN * HIDN;
#pragma unroll 4
        for (int k = 0; k < FN; k += 4) {
            const float4 v = *reinterpret_cast<const float4*>(src + k);
            const float* w = wbase + k * HIDN;
#pragma unroll
            for (int j = 0; j < HIDN; ++j) {
                float hj = h[j];
                hj = fmaf(v.x, w[j], hj);
                hj = fmaf(v.y, w[HIDN + j], hj);
                hj = fmaf(v.z, w[2 * HIDN + j], hj);
                hj = fmaf(v.w, w[3 * HIDN + j], hj);
                h[j] = hj;
            }
        }
    }
#pragma unroll
    for (int j = 0; j < HIDN; ++j) h[j] = fmaxf(h[j], 0.0f);

    float* mdst = msg + (size_t)p * FMSG;
#pragma unroll 4
    for (int j = 0; j < FMSG; j += 4) {
        float4 acc = make_float4(b2[j], b2[j + 1], b2[j + 2], b2[j + 3]);
#pragma unroll
        for (int k = 0; k < HIDN; ++k) {
            const float hk = h[k];
            acc.x = fmaf(hk, W2[k * FMSG + j],     acc.x);
            acc.y = fmaf(hk, W2[k * FMSG + j + 1], acc.y);
            acc.z = fmaf(hk, W2[k * FMSG + j + 2], acc.z);
            acc.w = fmaf(hk, W2[k * FMSG + j + 3], acc.w);
        }
        acc.x = fmaxf(acc.x, 0.0f);
        acc.y = fmaxf(acc.y, 0.0f);
        acc.z = fmaxf(acc.z, 0.0f);
        acc.w = fmaxf(acc.w, 0.0f);
        *reinterpret_cast<float4*>(mdst + j) = acc;
    }
}

// One wave per node; lane = feature. Coalesced segmented mean+max.
__global__ __launch_bounds__(256) void aggregate_kernel(
    const float* __restrict__ msg, const int* __restrict__ offs,
    float* __restrict__ agg_mean, float* __restrict__ agg_max, int N)
{
    const int n = blockIdx.x * 4 + (threadIdx.x >> 6);
    if (n >= N) return;
    const int lane = threadIdx.x & 63;
    const int s = offs[n], t = offs[n + 1];
    float sum = 0.0f, mx = 0.0f;
    int p = s;
    for (; p + 1 < t; p += 2) {
        const float v0 = msg[(size_t)p * FMSG + lane];
        const float v1 = msg[(size_t)(p + 1) * FMSG + lane];
        sum += v0 + v1;
        mx = fmaxf(mx, fmaxf(v0, v1));
    }
    if (p < t) {
        const float v0 = msg[(size_t)p * FMSG + lane];
        sum += v0;
        mx = fmaxf(mx, v0);
    }
    const float inv = (t > s) ? 1.0f / (float)(t - s) : 0.0f;
    agg_mean[(size_t)n * FMSG + lane] = sum * inv;
    agg_max [(size_t)n * FMSG + lane] = mx;   // msgs >= 0, empty -> 0
}

// Node MLP consuming pre-divided mean and float max.
__global__ __launch_bounds__(256) void node_mlp_sorted(
    const float* __restrict__ x,
    const float* __restrict__ u,
    const int*   __restrict__ batch,
    const float* __restrict__ W3,   // [256, 32]
    const float* __restrict__ b3,
    const float* __restrict__ W4,   // [32, 128]
    const float* __restrict__ b4,
    const float* __restrict__ agg_mean,
    const float* __restrict__ agg_max,
    float* __restrict__ out,
    int N)
{
    const int n = blockIdx.x * 256 + threadIdx.x;
    if (n >= N) return;

    float h[HIDN];
#pragma unroll
    for (int j = 0; j < HIDN; ++j) h[j] = b3[j];

    const float* seg_src[4] = {
        x + (size_t)n * FN,
        agg_mean + (size_t)n * FMSG,
        agg_max + (size_t)n * FMSG,
        u + (size_t)batch[n] * FN
    };

#pragma unroll
    for (int seg = 0; seg < 4; ++seg) {
        const float* src   = seg_src[seg];
        const float* wbase = W3 + (size_t)seg * FN * HIDN;
#pragma unroll 4
        for (int k = 0; k < FN; k += 4) {
            const float4 v = *reinterpret_cast<const float4*>(src + k);
            const float* w = wbase + k * HIDN;
#pragma unroll
            for (int j = 0; j < HIDN; ++j) {
                float hj = h[j];
                hj = fmaf(v.x, w[j], hj);
                hj = fmaf(v.y, w[HIDN + j], hj);
                hj = fmaf(v.z, w[2 * HIDN + j], hj);
                hj = fmaf(v.w, w[3 * HIDN + j], hj);
                h[j] = hj;
            }
        }
    }
#pragma unroll
    for (int j = 0; j < HIDN; ++j) h[j] = fmaxf(h[j], 0.0f);

    float* o = out + (size_t)n * FOUT;
#pragma unroll 4
    for (int j = 0; j < FOUT; j += 4) {
        float4 acc = make_float4(b4[j], b4[j + 1], b4[j + 2], b4[j + 3]);
#pragma unroll
        for (int k = 0; k < HIDN; ++k) {
            const float hk = h[k];
            acc.x = fmaf(hk, W4[k * FOUT + j],     acc.x);
            acc.y = fmaf(hk, W4[k * FOUT + j + 1], acc.y);
            acc.z = fmaf(hk, W4[k * FOUT + j + 2], acc.z);
            acc.w = fmaf(hk, W4[k * FOUT + j + 3], acc.w);
        }
        acc.x = fmaxf(acc.x, 0.0f);
        acc.y = fmaxf(acc.y, 0.0f);
        acc.z = fmaxf(acc.z, 0.0f);
        acc.w = fmaxf(acc.w, 0.0f);
        *reinterpret_cast<float4*>(o + j) = acc;
    }
}

// ===========================================================================
// Fallback atomic path (round-1 kernels) — used only if ws too small.
// ===========================================================================

__global__ __launch_bounds__(256) void edge_mlp_scatter(
    const float* __restrict__ x, const int* __restrict__ ei,
    const float* __restrict__ ea,
    const float* __restrict__ W1, const float* __restrict__ b1,
    const float* __restrict__ W2, const float* __restrict__ b2,
    float* __restrict__ agg_sum, int* __restrict__ agg_maxb,
    int* __restrict__ cnt, int E)
{
    const int e = blockIdx.x * 256 + threadIdx.x;
    if (e >= E) return;
    const int row = ei[e];
    const int col = ei[E + e];
    float h[HIDN];
#pragma unroll
    for (int j = 0; j < HIDN; ++j) h[j] = b1[j];
    const float* seg_src[3] = { x + (size_t)row * FN, x + (size_t)col * FN,
                                ea + (size_t)e * FN };
#pragma unroll
    for (int seg = 0; seg < 3; ++seg) {
        const float* src = seg_src[seg];
        const float* wbase = W1 + (size_t)seg * FN * HIDN;
#pragma unroll 4
        for (int k = 0; k < FN; k += 4) {
            const float4 v = *reinterpret_cast<const float4*>(src + k);
            const float* w = wbase + k * HIDN;
#pragma unroll
            for (int j = 0; j < HIDN; ++j) {
                float hj = h[j];
                hj = fmaf(v.x, w[j], hj);
                hj = fmaf(v.y, w[HIDN + j], hj);
                hj = fmaf(v.z, w[2 * HIDN + j], hj);
                hj = fmaf(v.w, w[3 * HIDN + j], hj);
                h[j] = hj;
            }
        }
    }
#pragma unroll
    for (int j = 0; j < HIDN; ++j) h[j] = fmaxf(h[j], 0.0f);
    float* sdst = agg_sum + (size_t)col * FMSG;
    int* mdst = agg_maxb + (size_t)col * FMSG;
#pragma unroll 8
    for (int j = 0; j < FMSG; ++j) {
        float acc = b2[j];
#pragma unroll
        for (int k = 0; k < HIDN; ++k) acc = fmaf(h[k], W2[k * FMSG + j], acc);
        acc = fmaxf(acc, 0.0f);
        unsafeAtomicAdd(sdst + j, acc);
        atomicMax(mdst + j, __float_as_int(acc));
    }
    atomicAdd(cnt + col, 1);
}

__global__ __launch_bounds__(256) void node_mlp_atomic(
    const float* __restrict__ x, const float* __restrict__ u,
    const int* __restrict__ batch,
    const float* __restrict__ W3, const float* __restrict__ b3,
    const float* __restrict__ W4, const float* __restrict__ b4,
    const float* __restrict__ agg_sum, const int* __restrict__ agg_maxb,
    const int* __restrict__ cnt, float* __restrict__ out, int N)
{
    const int n = blockIdx.x * 256 + threadIdx.x;
    if (n >= N) return;
    const float inv = 1.0f / fmaxf((float)cnt[n], 1.0f);
    float h[HIDN];
#pragma unroll
    for (int j = 0; j < HIDN; ++j) h[j] = b3[j];
    const float* seg_src[4] = {
        x + (size_t)n * FN, agg_sum + (size_t)n * FMSG,
        reinterpret_cast<const float*>(agg_maxb) + (size_t)n * FMSG,
        u + (size_t)batch[n] * FN };
#pragma unroll
    for (int seg = 0; seg < 4; ++seg) {
        const float* src = seg_src[seg];
        const float sc = (seg == 1) ? inv : 1.0f;
        const float* wbase = W3 + (size_t)seg * FN * HIDN;
#pragma unroll 4
        for (int k = 0; k < FN; k += 4) {
            float4 v = *reinterpret_cast<const float4*>(src + k);
            v.x *= sc; v.y *= sc; v.z *= sc; v.w *= sc;
            const float* w = wbase + k * HIDN;
#pragma unroll
            for (int j = 0; j < HIDN; ++j) {
                float hj = h[j];
                hj = fmaf(v.x, w[j], hj);
                hj = fmaf(v.y, w[HIDN + j], hj);
                hj = fmaf(v.z, w[2 * HIDN + j], hj);
                hj = fmaf(v.w, w[3 * HIDN + j], hj);
                h[j] = hj;
            }
        }
    }
#pragma unroll
    for (int j = 0; j < HIDN; ++j) h[j] = fmaxf(h[j], 0.0f);
    float* o = out + (size_t)n * FOUT;
#pragma unroll 4
    for (int j = 0; j < FOUT; j += 4) {
        float4 acc = make_float4(b4[j], b4[j + 1], b4[j + 2], b4[j + 3]);
#pragma unroll
        for (int k = 0; k < HIDN; ++k) {
            const float hk = h[k];
            acc.x = fmaf(hk, W4[k * FOUT + j],     acc.x);
            acc.y = fmaf(hk, W4[k * FOUT + j + 1], acc.y);
            acc.z = fmaf(hk, W4[k * FOUT + j + 2], acc.z);
            acc.w = fmaf(hk, W4[k * FOUT + j + 3], acc.w);
        }
        acc.x = fmaxf(acc.x, 0.0f);
        acc.y = fmaxf(acc.y, 0.0f);
        acc.z = fmaxf(acc.z, 0.0f);
        acc.w = fmaxf(acc.w, 0.0f);
        *reinterpret_cast<float4*>(o + j) = acc;
    }
}

// ===========================================================================
extern "C" void kernel_launch(void* const* d_in, const int* in_sizes, int n_in,
                              void* d_out, int out_size, void* d_ws, size_t ws_size,
                              hipStream_t stream)
{
    const float* x     = (const float*)d_in[0];
    const int*   ei    = (const int*)  d_in[1];
    const float* ea    = (const float*)d_in[2];
    const float* u     = (const float*)d_in[3];
    const int*   batch = (const int*)  d_in[4];
    const float* W1    = (const float*)d_in[5];
    const float* b1    = (const float*)d_in[6];
    const float* W2    = (const float*)d_in[7];
    const float* b2    = (const float*)d_in[8];
    const float* W3    = (const float*)d_in[9];
    const float* b3    = (const float*)d_in[10];
    const float* W4    = (const float*)d_in[11];
    const float* b4    = (const float*)d_in[12];
    float* out = (float*)d_out;

    const int N = in_sizes[0] / FN;   // 50000
    const int E = in_sizes[1] / 2;    // 800000

    const size_t msgB  = (size_t)E * FMSG * 4;
    const size_t aggB  = (size_t)N * FMSG * 4;
    const size_t permB = (size_t)E * 4;
    const size_t needed = msgB + 2 * aggB + permB + ((size_t)N * 3 + 16) * 4;

    if (ws_size >= needed) {
        // ---- sorted path ----
        char* wp = (char*)d_ws;
        float* msg      = (float*)wp;            wp += msgB;
        float* agg_mean = (float*)wp;            wp += aggB;
        float* agg_max  = (float*)wp;            wp += aggB;
        int*   perm     = (int*)wp;              wp += permB;
        int*   offs     = (int*)wp;              wp += ((size_t)N + 4) * 4;
        int*   cnt      = (int*)wp;              wp += (size_t)N * 4;
        int*   cursor   = (int*)wp;

        hipMemsetAsync(cnt, 0, (size_t)N * 4, stream);
        hipMemsetAsync(cursor, 0, (size_t)N * 4, stream);

        hist_kernel<<<(E + 255) / 256, 256, 0, stream>>>(ei, cnt, E);
        scan_kernel<<<1, 1024, 0, stream>>>(cnt, offs, N);
        scatter_kernel<<<(E + 255) / 256, 256, 0, stream>>>(ei, offs, cursor, perm, E);
        edge_mlp_sorted<<<(E + 255) / 256, 256, 0, stream>>>(
            x, ei, ea, W1, b1, W2, b2, perm, msg, E);
        aggregate_kernel<<<(N + 3) / 4, 256, 0, stream>>>(msg, offs, agg_mean, agg_max, N);
        node_mlp_sorted<<<(N + 255) / 256, 256, 0, stream>>>(
            x, u, batch, W3, b3, W4, b4, agg_mean, agg_max, out, N);
    } else {
        // ---- fallback atomic path ----
        float* agg_sum  = (float*)d_ws;
        int*   agg_maxb = (int*)((char*)d_ws + (size_t)N * FMSG * 4);
        int*   cnt      = (int*)((char*)d_ws + (size_t)N * FMSG * 8);
        hipMemsetAsync(d_ws, 0, (size_t)N * FMSG * 8 + (size_t)N * 4, stream);
        edge_mlp_scatter<<<(E + 255) / 256, 256, 0, stream>>>(
            x, ei, ea, W1, b1, W2, b2, agg_sum, agg_maxb, cnt, E);
        node_mlp_atomic<<<(N + 255) / 256, 256, 0, stream>>>(
            x, u, batch, W3, b3, W4, b4, agg_sum, agg_maxb, cnt, out, N);
    }
}

// Round 3
// 565.044 us; speedup vs baseline: 8.6039x; 1.5264x over previous
//
#include <hip/hip_runtime.h>
#include <stdint.h>

constexpr int FN   = 64;   // node / edge / glob feature width
constexpr int HIDN = 32;   // hidden width of both MLPs
constexpr int FMSG = 64;   // message width
constexpr int FOUT = 128;  // output width

__device__ __forceinline__ uint32_t pack_bf16(float a, float b) {
    uint32_t ua = __float_as_uint(a), ub = __float_as_uint(b);
    ua = (ua + 0x7fffu + ((ua >> 16) & 1u)) >> 16;   // RNE
    ub = (ub + 0x7fffu + ((ub >> 16) & 1u)) >> 16;
    return ua | (ub << 16);
}
__device__ __forceinline__ float bf16_to_f(uint32_t h16) {
    return __uint_as_float(h16 << 16);
}

// max n in [0,N-1] with offs[n] <= target   (offs[0]=0 <= target always)
__device__ __forceinline__ int node_of(const int* __restrict__ offs, int N, int target) {
    int l = 0, r = N + 1;                 // invariant: offs[l] <= target < offs[r]
    while (l + 1 < r) {
        const int m = (l + r) >> 1;
        if (offs[m] <= target) l = m; else r = m;
    }
    return l;
}

// ---------------------------------------------------------------------------
__global__ __launch_bounds__(256) void hist_kernel(
    const int* __restrict__ ei, int* __restrict__ cnt, int E)
{
    const int e = blockIdx.x * 256 + threadIdx.x;
    if (e >= E) return;
    atomicAdd(cnt + ei[E + e], 1);
}

// Two-phase exclusive scan, single block of 1024, per-thread contiguous chunk.
__global__ __launch_bounds__(1024) void scan_kernel(
    const int* __restrict__ cnt, int* __restrict__ offs, int N)
{
    __shared__ int sb[1024];
    const int tid   = threadIdx.x;
    const int chunk = (N + 1023) >> 10;
    const int start = tid * chunk;
    const int end   = min(start + chunk, N);
    int run = 0;
    for (int i = start; i < end; ++i) { offs[i] = run; run += cnt[i]; }
    sb[tid] = run;
    __syncthreads();
    for (int d = 1; d < 1024; d <<= 1) {
        const int t = (tid >= d) ? sb[tid - d] : 0;
        __syncthreads();
        sb[tid] += t;
        __syncthreads();
    }
    const int base = sb[tid] - run;       // exclusive prefix of this chunk
    for (int i = start; i < end; ++i) offs[i] += base;
    if (tid == 1023) offs[N] = sb[1023];
}

// Build gathered, dst-sorted edge arrays.
__global__ __launch_bounds__(256) void scatter_kernel(
    const int* __restrict__ ei, const int* __restrict__ offs,
    int* __restrict__ cursor,
    int* __restrict__ rowg, int* __restrict__ colg, int* __restrict__ eidx, int E)
{
    const int e = blockIdx.x * 256 + threadIdx.x;
    if (e >= E) return;
    const int row = ei[e];
    const int col = ei[E + e];
    const int pos = offs[col] + atomicAdd(cursor + col, 1);
    rowg[pos] = row;
    colg[pos] = col;
    eidx[pos] = e;
}

// Per-node linear precompute: Pa = x@W1a + b1, Pb = x@W1b.
__global__ __launch_bounds__(256) void node_pre(
    const float* __restrict__ x, const float* __restrict__ W1,
    const float* __restrict__ b1,
    float* __restrict__ Pa, float* __restrict__ Pb, int N)
{
    const int n = blockIdx.x * 256 + threadIdx.x;
    if (n >= N) return;
    float a[HIDN], bq[HIDN];
#pragma unroll
    for (int j = 0; j < HIDN; ++j) { a[j] = b1[j]; bq[j] = 0.0f; }
    const float* xr = x + (size_t)n * FN;
    const float* WA = W1;               // rows 0..63   (x[row] part)
    const float* WB = W1 + FN * HIDN;   // rows 64..127 (x[col] part)
#pragma unroll 4
    for (int k = 0; k < FN; k += 4) {
        const float4 v = *reinterpret_cast<const float4*>(xr + k);
        const float* wa = WA + k * HIDN;
        const float* wb = WB + k * HIDN;
#pragma unroll
        for (int j = 0; j < HIDN; ++j) {
            float aj = a[j], bj = bq[j];
            aj = fmaf(v.x, wa[j], aj);            bj = fmaf(v.x, wb[j], bj);
            aj = fmaf(v.y, wa[HIDN + j], aj);     bj = fmaf(v.y, wb[HIDN + j], bj);
            aj = fmaf(v.z, wa[2 * HIDN + j], aj); bj = fmaf(v.z, wb[2 * HIDN + j], bj);
            aj = fmaf(v.w, wa[3 * HIDN + j], aj); bj = fmaf(v.w, wb[3 * HIDN + j], bj);
            a[j] = aj; bq[j] = bj;
        }
    }
    float4* pa = reinterpret_cast<float4*>(Pa + (size_t)n * HIDN);
    float4* pb = reinterpret_cast<float4*>(Pb + (size_t)n * HIDN);
#pragma unroll
    for (int q = 0; q < HIDN / 4; ++q) {
        pa[q] = make_float4(a[4*q], a[4*q+1], a[4*q+2], a[4*q+3]);
        pb[q] = make_float4(bq[4*q], bq[4*q+1], bq[4*q+2], bq[4*q+3]);
    }
}

// ---------------------------------------------------------------------------
// Fused: edge MLP (256 edges/block) -> bf16 msgs in LDS -> in-block segmented
// mean/max reduction. Boundary segments combined via atomics.
// LDS row stride 33 words (pad) -> conflict-free reads (2-way broadcast).
// ---------------------------------------------------------------------------
__global__ __launch_bounds__(256) void fused_edge(
    const float* __restrict__ ea,
    const float* __restrict__ W1, const float* __restrict__ W2,
    const float* __restrict__ b2,
    const float* __restrict__ Pa, const float* __restrict__ Pb,
    const int* __restrict__ rowg, const int* __restrict__ colg,
    const int* __restrict__ eidx, const int* __restrict__ offs,
    float* __restrict__ agg_sum, int* __restrict__ agg_maxb,
    int N, int E)
{
    __shared__ uint32_t lmsg[256 * 33];   // 33 KB: 256 edges x 32 bf16-pairs (+pad)
    __shared__ int sh[2];
    const int tid = threadIdx.x;
    const int e0  = blockIdx.x * 256;
    const int e1  = min(e0 + 256, E);
    if (tid == 0) sh[0] = node_of(offs, N, e0);
    if (tid == 1) sh[1] = node_of(offs, N, e1 - 1);

    const int p = e0 + tid;
    if (p < E) {
        const int row = rowg[p];
        const int col = colg[p];
        const int eix = eidx[p];

        float h[HIDN];
        const float4* pa = reinterpret_cast<const float4*>(Pa + (size_t)row * HIDN);
        const float4* pb = reinterpret_cast<const float4*>(Pb + (size_t)col * HIDN);
#pragma unroll
        for (int q = 0; q < HIDN / 4; ++q) {
            const float4 va = pa[q], vb = pb[q];
            h[4*q]   = va.x + vb.x;
            h[4*q+1] = va.y + vb.y;
            h[4*q+2] = va.z + vb.z;
            h[4*q+3] = va.w + vb.w;
        }
        const float* er = ea + (size_t)eix * FN;
        const float* WC = W1 + 2 * FN * HIDN;    // rows 128..191 (edge_attr part)
#pragma unroll 4
        for (int k = 0; k < FN; k += 4) {
            const float4 v = *reinterpret_cast<const float4*>(er + k);
            const float* w = WC + k * HIDN;
#pragma unroll
            for (int j = 0; j < HIDN; ++j) {
                float hj = h[j];
                hj = fmaf(v.x, w[j], hj);
                hj = fmaf(v.y, w[HIDN + j], hj);
                hj = fmaf(v.z, w[2 * HIDN + j], hj);
                hj = fmaf(v.w, w[3 * HIDN + j], hj);
                h[j] = hj;
            }
        }
#pragma unroll
        for (int j = 0; j < HIDN; ++j) h[j] = fmaxf(h[j], 0.0f);

        uint32_t* myrow = lmsg + tid * 33;
#pragma unroll 4
        for (int j = 0; j < FMSG; j += 2) {
            float a0 = b2[j], a1 = b2[j + 1];
#pragma unroll
            for (int k = 0; k < HIDN; ++k) {
                const float hk = h[k];
                a0 = fmaf(hk, W2[k * FMSG + j], a0);
                a1 = fmaf(hk, W2[k * FMSG + j + 1], a1);
            }
            a0 = fmaxf(a0, 0.0f);
            a1 = fmaxf(a1, 0.0f);
            myrow[j >> 1] = pack_bf16(a0, a1);
        }
    }
    __syncthreads();

    // ---- segmented reduction over this block's edge window ----
    const int wid = tid >> 6, lane = tid & 63;
    const int n0 = sh[0], n1 = sh[1];
    for (int n = n0 + wid; n <= n1; n += 4) {
        const int s0 = offs[n], t0 = offs[n + 1];
        const int s = max(s0, e0), t = min(t0, e1);
        float sum = 0.0f, mx = 0.0f;
        for (int q = s; q < t; ++q) {
            const uint32_t wv = lmsg[(q - e0) * 33 + (lane >> 1)];
            const float v = bf16_to_f((lane & 1) ? (wv >> 16) : (wv & 0xffffu));
            sum += v;
            mx = fmaxf(mx, v);
        }
        float* sp = agg_sum  + (size_t)n * FMSG + lane;
        int*   mp = agg_maxb + (size_t)n * FMSG + lane;
        if (s0 >= e0 && t0 <= e1) {       // segment fully inside this block
            *sp = sum;
            *mp = __float_as_int(mx);
        } else {
            unsafeAtomicAdd(sp, sum);
            atomicMax(mp, __float_as_int(mx));
        }
    }
}

// ---------------------------------------------------------------------------
__global__ __launch_bounds__(256) void node_mlp(
    const float* __restrict__ x,
    const float* __restrict__ u,
    const int*   __restrict__ batch,
    const float* __restrict__ W3, const float* __restrict__ b3,
    const float* __restrict__ W4, const float* __restrict__ b4,
    const float* __restrict__ agg_sum, const int* __restrict__ agg_maxb,
    const int*   __restrict__ offs,
    float* __restrict__ out, int N)
{
    const int n = blockIdx.x * 256 + threadIdx.x;
    if (n >= N) return;
    const int deg = offs[n + 1] - offs[n];
    const float inv = (deg > 0) ? 1.0f / (float)deg : 0.0f;

    float h[HIDN];
#pragma unroll
    for (int j = 0; j < HIDN; ++j) h[j] = b3[j];

    const float* seg_src[4] = {
        x + (size_t)n * FN,
        agg_sum + (size_t)n * FMSG,                               // * inv
        reinterpret_cast<const float*>(agg_maxb) + (size_t)n * FMSG,
        u + (size_t)batch[n] * FN
    };

#pragma unroll
    for (int seg = 0; seg < 4; ++seg) {
        const float* src   = seg_src[seg];
        const float  sc    = (seg == 1) ? inv : 1.0f;
        const float* wbase = W3 + (size_t)seg * FN * HIDN;
#pragma unroll 4
        for (int k = 0; k < FN; k += 4) {
            float4 v = *reinterpret_cast<const float4*>(src + k);
            v.x *= sc; v.y *= sc; v.z *= sc; v.w *= sc;
            const float* w = wbase + k * HIDN;
#pragma unroll
            for (int j = 0; j < HIDN; ++j) {
                float hj = h[j];
                hj = fmaf(v.x, w[j], hj);
                hj = fmaf(v.y, w[HIDN + j], hj);
                hj = fmaf(v.z, w[2 * HIDN + j], hj);
                hj = fmaf(v.w, w[3 * HIDN + j], hj);
                h[j] = hj;
            }
        }
    }
#pragma unroll
    for (int j = 0; j < HIDN; ++j) h[j] = fmaxf(h[j], 0.0f);

    float* o = out + (size_t)n * FOUT;
#pragma unroll 4
    for (int j = 0; j < FOUT; j += 4) {
        float4 acc = make_float4(b4[j], b4[j + 1], b4[j + 2], b4[j + 3]);
#pragma unroll
        for (int k = 0; k < HIDN; ++k) {
            const float hk = h[k];
            acc.x = fmaf(hk, W4[k * FOUT + j],     acc.x);
            acc.y = fmaf(hk, W4[k * FOUT + j + 1], acc.y);
            acc.z = fmaf(hk, W4[k * FOUT + j + 2], acc.z);
            acc.w = fmaf(hk, W4[k * FOUT + j + 3], acc.w);
        }
        acc.x = fmaxf(acc.x, 0.0f);
        acc.y = fmaxf(acc.y, 0.0f);
        acc.z = fmaxf(acc.z, 0.0f);
        acc.w = fmaxf(acc.w, 0.0f);
        *reinterpret_cast<float4*>(o + j) = acc;
    }
}

// ===========================================================================
extern "C" void kernel_launch(void* const* d_in, const int* in_sizes, int n_in,
                              void* d_out, int out_size, void* d_ws, size_t ws_size,
                              hipStream_t stream)
{
    const float* x     = (const float*)d_in[0];
    const int*   ei    = (const int*)  d_in[1];
    const float* ea    = (const float*)d_in[2];
    const float* u     = (const float*)d_in[3];
    const int*   batch = (const int*)  d_in[4];
    const float* W1    = (const float*)d_in[5];
    const float* b1    = (const float*)d_in[6];
    const float* W2    = (const float*)d_in[7];
    const float* b2    = (const float*)d_in[8];
    const float* W3    = (const float*)d_in[9];
    const float* b3    = (const float*)d_in[10];
    const float* W4    = (const float*)d_in[11];
    const float* b4    = (const float*)d_in[12];
    float* out = (float*)d_out;

    const int N = in_sizes[0] / FN;   // 50000
    const int E = in_sizes[1] / 2;    // 800000

    // ---- workspace carve (256-B aligned slots) ----
    char* wp = (char*)d_ws;
    auto take = [&](size_t bytes) -> void* {
        void* r = (void*)wp;
        wp += (bytes + 255) & ~(size_t)255;
        return r;
    };
    float* agg_sum  = (float*)take((size_t)N * FMSG * 4);
    int*   agg_maxb = (int*)  take((size_t)N * FMSG * 4);
    int*   cnt      = (int*)  take((size_t)N * 4);
    int*   cursor   = (int*)  take((size_t)N * 4);
    char*  zero_end = wp;                       // zero span: agg_sum..cursor
    int*   offs     = (int*)  take(((size_t)N + 1) * 4);
    int*   rowg     = (int*)  take((size_t)E * 4);
    int*   colg     = (int*)  take((size_t)E * 4);
    int*   eidx     = (int*)  take((size_t)E * 4);
    float* Pa       = (float*)take((size_t)N * HIDN * 4);
    float* Pb       = (float*)take((size_t)N * HIDN * 4);

    hipMemsetAsync(agg_sum, 0, (size_t)(zero_end - (char*)agg_sum), stream);

    hist_kernel   <<<(E + 255) / 256, 256, 0, stream>>>(ei, cnt, E);
    scan_kernel   <<<1, 1024, 0, stream>>>(cnt, offs, N);
    scatter_kernel<<<(E + 255) / 256, 256, 0, stream>>>(ei, offs, cursor, rowg, colg, eidx, E);
    node_pre      <<<(N + 255) / 256, 256, 0, stream>>>(x, W1, b1, Pa, Pb, N);
    fused_edge    <<<(E + 255) / 256, 256, 0, stream>>>(
        ea, W1, W2, b2, Pa, Pb, rowg, colg, eidx, offs, agg_sum, agg_maxb, N, E);
    node_mlp      <<<(N + 255) / 256, 256, 0, stream>>>(
        x, u, batch, W3, b3, W4, b4, agg_sum, agg_maxb, offs, out, N);
}

// Round 4
// 482.478 us; speedup vs baseline: 10.0763x; 1.1711x over previous
//
#include <hip/hip_runtime.h>
#include <stdint.h>

constexpr int FN   = 64;
constexpr int HIDN = 32;
constexpr int FMSG = 64;
constexpr int FOUT = 128;

using short8 = __attribute__((ext_vector_type(8))) short;
using f32x4  = __attribute__((ext_vector_type(4))) float;

union Frag { short8 v; uint32_t u[4]; };

__device__ __forceinline__ uint32_t pack_bf16(float a, float b) {
    uint32_t ua = __float_as_uint(a), ub = __float_as_uint(b);
    ua = (ua + 0x7fffu + ((ua >> 16) & 1u)) >> 16;
    ub = (ub + 0x7fffu + ((ub >> 16) & 1u)) >> 16;
    return ua | (ub << 16);
}
__device__ __forceinline__ uint32_t f2bf(float a) {
    uint32_t ua = __float_as_uint(a);
    return (ua + 0x7fffu + ((ua >> 16) & 1u)) >> 16;
}
__device__ __forceinline__ float bf16_to_f(uint32_t h16) {
    return __uint_as_float(h16 << 16);
}

__device__ __forceinline__ int node_of(const int* __restrict__ offs, int N, int target) {
    int l = 0, r = N + 1;
    while (l + 1 < r) {
        const int m = (l + r) >> 1;
        if (offs[m] <= target) l = m; else r = m;
    }
    return l;
}

// ---------------------------------------------------------------------------
// hist: count per dst node AND record each edge's within-node rank
// (atomicAdd return value) -> scatter needs no cursor atomics.
__global__ __launch_bounds__(256) void hist_kernel(
    const int* __restrict__ ei, int* __restrict__ cnt, int* __restrict__ rank, int E)
{
    const int e4 = (blockIdx.x * 256 + threadIdx.x) * 4;
    if (e4 + 3 < E) {
        const int4 c = *reinterpret_cast<const int4*>(ei + E + e4);
        int4 r;
        r.x = atomicAdd(cnt + c.x, 1);
        r.y = atomicAdd(cnt + c.y, 1);
        r.z = atomicAdd(cnt + c.z, 1);
        r.w = atomicAdd(cnt + c.w, 1);
        *reinterpret_cast<int4*>(rank + e4) = r;
    } else {
        for (int e = e4; e < E; ++e) rank[e] = atomicAdd(cnt + ei[E + e], 1);
    }
}

__global__ __launch_bounds__(1024) void scan_kernel(
    const int* __restrict__ cnt, int* __restrict__ offs, int N)
{
    __shared__ int sb[1024];
    const int tid   = threadIdx.x;
    const int chunk = (N + 1023) >> 10;
    const int start = tid * chunk;
    const int end   = min(start + chunk, N);
    int run = 0;
    for (int i = start; i < end; ++i) { offs[i] = run; run += cnt[i]; }
    sb[tid] = run;
    __syncthreads();
    for (int d = 1; d < 1024; d <<= 1) {
        const int t = (tid >= d) ? sb[tid - d] : 0;
        __syncthreads();
        sb[tid] += t;
        __syncthreads();
    }
    const int base = sb[tid] - run;
    for (int i = start; i < end; ++i) offs[i] += base;
    if (tid == 1023) offs[N] = sb[1023];
}

// scatter: pos = offs[col] + rank[e]; single aligned int4 write per edge.
__global__ __launch_bounds__(256) void scatter_kernel(
    const int* __restrict__ ei, const int* __restrict__ offs,
    const int* __restrict__ rank, int4* __restrict__ re4, int E)
{
    const int e = blockIdx.x * 256 + threadIdx.x;
    if (e >= E) return;
    const int row = ei[e];
    const int col = ei[E + e];
    const int pos = offs[col] + rank[e];
    re4[pos] = make_int4(row, col, e, 0);
}

// Per-node linear precompute (fp32, exact): Pa = x@W1a + b1, Pb = x@W1b.
__global__ __launch_bounds__(256) void node_pre(
    const float* __restrict__ x, const float* __restrict__ W1,
    const float* __restrict__ b1,
    float* __restrict__ Pa, float* __restrict__ Pb, int N)
{
    const int n = blockIdx.x * 256 + threadIdx.x;
    if (n >= N) return;
    float a[HIDN], bq[HIDN];
#pragma unroll
    for (int j = 0; j < HIDN; ++j) { a[j] = b1[j]; bq[j] = 0.0f; }
    const float* xr = x + (size_t)n * FN;
    const float* WA = W1;
    const float* WB = W1 + FN * HIDN;
#pragma unroll 4
    for (int k = 0; k < FN; k += 4) {
        const float4 v = *reinterpret_cast<const float4*>(xr + k);
        const float* wa = WA + k * HIDN;
        const float* wb = WB + k * HIDN;
#pragma unroll
        for (int j = 0; j < HIDN; ++j) {
            float aj = a[j], bj = bq[j];
            aj = fmaf(v.x, wa[j], aj);            bj = fmaf(v.x, wb[j], bj);
            aj = fmaf(v.y, wa[HIDN + j], aj);     bj = fmaf(v.y, wb[HIDN + j], bj);
            aj = fmaf(v.z, wa[2 * HIDN + j], aj); bj = fmaf(v.z, wb[2 * HIDN + j], bj);
            aj = fmaf(v.w, wa[3 * HIDN + j], aj); bj = fmaf(v.w, wb[3 * HIDN + j], bj);
            a[j] = aj; bq[j] = bj;
        }
    }
    float4* pa = reinterpret_cast<float4*>(Pa + (size_t)n * HIDN);
    float4* pb = reinterpret_cast<float4*>(Pb + (size_t)n * HIDN);
#pragma unroll
    for (int q = 0; q < HIDN / 4; ++q) {
        pa[q] = make_float4(a[4*q], a[4*q+1], a[4*q+2], a[4*q+3]);
        pb[q] = make_float4(bq[4*q], bq[4*q+1], bq[4*q+2], bq[4*q+3]);
    }
}

// ---------------------------------------------------------------------------
// MFMA fused edge kernel. Per block: 256 sorted edges, 4 waves.
//   GEMM1: h = relu( (Pa[row]+Pb[col])  +  ea @ WC )   [256x64]@[64x32], bf16
//   GEMM2: msg = relu( h @ W2 + b2 )                   [256x32]@[32x64], bf16
//   then in-block segmented mean/max reduction (lane = feature).
// LDS: one 36 KB buffer, time-shared: Ppair(f32,str36) -> h(f32,str36) -> msg(bf16).
// ---------------------------------------------------------------------------
__global__ __launch_bounds__(256) void fused_edge_mfma(
    const float* __restrict__ ea,
    const float* __restrict__ W1, const float* __restrict__ W2,
    const float* __restrict__ b2,
    const float* __restrict__ Pa, const float* __restrict__ Pb,
    const int4* __restrict__ re4, const int* __restrict__ offs,
    float* __restrict__ agg_sum, int* __restrict__ agg_maxb,
    int N, int E)
{
    __shared__ uint32_t smem[256 * 36];
    __shared__ int sh[2];
    const int tid  = threadIdx.x;
    const int lane = tid & 63;
    const int w    = tid >> 6;
    const int l15  = lane & 15;
    const int l4   = lane >> 4;
    const int e0   = blockIdx.x * 256;
    const int e1   = min(e0 + 256, E);
    if (tid == 0) sh[0] = node_of(offs, N, e0);
    if (tid == 1) sh[1] = node_of(offs, N, e1 - 1);

    // ---- phase 1: Ppair = Pa[row]+Pb[col] into LDS (f32, row stride 36) ----
    const int p = e0 + tid;
    const int4 rce = re4[min(p, E - 1)];
    {
        const float4* pa = reinterpret_cast<const float4*>(Pa + (size_t)rce.x * HIDN);
        const float4* pb = reinterpret_cast<const float4*>(Pb + (size_t)rce.y * HIDN);
        float4* dst = reinterpret_cast<float4*>(&smem[tid * 36]);
#pragma unroll
        for (int q = 0; q < 8; ++q) {
            const float4 a = pa[q], b = pb[q];
            dst[q] = make_float4(a.x + b.x, a.y + b.y, a.z + b.z, a.w + b.w);
        }
    }

    // ---- B fragments (WC rows of W1; W2) -- small, L1/L2-hot ----
    Frag B1[2][2];    // [nt][ks]
    const float* WC = W1 + 2 * FN * HIDN;
#pragma unroll
    for (int nt = 0; nt < 2; ++nt)
#pragma unroll
        for (int ks = 0; ks < 2; ++ks) {
            const int j = nt * 16 + l15;
#pragma unroll
            for (int q = 0; q < 4; ++q) {
                const int k = ks * 32 + l4 * 8 + 2 * q;
                B1[nt][ks].u[q] = pack_bf16(WC[k * HIDN + j], WC[(k + 1) * HIDN + j]);
            }
        }
    Frag B2[4];       // [nt]
#pragma unroll
    for (int nt = 0; nt < 4; ++nt) {
        const int j = nt * 16 + l15;
#pragma unroll
        for (int q = 0; q < 4; ++q) {
            const int k = l4 * 8 + 2 * q;
            B2[nt].u[q] = pack_bf16(W2[k * FMSG + j], W2[(k + 1) * FMSG + j]);
        }
    }

    // ---- A1 fragments: gather ea rows (bf16), lane holds row (l&15) of tile ----
    Frag A1[4][2];    // [mt][ks]
#pragma unroll
    for (int mt = 0; mt < 4; ++mt) {
        const int eix = __shfl(rce.z, mt * 16 + l15, 64);
        const float* rp = ea + (size_t)eix * FN;
#pragma unroll
        for (int ks = 0; ks < 2; ++ks) {
            const float4* gp = reinterpret_cast<const float4*>(rp + ks * 32 + l4 * 8);
            const float4 f0 = gp[0], f1 = gp[1];
            A1[mt][ks].u[0] = pack_bf16(f0.x, f0.y);
            A1[mt][ks].u[1] = pack_bf16(f0.z, f0.w);
            A1[mt][ks].u[2] = pack_bf16(f1.x, f1.y);
            A1[mt][ks].u[3] = pack_bf16(f1.z, f1.w);
        }
    }

    __syncthreads();   // Ppair visible

    // ---- acc1 init = Ppair (C-layout reads), then GEMM1 ----
    f32x4 acc1[4][2];
    const float* Pl = reinterpret_cast<const float*>(smem);
#pragma unroll
    for (int mt = 0; mt < 4; ++mt)
#pragma unroll
        for (int nt = 0; nt < 2; ++nt)
#pragma unroll
            for (int r = 0; r < 4; ++r) {
                const int et = w * 64 + mt * 16 + l4 * 4 + r;
                acc1[mt][nt][r] = Pl[et * 36 + nt * 16 + l15];
            }
#pragma unroll
    for (int mt = 0; mt < 4; ++mt)
#pragma unroll
        for (int nt = 0; nt < 2; ++nt)
#pragma unroll
            for (int ks = 0; ks < 2; ++ks)
                acc1[mt][nt] = __builtin_amdgcn_mfma_f32_16x16x32_bf16(
                    A1[mt][ks].v, B1[nt][ks].v, acc1[mt][nt], 0, 0, 0);

    __syncthreads();   // all Ppair reads done; reuse buffer for h

    // ---- h = relu(acc1) -> LDS (f32, stride 36) in [edge][j] layout ----
    float* Hl = reinterpret_cast<float*>(smem);
#pragma unroll
    for (int mt = 0; mt < 4; ++mt)
#pragma unroll
        for (int nt = 0; nt < 2; ++nt)
#pragma unroll
            for (int r = 0; r < 4; ++r) {
                const int et = w * 64 + mt * 16 + l4 * 4 + r;
                Hl[et * 36 + nt * 16 + l15] = fmaxf(acc1[mt][nt][r], 0.0f);
            }
    __syncthreads();

    // ---- A2 fragments from h (b128 reads, 2-way max), cvt to bf16 ----
    Frag A2[4];
#pragma unroll
    for (int mt = 0; mt < 4; ++mt) {
        const int et2 = w * 64 + mt * 16 + l15;
        const float4* hp = reinterpret_cast<const float4*>(&Hl[et2 * 36 + l4 * 8]);
        const float4 f0 = hp[0], f1 = hp[1];
        A2[mt].u[0] = pack_bf16(f0.x, f0.y);
        A2[mt].u[1] = pack_bf16(f0.z, f0.w);
        A2[mt].u[2] = pack_bf16(f1.x, f1.y);
        A2[mt].u[3] = pack_bf16(f1.z, f1.w);
    }
    __syncthreads();   // all h reads done; reuse buffer for msgs

    // ---- GEMM2 + epilogue: msg = relu(acc2 + b2) -> LDS bf16, swizzled ----
    f32x4 acc2[4][4];
#pragma unroll
    for (int mt = 0; mt < 4; ++mt)
#pragma unroll
        for (int nt = 0; nt < 4; ++nt) {
            acc2[mt][nt] = (f32x4){0.f, 0.f, 0.f, 0.f};
            acc2[mt][nt] = __builtin_amdgcn_mfma_f32_16x16x32_bf16(
                A2[mt].v, B2[nt].v, acc2[mt][nt], 0, 0, 0);
        }
    float b2j[4];
#pragma unroll
    for (int nt = 0; nt < 4; ++nt) b2j[nt] = b2[nt * 16 + l15];

    uint16_t* m16 = reinterpret_cast<uint16_t*>(smem);
#pragma unroll
    for (int mt = 0; mt < 4; ++mt)
#pragma unroll
        for (int nt = 0; nt < 4; ++nt)
#pragma unroll
            for (int r = 0; r < 4; ++r) {
                const int et = w * 64 + mt * 16 + l4 * 4 + r;
                const int j  = nt * 16 + l15;
                const float v = fmaxf(acc2[mt][nt][r] + b2j[nt], 0.0f);
                const int c = nt ^ ((et >> 2) & 3);            // chunk swizzle
                const int word = et * 32 + c * 8 + ((j & 15) >> 1);
                m16[word * 2 + (j & 1)] = (uint16_t)f2bf(v);
            }
    __syncthreads();

    // ---- segmented mean/max reduction (lane = feature) ----
    const int n0 = sh[0], n1 = sh[1];
    for (int n = n0 + w; n <= n1; n += 4) {
        const int s0 = offs[n], t0 = offs[n + 1];
        const int s = max(s0, e0), t = min(t0, e1);
        float sum = 0.0f, mx = 0.0f;
        for (int q = s; q < t; ++q) {
            const int ql = q - e0;
            const int c = (lane >> 4) ^ ((ql >> 2) & 3);
            const uint32_t wv = smem[ql * 32 + c * 8 + ((l15) >> 1)];
            const float v = bf16_to_f((lane & 1) ? (wv >> 16) : (wv & 0xffffu));
            sum += v;
            mx = fmaxf(mx, v);
        }
        float* sp = agg_sum  + (size_t)n * FMSG + lane;
        int*   mp = agg_maxb + (size_t)n * FMSG + lane;
        if (s0 >= e0 && t0 <= e1) {
            *sp = sum;
            *mp = __float_as_int(mx);
        } else {
            unsafeAtomicAdd(sp, sum);
            atomicMax(mp, __float_as_int(mx));
        }
    }
}

// ---------------------------------------------------------------------------
__global__ __launch_bounds__(256) void node_mlp(
    const float* __restrict__ x,
    const float* __restrict__ u,
    const int*   __restrict__ batch,
    const float* __restrict__ W3, const float* __restrict__ b3,
    const float* __restrict__ W4, const float* __restrict__ b4,
    const float* __restrict__ agg_sum, const int* __restrict__ agg_maxb,
    const int*   __restrict__ offs,
    float* __restrict__ out, int N)
{
    const int n = blockIdx.x * 256 + threadIdx.x;
    if (n >= N) return;
    const int deg = offs[n + 1] - offs[n];
    const float inv = (deg > 0) ? 1.0f / (float)deg : 0.0f;

    float h[HIDN];
#pragma unroll
    for (int j = 0; j < HIDN; ++j) h[j] = b3[j];

    const float* seg_src[4] = {
        x + (size_t)n * FN,
        agg_sum + (size_t)n * FMSG,
        reinterpret_cast<const float*>(agg_maxb) + (size_t)n * FMSG,
        u + (size_t)batch[n] * FN
    };

#pragma unroll
    for (int seg = 0; seg < 4; ++seg) {
        const float* src   = seg_src[seg];
        const float  sc    = (seg == 1) ? inv : 1.0f;
        const float* wbase = W3 + (size_t)seg * FN * HIDN;
#pragma unroll 4
        for (int k = 0; k < FN; k += 4) {
            float4 v = *reinterpret_cast<const float4*>(src + k);
            v.x *= sc; v.y *= sc; v.z *= sc; v.w *= sc;
            const float* wk = wbase + k * HIDN;
#pragma unroll
            for (int j = 0; j < HIDN; ++j) {
                float hj = h[j];
                hj = fmaf(v.x, wk[j], hj);
                hj = fmaf(v.y, wk[HIDN + j], hj);
                hj = fmaf(v.z, wk[2 * HIDN + j], hj);
                hj = fmaf(v.w, wk[3 * HIDN + j], hj);
                h[j] = hj;
            }
        }
    }
#pragma unroll
    for (int j = 0; j < HIDN; ++j) h[j] = fmaxf(h[j], 0.0f);

    float* o = out + (size_t)n * FOUT;
#pragma unroll 4
    for (int j = 0; j < FOUT; j += 4) {
        float4 acc = make_float4(b4[j], b4[j + 1], b4[j + 2], b4[j + 3]);
#pragma unroll
        for (int k = 0; k < HIDN; ++k) {
            const float hk = h[k];
            acc.x = fmaf(hk, W4[k * FOUT + j],     acc.x);
            acc.y = fmaf(hk, W4[k * FOUT + j + 1], acc.y);
            acc.z = fmaf(hk, W4[k * FOUT + j + 2], acc.z);
            acc.w = fmaf(hk, W4[k * FOUT + j + 3], acc.w);
        }
        acc.x = fmaxf(acc.x, 0.0f);
        acc.y = fmaxf(acc.y, 0.0f);
        acc.z = fmaxf(acc.z, 0.0f);
        acc.w = fmaxf(acc.w, 0.0f);
        *reinterpret_cast<float4*>(o + j) = acc;
    }
}

// ===========================================================================
extern "C" void kernel_launch(void* const* d_in, const int* in_sizes, int n_in,
                              void* d_out, int out_size, void* d_ws, size_t ws_size,
                              hipStream_t stream)
{
    const float* x     = (const float*)d_in[0];
    const int*   ei    = (const int*)  d_in[1];
    const float* ea    = (const float*)d_in[2];
    const float* u     = (const float*)d_in[3];
    const int*   batch = (const int*)  d_in[4];
    const float* W1    = (const float*)d_in[5];
    const float* b1    = (const float*)d_in[6];
    const float* W2    = (const float*)d_in[7];
    const float* b2    = (const float*)d_in[8];
    const float* W3    = (const float*)d_in[9];
    const float* b3    = (const float*)d_in[10];
    const float* W4    = (const float*)d_in[11];
    const float* b4    = (const float*)d_in[12];
    float* out = (float*)d_out;

    const int N = in_sizes[0] / FN;   // 50000
    const int E = in_sizes[1] / 2;    // 800000

    char* wp = (char*)d_ws;
    auto take = [&](size_t bytes) -> void* {
        void* r = (void*)wp;
        wp += (bytes + 255) & ~(size_t)255;
        return r;
    };
    float* agg_sum  = (float*)take((size_t)N * FMSG * 4);
    int*   agg_maxb = (int*)  take((size_t)N * FMSG * 4);
    int*   cnt      = (int*)  take((size_t)N * 4);
    char*  zero_end = wp;                       // zero span: agg_sum..cnt
    int*   offs     = (int*)  take(((size_t)N + 1) * 4);
    int*   rank     = (int*)  take((size_t)E * 4);
    int4*  re4      = (int4*) take((size_t)E * 16);
    float* Pa       = (float*)take((size_t)N * HIDN * 4);
    float* Pb       = (float*)take((size_t)N * HIDN * 4);

    hipMemsetAsync(agg_sum, 0, (size_t)(zero_end - (char*)agg_sum), stream);

    hist_kernel   <<<(E / 4 + 255) / 256, 256, 0, stream>>>(ei, cnt, rank, E);
    scan_kernel   <<<1, 1024, 0, stream>>>(cnt, offs, N);
    scatter_kernel<<<(E + 255) / 256, 256, 0, stream>>>(ei, offs, rank, re4, E);
    node_pre      <<<(N + 255) / 256, 256, 0, stream>>>(x, W1, b1, Pa, Pb, N);
    fused_edge_mfma<<<(E + 255) / 256, 256, 0, stream>>>(
        ea, W1, W2, b2, Pa, Pb, re4, offs, agg_sum, agg_maxb, N, E);
    node_mlp      <<<(N + 255) / 256, 256, 0, stream>>>(
        x, u, batch, W3, b3, W4, b4, agg_sum, agg_maxb, offs, out, N);
}

// Round 5
// 367.413 us; speedup vs baseline: 13.2320x; 1.3132x over previous
//
#include <hip/hip_runtime.h>
#include <hip/hip_bf16.h>
#include <stdint.h>

constexpr int FN   = 64;
constexpr int HIDN = 32;
constexpr int FMSG = 64;
constexpr int FOUT = 128;

using short8 = __attribute__((ext_vector_type(8))) short;
using f32x4  = __attribute__((ext_vector_type(4))) float;

union Frag { short8 v; uint32_t u[4]; };

__device__ __forceinline__ uint32_t packrn(float a, float b) {
    union { __hip_bfloat162 h; uint32_t u; } cv;
    cv.h = __float22bfloat162_rn(make_float2(a, b));   // v_cvt_pk_bf16_f32
    return cv.u;
}
__device__ __forceinline__ float bf16_to_f(uint32_t h16) {
    return __uint_as_float(h16 << 16);
}

__device__ __forceinline__ int node_of(const int* __restrict__ offs, int N, int target) {
    int l = 0, r = N + 1;
    while (l + 1 < r) {
        const int m = (l + r) >> 1;
        if (offs[m] <= target) l = m; else r = m;
    }
    return l;
}

// ---------------------------------------------------------------------------
// prep: [0,BH) hist+rank | [BH,BH+BP) node_pre (Pa,Pb) | [BH+BP] pack weights
// ---------------------------------------------------------------------------
__global__ __launch_bounds__(256) void prep_kernel(
    const int* __restrict__ ei, int* __restrict__ cnt, int* __restrict__ rank,
    const float* __restrict__ x, const float* __restrict__ W1,
    const float* __restrict__ b1, const float* __restrict__ W2,
    float* __restrict__ Pa, float* __restrict__ Pb,
    uint32_t* __restrict__ PW1, uint32_t* __restrict__ PW2,
    int E, int N, int BH, int BP)
{
    const int b   = blockIdx.x;
    const int tid = threadIdx.x;

    if (b < BH) {
        // ---- histogram + within-node rank ----
        const int e4 = (b * 256 + tid) * 4;
        if (e4 + 3 < E) {
            const int4 c = *reinterpret_cast<const int4*>(ei + E + e4);
            int4 r;
            r.x = atomicAdd(cnt + c.x, 1);
            r.y = atomicAdd(cnt + c.y, 1);
            r.z = atomicAdd(cnt + c.z, 1);
            r.w = atomicAdd(cnt + c.w, 1);
            *reinterpret_cast<int4*>(rank + e4) = r;
        } else {
            for (int e = e4; e < E; ++e) rank[e] = atomicAdd(cnt + ei[E + e], 1);
        }
        return;
    }
    if (b < BH + BP) {
        // ---- node_pre: Pa = x@W1a + b1, Pb = x@W1b (exact fp32) ----
        const int n = (b - BH) * 256 + tid;
        if (n >= N) return;
        float a[HIDN], bq[HIDN];
#pragma unroll
        for (int j = 0; j < HIDN; ++j) { a[j] = b1[j]; bq[j] = 0.0f; }
        const float* xr = x + (size_t)n * FN;
        const float* WA = W1;
        const float* WB = W1 + FN * HIDN;
#pragma unroll 4
        for (int k = 0; k < FN; k += 4) {
            const float4 v = *reinterpret_cast<const float4*>(xr + k);
            const float* wa = WA + k * HIDN;
            const float* wb = WB + k * HIDN;
#pragma unroll
            for (int j = 0; j < HIDN; ++j) {
                float aj = a[j], bj = bq[j];
                aj = fmaf(v.x, wa[j], aj);            bj = fmaf(v.x, wb[j], bj);
                aj = fmaf(v.y, wa[HIDN + j], aj);     bj = fmaf(v.y, wb[HIDN + j], bj);
                aj = fmaf(v.z, wa[2 * HIDN + j], aj); bj = fmaf(v.z, wb[2 * HIDN + j], bj);
                aj = fmaf(v.w, wa[3 * HIDN + j], aj); bj = fmaf(v.w, wb[3 * HIDN + j], bj);
                a[j] = aj; bq[j] = bj;
            }
        }
        float4* pa = reinterpret_cast<float4*>(Pa + (size_t)n * HIDN);
        float4* pb = reinterpret_cast<float4*>(Pb + (size_t)n * HIDN);
#pragma unroll
        for (int q = 0; q < HIDN / 4; ++q) {
            pa[q] = make_float4(a[4*q], a[4*q+1], a[4*q+2], a[4*q+3]);
            pb[q] = make_float4(bq[4*q], bq[4*q+1], bq[4*q+2], bq[4*q+3]);
        }
        return;
    }
    // ---- pack WC (W1 rows 128..191) and W2 into bf16 B-fragment layout ----
    const float* WC = W1 + 2 * FN * HIDN;
    for (int i = tid; i < 1024; i += 256) {          // PW1[j][k2], j<32, k2<32
        const int j = i >> 5, k2 = i & 31;
        PW1[i] = packrn(WC[(2 * k2) * HIDN + j], WC[(2 * k2 + 1) * HIDN + j]);
    }
    for (int i = tid; i < 1024; i += 256) {          // PW2[j][k2], j<64, k2<16
        const int j = i >> 4, k2 = i & 15;
        PW2[i] = packrn(W2[(2 * k2) * FMSG + j], W2[(2 * k2 + 1) * FMSG + j]);
    }
}

// ---------------------------------------------------------------------------
// Multi-block scan over cnt[N] -> offs[N+1]
// ---------------------------------------------------------------------------
__global__ __launch_bounds__(256) void scanA_kernel(
    const int* __restrict__ cnt, int* __restrict__ part, int N)
{
    __shared__ int red[256];
    const int tid  = threadIdx.x;
    const int base = blockIdx.x * 2048 + tid * 8;
    int s = 0;
    if (base + 8 <= N) {
        const int4 a = *reinterpret_cast<const int4*>(cnt + base);
        const int4 b = *reinterpret_cast<const int4*>(cnt + base + 4);
        s = a.x + a.y + a.z + a.w + b.x + b.y + b.z + b.w;
    } else {
        for (int i = base; i < min(base + 8, N); ++i) s += cnt[i];
    }
    red[tid] = s;
    __syncthreads();
    for (int d = 128; d > 0; d >>= 1) {
        if (tid < d) red[tid] += red[tid + d];
        __syncthreads();
    }
    if (tid == 0) part[blockIdx.x] = red[0];
}

__global__ __launch_bounds__(64) void scanB_kernel(
    const int* __restrict__ part, int* __restrict__ partx,
    int* __restrict__ offs, int NB, int N)
{
    if (threadIdx.x == 0) {
        int run = 0;
        for (int i = 0; i < NB; ++i) { partx[i] = run; run += part[i]; }
        offs[N] = run;
    }
}

__global__ __launch_bounds__(256) void scanC_kernel(
    const int* __restrict__ cnt, const int* __restrict__ partx,
    int* __restrict__ offs, int N)
{
    __shared__ int sb[256];
    const int tid  = threadIdx.x;
    const int base = blockIdx.x * 2048 + tid * 8;
    int v[8];
    int tsum = 0;
#pragma unroll
    for (int q = 0; q < 8; ++q) {
        const int i = base + q;
        v[q] = (i < N) ? cnt[i] : 0;
        tsum += v[q];
    }
    sb[tid] = tsum;
    __syncthreads();
    for (int d = 1; d < 256; d <<= 1) {
        const int t = (tid >= d) ? sb[tid - d] : 0;
        __syncthreads();
        sb[tid] += t;
        __syncthreads();
    }
    int run = partx[blockIdx.x] + sb[tid] - tsum;
#pragma unroll
    for (int q = 0; q < 8; ++q) {
        const int i = base + q;
        if (i < N) offs[i] = run;
        run += v[q];
    }
}

// scatter: pos = offs[col] + rank[e]; single aligned int4 write per edge.
__global__ __launch_bounds__(256) void scatter_kernel(
    const int* __restrict__ ei, const int* __restrict__ offs,
    const int* __restrict__ rank, int4* __restrict__ re4, int E)
{
    const int e = blockIdx.x * 256 + threadIdx.x;
    if (e >= E) return;
    const int row = ei[e];
    const int col = ei[E + e];
    const int pos = offs[col] + rank[e];
    re4[pos] = make_int4(row, col, e, 0);
}

// ---------------------------------------------------------------------------
// MFMA fused edge kernel: 192 sorted edges / 3 waves per block.
//   GEMM1: h = relu( (Pa[row]+Pb[col]) + ea @ WC )    [192x64]@[64x32] bf16
//   GEMM2: msg = relu( h @ W2 + b2 )                  [192x32]@[32x64] bf16
//   in-block segmented mean/max (lane = feature), pairs packed along edges.
// LDS 26.1KB time-shared: Ppair(f32,str34) -> h(f32,str34) -> msg(u32 pairs).
// ---------------------------------------------------------------------------
__global__ __launch_bounds__(192) void fused_edge_mfma(
    const float* __restrict__ ea,
    const uint32_t* __restrict__ PW1, const uint32_t* __restrict__ PW2,
    const float* __restrict__ b2,
    const float* __restrict__ Pa, const float* __restrict__ Pb,
    const int4* __restrict__ re4, const int* __restrict__ offs,
    float* __restrict__ agg_sum, int* __restrict__ agg_maxb,
    int N, int E)
{
    __shared__ uint32_t smem[192 * 34];
    __shared__ int sh[2];
    const int tid  = threadIdx.x;
    const int lane = tid & 63;
    const int w    = tid >> 6;            // 0..2
    const int l15  = lane & 15;
    const int l4   = lane >> 4;
    const int e0   = blockIdx.x * 192;
    const int e1   = min(e0 + 192, E);
    if (tid == 0) sh[0] = node_of(offs, N, e0);
    if (tid == 1) sh[1] = node_of(offs, N, e1 - 1);

    // ---- phase 1: Ppair = Pa[row]+Pb[col] -> LDS (f32, row stride 34) ----
    const int p = e0 + tid;
    const int4 rce = re4[min(p, E - 1)];
    {
        const float2* pa = reinterpret_cast<const float2*>(Pa + (size_t)rce.x * HIDN);
        const float2* pb = reinterpret_cast<const float2*>(Pb + (size_t)rce.y * HIDN);
        float2* dst = reinterpret_cast<float2*>(&smem[tid * 34]);
#pragma unroll
        for (int q = 0; q < 16; ++q) {
            const float2 a = pa[q], b = pb[q];
            dst[q] = make_float2(a.x + b.x, a.y + b.y);
        }
    }

    // ---- B fragments: direct b128 loads of pre-packed weights ----
    Frag B1[2][2];
#pragma unroll
    for (int nt = 0; nt < 2; ++nt)
#pragma unroll
        for (int ks = 0; ks < 2; ++ks) {
            const uint4 q = *reinterpret_cast<const uint4*>(
                &PW1[(nt * 16 + l15) * 32 + ks * 16 + l4 * 4]);
            B1[nt][ks].u[0] = q.x; B1[nt][ks].u[1] = q.y;
            B1[nt][ks].u[2] = q.z; B1[nt][ks].u[3] = q.w;
        }
    Frag B2[4];
#pragma unroll
    for (int nt = 0; nt < 4; ++nt) {
        const uint4 q = *reinterpret_cast<const uint4*>(
            &PW2[(nt * 16 + l15) * 16 + l4 * 4]);
        B2[nt].u[0] = q.x; B2[nt].u[1] = q.y;
        B2[nt].u[2] = q.z; B2[nt].u[3] = q.w;
    }

    // ---- A1: gather ea rows, cvt_pk to bf16 ----
    Frag A1[4][2];
#pragma unroll
    for (int mt = 0; mt < 4; ++mt) {
        const int eix = __shfl(rce.z, mt * 16 + l15, 64);
        const float* rp = ea + (size_t)eix * FN;
#pragma unroll
        for (int ks = 0; ks < 2; ++ks) {
            const float4* gp = reinterpret_cast<const float4*>(rp + ks * 32 + l4 * 8);
            const float4 f0 = gp[0], f1 = gp[1];
            A1[mt][ks].u[0] = packrn(f0.x, f0.y);
            A1[mt][ks].u[1] = packrn(f0.z, f0.w);
            A1[mt][ks].u[2] = packrn(f1.x, f1.y);
            A1[mt][ks].u[3] = packrn(f1.z, f1.w);
        }
    }

    __syncthreads();   // Ppair visible

    // ---- acc1 init = Ppair (C-layout), GEMM1 ----
    f32x4 acc1[4][2];
    const float* Pl = reinterpret_cast<const float*>(smem);
#pragma unroll
    for (int mt = 0; mt < 4; ++mt)
#pragma unroll
        for (int nt = 0; nt < 2; ++nt)
#pragma unroll
            for (int r = 0; r < 4; ++r) {
                const int et = w * 64 + mt * 16 + l4 * 4 + r;
                acc1[mt][nt][r] = Pl[et * 34 + nt * 16 + l15];
            }
#pragma unroll
    for (int mt = 0; mt < 4; ++mt)
#pragma unroll
        for (int nt = 0; nt < 2; ++nt)
#pragma unroll
            for (int ks = 0; ks < 2; ++ks)
                acc1[mt][nt] = __builtin_amdgcn_mfma_f32_16x16x32_bf16(
                    A1[mt][ks].v, B1[nt][ks].v, acc1[mt][nt], 0, 0, 0);

    __syncthreads();   // Ppair reads done; reuse buffer for h

    float* Hl = reinterpret_cast<float*>(smem);
#pragma unroll
    for (int mt = 0; mt < 4; ++mt)
#pragma unroll
        for (int nt = 0; nt < 2; ++nt)
#pragma unroll
            for (int r = 0; r < 4; ++r) {
                const int et = w * 64 + mt * 16 + l4 * 4 + r;
                Hl[et * 34 + nt * 16 + l15] = fmaxf(acc1[mt][nt][r], 0.0f);
            }
    __syncthreads();

    // ---- A2 from h (float2 reads), cvt_pk ----
    Frag A2[4];
#pragma unroll
    for (int mt = 0; mt < 4; ++mt) {
        const int et2 = w * 64 + mt * 16 + l15;
        const float* hb = &Hl[et2 * 34 + l4 * 8];
        const float2 g0 = *reinterpret_cast<const float2*>(hb + 0);
        const float2 g1 = *reinterpret_cast<const float2*>(hb + 2);
        const float2 g2 = *reinterpret_cast<const float2*>(hb + 4);
        const float2 g3 = *reinterpret_cast<const float2*>(hb + 6);
        A2[mt].u[0] = packrn(g0.x, g0.y);
        A2[mt].u[1] = packrn(g1.x, g1.y);
        A2[mt].u[2] = packrn(g2.x, g2.y);
        A2[mt].u[3] = packrn(g3.x, g3.y);
    }
    __syncthreads();   // h reads done; reuse buffer for msg pairs

    // ---- GEMM2 + epilogue: pack msg pairs along edge dim ----
    f32x4 acc2[4][4];
#pragma unroll
    for (int mt = 0; mt < 4; ++mt)
#pragma unroll
        for (int nt = 0; nt < 4; ++nt) {
            acc2[mt][nt] = (f32x4){0.f, 0.f, 0.f, 0.f};
            acc2[mt][nt] = __builtin_amdgcn_mfma_f32_16x16x32_bf16(
                A2[mt].v, B2[nt].v, acc2[mt][nt], 0, 0, 0);
        }
    float b2j[4];
#pragma unroll
    for (int nt = 0; nt < 4; ++nt) b2j[nt] = b2[nt * 16 + l15];

#pragma unroll
    for (int mt = 0; mt < 4; ++mt)
#pragma unroll
        for (int nt = 0; nt < 4; ++nt) {
            const int j = nt * 16 + l15;
#pragma unroll
            for (int rp2 = 0; rp2 < 2; ++rp2) {
                const int r  = rp2 * 2;
                const int q2 = (w * 64 + mt * 16 + l4 * 4 + r) >> 1;
                const float v0 = fmaxf(acc2[mt][nt][r]     + b2j[nt], 0.0f);
                const float v1 = fmaxf(acc2[mt][nt][r + 1] + b2j[nt], 0.0f);
                smem[q2 * 64 + (j ^ ((q2 & 3) << 4))] = packrn(v0, v1);
            }
        }
    __syncthreads();

    // ---- segmented mean/max (lane = feature), 2 edges per LDS read ----
    const int n0 = sh[0], n1 = sh[1];
    for (int n = n0 + w; n <= n1; n += 3) {
        const int s0 = offs[n], t0 = offs[n + 1];
        const int sl = max(s0, e0) - e0, tl = min(t0, e1) - e0;
        float sum = 0.0f, mx = 0.0f;
        int q = sl;
        if (q < tl && (q & 1)) {
            const int q2 = q >> 1;
            const uint32_t wv = smem[q2 * 64 + (lane ^ ((q2 & 3) << 4))];
            const float v = bf16_to_f(wv >> 16);
            sum += v; mx = fmaxf(mx, v); ++q;
        }
        for (; q + 1 < tl; q += 2) {
            const int q2 = q >> 1;
            const uint32_t wv = smem[q2 * 64 + (lane ^ ((q2 & 3) << 4))];
            const float v0 = bf16_to_f(wv & 0xffffu), v1 = bf16_to_f(wv >> 16);
            sum += v0 + v1; mx = fmaxf(mx, fmaxf(v0, v1));
        }
        if (q < tl) {
            const int q2 = q >> 1;
            const uint32_t wv = smem[q2 * 64 + (lane ^ ((q2 & 3) << 4))];
            const float v = bf16_to_f(wv & 0xffffu);
            sum += v; mx = fmaxf(mx, v);
        }
        float* sp = agg_sum  + (size_t)n * FMSG + lane;
        int*   mp = agg_maxb + (size_t)n * FMSG + lane;
        if (s0 >= e0 && t0 <= e1) {
            *sp = sum;
            *mp = __float_as_int(mx);
        } else {
            unsafeAtomicAdd(sp, sum);
            atomicMax(mp, __float_as_int(mx));
        }
    }
}

// ---------------------------------------------------------------------------
__global__ __launch_bounds__(256) void node_mlp(
    const float* __restrict__ x,
    const float* __restrict__ u,
    const int*   __restrict__ batch,
    const float* __restrict__ W3, const float* __restrict__ b3,
    const float* __restrict__ W4, const float* __restrict__ b4,
    const float* __restrict__ agg_sum, const int* __restrict__ agg_maxb,
    const int*   __restrict__ offs,
    float* __restrict__ out, int N)
{
    const int n = blockIdx.x * 256 + threadIdx.x;
    if (n >= N) return;
    const int deg = offs[n + 1] - offs[n];
    const float inv = (deg > 0) ? 1.0f / (float)deg : 0.0f;

    float h[HIDN];
#pragma unroll
    for (int j = 0; j < HIDN; ++j) h[j] = b3[j];

    const float* seg_src[4] = {
        x + (size_t)n * FN,
        agg_sum + (size_t)n * FMSG,
        reinterpret_cast<const float*>(agg_maxb) + (size_t)n * FMSG,
        u + (size_t)batch[n] * FN
    };

#pragma unroll
    for (int seg = 0; seg < 4; ++seg) {
        const float* src   = seg_src[seg];
        const float  sc    = (seg == 1) ? inv : 1.0f;
        const float* wbase = W3 + (size_t)seg * FN * HIDN;
#pragma unroll 4
        for (int k = 0; k < FN; k += 4) {
            float4 v = *reinterpret_cast<const float4*>(src + k);
            v.x *= sc; v.y *= sc; v.z *= sc; v.w *= sc;
            const float* wk = wbase + k * HIDN;
#pragma unroll
            for (int j = 0; j < HIDN; ++j) {
                float hj = h[j];
                hj = fmaf(v.x, wk[j], hj);
                hj = fmaf(v.y, wk[HIDN + j], hj);
                hj = fmaf(v.z, wk[2 * HIDN + j], hj);
                hj = fmaf(v.w, wk[3 * HIDN + j], hj);
                h[j] = hj;
            }
        }
    }
#pragma unroll
    for (int j = 0; j < HIDN; ++j) h[j] = fmaxf(h[j], 0.0f);

    float* o = out + (size_t)n * FOUT;
#pragma unroll 4
    for (int j = 0; j < FOUT; j += 4) {
        float4 acc = make_float4(b4[j], b4[j + 1], b4[j + 2], b4[j + 3]);
#pragma unroll
        for (int k = 0; k < HIDN; ++k) {
            const float hk = h[k];
            acc.x = fmaf(hk, W4[k * FOUT + j],     acc.x);
            acc.y = fmaf(hk, W4[k * FOUT + j + 1], acc.y);
            acc.z = fmaf(hk, W4[k * FOUT + j + 2], acc.z);
            acc.w = fmaf(hk, W4[k * FOUT + j + 3], acc.w);
        }
        acc.x = fmaxf(acc.x, 0.0f);
        acc.y = fmaxf(acc.y, 0.0f);
        acc.z = fmaxf(acc.z, 0.0f);
        acc.w = fmaxf(acc.w, 0.0f);
        *reinterpret_cast<float4*>(o + j) = acc;
    }
}

// ===========================================================================
extern "C" void kernel_launch(void* const* d_in, const int* in_sizes, int n_in,
                              void* d_out, int out_size, void* d_ws, size_t ws_size,
                              hipStream_t stream)
{
    const float* x     = (const float*)d_in[0];
    const int*   ei    = (const int*)  d_in[1];
    const float* ea    = (const float*)d_in[2];
    const float* u     = (const float*)d_in[3];
    const int*   batch = (const int*)  d_in[4];
    const float* W1    = (const float*)d_in[5];
    const float* b1    = (const float*)d_in[6];
    const float* W2    = (const float*)d_in[7];
    const float* b2    = (const float*)d_in[8];
    const float* W3    = (const float*)d_in[9];
    const float* b3    = (const float*)d_in[10];
    const float* W4    = (const float*)d_in[11];
    const float* b4    = (const float*)d_in[12];
    float* out = (float*)d_out;

    const int N = in_sizes[0] / FN;   // 50000
    const int E = in_sizes[1] / 2;    // 800000

    char* wp = (char*)d_ws;
    auto take = [&](size_t bytes) -> void* {
        void* r = (void*)wp;
        wp += (bytes + 255) & ~(size_t)255;
        return r;
    };
    float*    agg_sum  = (float*)   take((size_t)N * FMSG * 4);
    int*      agg_maxb = (int*)     take((size_t)N * FMSG * 4);
    int*      cnt      = (int*)     take((size_t)N * 4);
    char*     zero_end = wp;                       // zero span: agg_sum..cnt
    int*      offs     = (int*)     take(((size_t)N + 1) * 4);
    int*      rank     = (int*)     take((size_t)E * 4);
    int4*     re4      = (int4*)    take((size_t)E * 16);
    float*    Pa       = (float*)   take((size_t)N * HIDN * 4);
    float*    Pb       = (float*)   take((size_t)N * HIDN * 4);
    uint32_t* PW1      = (uint32_t*)take(1024 * 4);
    uint32_t* PW2      = (uint32_t*)take(1024 * 4);
    int*      part     = (int*)     take(64 * 4);
    int*      partx    = (int*)     take(64 * 4);

    hipMemsetAsync(agg_sum, 0, (size_t)(zero_end - (char*)agg_sum), stream);

    const int BH = (E / 4 + 255) / 256;            // hist blocks
    const int BP = (N + 255) / 256;                // node_pre blocks
    const int NB = (N + 2047) / 2048;              // scan blocks

    prep_kernel   <<<BH + BP + 1, 256, 0, stream>>>(
        ei, cnt, rank, x, W1, b1, W2, Pa, Pb, PW1, PW2, E, N, BH, BP);
    scanA_kernel  <<<NB, 256, 0, stream>>>(cnt, part, N);
    scanB_kernel  <<<1, 64, 0, stream>>>(part, partx, offs, NB, N);
    scanC_kernel  <<<NB, 256, 0, stream>>>(cnt, partx, offs, N);
    scatter_kernel<<<(E + 255) / 256, 256, 0, stream>>>(ei, offs, rank, re4, E);
    fused_edge_mfma<<<(E + 191) / 192, 192, 0, stream>>>(
        ea, PW1, PW2, b2, Pa, Pb, re4, offs, agg_sum, agg_maxb, N, E);
    node_mlp      <<<(N + 255) / 256, 256, 0, stream>>>(
        x, u, batch, W3, b3, W4, b4, agg_sum, agg_maxb, offs, out, N);
}

// Round 6
// 272.749 us; speedup vs baseline: 17.8245x; 1.3471x over previous
//
#include <hip/hip_runtime.h>
#include <hip/hip_bf16.h>
#include <stdint.h>

constexpr int FN   = 64;
constexpr int HIDN = 32;
constexpr int FMSG = 64;
constexpr int FOUT = 128;

using short8 = __attribute__((ext_vector_type(8))) short;
using f32x4  = __attribute__((ext_vector_type(4))) float;

union Frag { short8 v; uint32_t u[4]; };

__device__ __forceinline__ uint32_t packrn(float a, float b) {
    union { __hip_bfloat162 h; uint32_t u; } cv;
    cv.h = __float22bfloat162_rn(make_float2(a, b));   // v_cvt_pk_bf16_f32
    return cv.u;
}
__device__ __forceinline__ float bf16_to_f(uint32_t h16) {
    return __uint_as_float(h16 << 16);
}

__device__ __forceinline__ int node_of(const int* __restrict__ offs, int N, int target) {
    int l = 0, r = N + 1;
    while (l + 1 < r) {
        const int m = (l + r) >> 1;
        if (offs[m] <= target) l = m; else r = m;
    }
    return l;
}

// ---------------------------------------------------------------------------
// prep: [0,BH) hist+rank | [BH,BH+BP) node_pre (Pa,Pb,Qc) | [BH+BP] pack + Qu
// ---------------------------------------------------------------------------
__global__ __launch_bounds__(256) void prep_kernel(
    const int* __restrict__ ei, int* __restrict__ cnt, int* __restrict__ rank,
    const float* __restrict__ x, const float* __restrict__ u,
    const float* __restrict__ W1, const float* __restrict__ b1,
    const float* __restrict__ W2,
    const float* __restrict__ W3, const float* __restrict__ b3,
    const float* __restrict__ W4,
    float* __restrict__ Pa, float* __restrict__ Pb, float* __restrict__ Qc,
    float* __restrict__ Qu,
    uint32_t* __restrict__ PW1, uint32_t* __restrict__ PW2,
    uint32_t* __restrict__ PW3, uint32_t* __restrict__ PW4,
    int E, int N, int G, int BH, int BP)
{
    const int b   = blockIdx.x;
    const int tid = threadIdx.x;

    if (b < BH) {
        // ---- histogram + within-node rank ----
        const int e4 = (b * 256 + tid) * 4;
        if (e4 + 3 < E) {
            const int4 c = *reinterpret_cast<const int4*>(ei + E + e4);
            int4 r;
            r.x = atomicAdd(cnt + c.x, 1);
            r.y = atomicAdd(cnt + c.y, 1);
            r.z = atomicAdd(cnt + c.z, 1);
            r.w = atomicAdd(cnt + c.w, 1);
            *reinterpret_cast<int4*>(rank + e4) = r;
        } else {
            for (int e = e4; e < E; ++e) rank[e] = atomicAdd(cnt + ei[E + e], 1);
        }
        return;
    }
    if (b < BH + BP) {
        // ---- node_pre: Pa = x@W1a + b1, Pb = x@W1b, Qc = x@W3a + b3 ----
        const int n = (b - BH) * 256 + tid;
        if (n >= N) return;
        float a[HIDN], bq[HIDN], c[HIDN];
#pragma unroll
        for (int j = 0; j < HIDN; ++j) { a[j] = b1[j]; bq[j] = 0.0f; c[j] = b3[j]; }
        const float* xr = x + (size_t)n * FN;
        const float* WA = W1;
        const float* WB = W1 + FN * HIDN;
        const float* WX = W3;                   // rows 0..63 of W3
#pragma unroll 2
        for (int k = 0; k < FN; k += 4) {
            const float4 v = *reinterpret_cast<const float4*>(xr + k);
            const float* wa = WA + k * HIDN;
            const float* wb = WB + k * HIDN;
            const float* wc = WX + k * HIDN;
#pragma unroll
            for (int j = 0; j < HIDN; ++j) {
                float aj = a[j], bj = bq[j], cj = c[j];
                aj = fmaf(v.x, wa[j], aj);            bj = fmaf(v.x, wb[j], bj);            cj = fmaf(v.x, wc[j], cj);
                aj = fmaf(v.y, wa[HIDN + j], aj);     bj = fmaf(v.y, wb[HIDN + j], bj);     cj = fmaf(v.y, wc[HIDN + j], cj);
                aj = fmaf(v.z, wa[2 * HIDN + j], aj); bj = fmaf(v.z, wb[2 * HIDN + j], bj); cj = fmaf(v.z, wc[2 * HIDN + j], cj);
                aj = fmaf(v.w, wa[3 * HIDN + j], aj); bj = fmaf(v.w, wb[3 * HIDN + j], bj); cj = fmaf(v.w, wc[3 * HIDN + j], cj);
                a[j] = aj; bq[j] = bj; c[j] = cj;
            }
        }
        float4* pa = reinterpret_cast<float4*>(Pa + (size_t)n * HIDN);
        float4* pb = reinterpret_cast<float4*>(Pb + (size_t)n * HIDN);
        float4* qc = reinterpret_cast<float4*>(Qc + (size_t)n * HIDN);
#pragma unroll
        for (int q = 0; q < HIDN / 4; ++q) {
            pa[q] = make_float4(a[4*q], a[4*q+1], a[4*q+2], a[4*q+3]);
            pb[q] = make_float4(bq[4*q], bq[4*q+1], bq[4*q+2], bq[4*q+3]);
            qc[q] = make_float4(c[4*q], c[4*q+1], c[4*q+2], c[4*q+3]);
        }
        return;
    }
    // ---- pack weights + Qu = u@W3d (per graph) ----
    const float* WC = W1 + 2 * FN * HIDN;
    for (int i = tid; i < 1024; i += 256) {          // PW1[j<32][k2<32]
        const int j = i >> 5, k2 = i & 31;
        PW1[i] = packrn(WC[(2 * k2) * HIDN + j], WC[(2 * k2 + 1) * HIDN + j]);
    }
    for (int i = tid; i < 1024; i += 256) {          // PW2[j<64][k2<16]
        const int j = i >> 4, k2 = i & 15;
        PW2[i] = packrn(W2[(2 * k2) * FMSG + j], W2[(2 * k2 + 1) * FMSG + j]);
    }
    const float* W3m = W3 + 64 * HIDN;               // rows 64..191 (mean|max)
    for (int i = tid; i < 2048; i += 256) {          // PW3[j<32][k2<64]
        const int j = i >> 6, k2 = i & 63;
        PW3[i] = packrn(W3m[(2 * k2) * HIDN + j], W3m[(2 * k2 + 1) * HIDN + j]);
    }
    for (int i = tid; i < 2048; i += 256) {          // PW4[j<128][k2<16]
        const int j = i >> 4, k2 = i & 15;
        PW4[i] = packrn(W4[(2 * k2) * FOUT + j], W4[(2 * k2 + 1) * FOUT + j]);
    }
    const float* W3u = W3 + 192 * HIDN;              // rows 192..255 (u part)
    for (int i = tid; i < G * HIDN; i += 256) {      // Qu[g][j]
        const int g = i >> 5, j = i & 31;
        const float* ur = u + (size_t)g * FN;
        float acc = 0.0f;
#pragma unroll 8
        for (int k = 0; k < FN; ++k) acc = fmaf(ur[k], W3u[k * HIDN + j], acc);
        Qu[i] = acc;
    }
}

// ---------------------------------------------------------------------------
// Multi-block scan over cnt[N] -> offs[N+1]
// ---------------------------------------------------------------------------
__global__ __launch_bounds__(256) void scanA_kernel(
    const int* __restrict__ cnt, int* __restrict__ part, int N)
{
    __shared__ int red[256];
    const int tid  = threadIdx.x;
    const int base = blockIdx.x * 2048 + tid * 8;
    int s = 0;
    if (base + 8 <= N) {
        const int4 a = *reinterpret_cast<const int4*>(cnt + base);
        const int4 b = *reinterpret_cast<const int4*>(cnt + base + 4);
        s = a.x + a.y + a.z + a.w + b.x + b.y + b.z + b.w;
    } else {
        for (int i = base; i < min(base + 8, N); ++i) s += cnt[i];
    }
    red[tid] = s;
    __syncthreads();
    for (int d = 128; d > 0; d >>= 1) {
        if (tid < d) red[tid] += red[tid + d];
        __syncthreads();
    }
    if (tid == 0) part[blockIdx.x] = red[0];
}

__global__ __launch_bounds__(64) void scanB_kernel(
    const int* __restrict__ part, int* __restrict__ partx,
    int* __restrict__ offs, int NB, int N)
{
    if (threadIdx.x == 0) {
        int run = 0;
        for (int i = 0; i < NB; ++i) { partx[i] = run; run += part[i]; }
        offs[N] = run;
    }
}

__global__ __launch_bounds__(256) void scanC_kernel(
    const int* __restrict__ cnt, const int* __restrict__ partx,
    int* __restrict__ offs, int N)
{
    __shared__ int sb[256];
    const int tid  = threadIdx.x;
    const int base = blockIdx.x * 2048 + tid * 8;
    int v[8];
    int tsum = 0;
#pragma unroll
    for (int q = 0; q < 8; ++q) {
        const int i = base + q;
        v[q] = (i < N) ? cnt[i] : 0;
        tsum += v[q];
    }
    sb[tid] = tsum;
    __syncthreads();
    for (int d = 1; d < 256; d <<= 1) {
        const int t = (tid >= d) ? sb[tid - d] : 0;
        __syncthreads();
        sb[tid] += t;
        __syncthreads();
    }
    int run = partx[blockIdx.x] + sb[tid] - tsum;
#pragma unroll
    for (int q = 0; q < 8; ++q) {
        const int i = base + q;
        if (i < N) offs[i] = run;
        run += v[q];
    }
}

// scatter: pos = offs[col] + rank[e]; single aligned int4 write per edge.
__global__ __launch_bounds__(256) void scatter_kernel(
    const int* __restrict__ ei, const int* __restrict__ offs,
    const int* __restrict__ rank, int4* __restrict__ re4, int E)
{
    const int e = blockIdx.x * 256 + threadIdx.x;
    if (e >= E) return;
    const int row = ei[e];
    const int col = ei[E + e];
    const int pos = offs[col] + rank[e];
    re4[pos] = make_int4(row, col, e, 0);
}

// ---------------------------------------------------------------------------
// MFMA fused edge kernel: 192 sorted edges / 3 waves per block (unchanged R5).
// ---------------------------------------------------------------------------
__global__ __launch_bounds__(192) void fused_edge_mfma(
    const float* __restrict__ ea,
    const uint32_t* __restrict__ PW1, const uint32_t* __restrict__ PW2,
    const float* __restrict__ b2,
    const float* __restrict__ Pa, const float* __restrict__ Pb,
    const int4* __restrict__ re4, const int* __restrict__ offs,
    float* __restrict__ agg_sum, int* __restrict__ agg_maxb,
    int N, int E)
{
    __shared__ uint32_t smem[192 * 34];
    __shared__ int sh[2];
    const int tid  = threadIdx.x;
    const int lane = tid & 63;
    const int w    = tid >> 6;
    const int l15  = lane & 15;
    const int l4   = lane >> 4;
    const int e0   = blockIdx.x * 192;
    const int e1   = min(e0 + 192, E);
    if (tid == 0) sh[0] = node_of(offs, N, e0);
    if (tid == 1) sh[1] = node_of(offs, N, e1 - 1);

    const int p = e0 + tid;
    const int4 rce = re4[min(p, E - 1)];
    {
        const float2* pa = reinterpret_cast<const float2*>(Pa + (size_t)rce.x * HIDN);
        const float2* pb = reinterpret_cast<const float2*>(Pb + (size_t)rce.y * HIDN);
        float2* dst = reinterpret_cast<float2*>(&smem[tid * 34]);
#pragma unroll
        for (int q = 0; q < 16; ++q) {
            const float2 a = pa[q], b = pb[q];
            dst[q] = make_float2(a.x + b.x, a.y + b.y);
        }
    }

    Frag B1[2][2];
#pragma unroll
    for (int nt = 0; nt < 2; ++nt)
#pragma unroll
        for (int ks = 0; ks < 2; ++ks) {
            const uint4 q = *reinterpret_cast<const uint4*>(
                &PW1[(nt * 16 + l15) * 32 + ks * 16 + l4 * 4]);
            B1[nt][ks].u[0] = q.x; B1[nt][ks].u[1] = q.y;
            B1[nt][ks].u[2] = q.z; B1[nt][ks].u[3] = q.w;
        }
    Frag B2[4];
#pragma unroll
    for (int nt = 0; nt < 4; ++nt) {
        const uint4 q = *reinterpret_cast<const uint4*>(
            &PW2[(nt * 16 + l15) * 16 + l4 * 4]);
        B2[nt].u[0] = q.x; B2[nt].u[1] = q.y;
        B2[nt].u[2] = q.z; B2[nt].u[3] = q.w;
    }

    Frag A1[4][2];
#pragma unroll
    for (int mt = 0; mt < 4; ++mt) {
        const int eix = __shfl(rce.z, mt * 16 + l15, 64);
        const float* rp = ea + (size_t)eix * FN;
#pragma unroll
        for (int ks = 0; ks < 2; ++ks) {
            const float4* gp = reinterpret_cast<const float4*>(rp + ks * 32 + l4 * 8);
            const float4 f0 = gp[0], f1 = gp[1];
            A1[mt][ks].u[0] = packrn(f0.x, f0.y);
            A1[mt][ks].u[1] = packrn(f0.z, f0.w);
            A1[mt][ks].u[2] = packrn(f1.x, f1.y);
            A1[mt][ks].u[3] = packrn(f1.z, f1.w);
        }
    }

    __syncthreads();

    f32x4 acc1[4][2];
    const float* Pl = reinterpret_cast<const float*>(smem);
#pragma unroll
    for (int mt = 0; mt < 4; ++mt)
#pragma unroll
        for (int nt = 0; nt < 2; ++nt)
#pragma unroll
            for (int r = 0; r < 4; ++r) {
                const int et = w * 64 + mt * 16 + l4 * 4 + r;
                acc1[mt][nt][r] = Pl[et * 34 + nt * 16 + l15];
            }
#pragma unroll
    for (int mt = 0; mt < 4; ++mt)
#pragma unroll
        for (int nt = 0; nt < 2; ++nt)
#pragma unroll
            for (int ks = 0; ks < 2; ++ks)
                acc1[mt][nt] = __builtin_amdgcn_mfma_f32_16x16x32_bf16(
                    A1[mt][ks].v, B1[nt][ks].v, acc1[mt][nt], 0, 0, 0);

    __syncthreads();

    float* Hl = reinterpret_cast<float*>(smem);
#pragma unroll
    for (int mt = 0; mt < 4; ++mt)
#pragma unroll
        for (int nt = 0; nt < 2; ++nt)
#pragma unroll
            for (int r = 0; r < 4; ++r) {
                const int et = w * 64 + mt * 16 + l4 * 4 + r;
                Hl[et * 34 + nt * 16 + l15] = fmaxf(acc1[mt][nt][r], 0.0f);
            }
    __syncthreads();

    Frag A2[4];
#pragma unroll
    for (int mt = 0; mt < 4; ++mt) {
        const int et2 = w * 64 + mt * 16 + l15;
        const float* hb = &Hl[et2 * 34 + l4 * 8];
        const float2 g0 = *reinterpret_cast<const float2*>(hb + 0);
        const float2 g1 = *reinterpret_cast<const float2*>(hb + 2);
        const float2 g2 = *reinterpret_cast<const float2*>(hb + 4);
        const float2 g3 = *reinterpret_cast<const float2*>(hb + 6);
        A2[mt].u[0] = packrn(g0.x, g0.y);
        A2[mt].u[1] = packrn(g1.x, g1.y);
        A2[mt].u[2] = packrn(g2.x, g2.y);
        A2[mt].u[3] = packrn(g3.x, g3.y);
    }
    __syncthreads();

    f32x4 acc2[4][4];
#pragma unroll
    for (int mt = 0; mt < 4; ++mt)
#pragma unroll
        for (int nt = 0; nt < 4; ++nt) {
            acc2[mt][nt] = (f32x4){0.f, 0.f, 0.f, 0.f};
            acc2[mt][nt] = __builtin_amdgcn_mfma_f32_16x16x32_bf16(
                A2[mt].v, B2[nt].v, acc2[mt][nt], 0, 0, 0);
        }
    float b2j[4];
#pragma unroll
    for (int nt = 0; nt < 4; ++nt) b2j[nt] = b2[nt * 16 + l15];

#pragma unroll
    for (int mt = 0; mt < 4; ++mt)
#pragma unroll
        for (int nt = 0; nt < 4; ++nt) {
            const int j = nt * 16 + l15;
#pragma unroll
            for (int rp2 = 0; rp2 < 2; ++rp2) {
                const int r  = rp2 * 2;
                const int q2 = (w * 64 + mt * 16 + l4 * 4 + r) >> 1;
                const float v0 = fmaxf(acc2[mt][nt][r]     + b2j[nt], 0.0f);
                const float v1 = fmaxf(acc2[mt][nt][r + 1] + b2j[nt], 0.0f);
                smem[q2 * 64 + (j ^ ((q2 & 3) << 4))] = packrn(v0, v1);
            }
        }
    __syncthreads();

    const int n0 = sh[0], n1 = sh[1];
    for (int n = n0 + w; n <= n1; n += 3) {
        const int s0 = offs[n], t0 = offs[n + 1];
        const int sl = max(s0, e0) - e0, tl = min(t0, e1) - e0;
        float sum = 0.0f, mx = 0.0f;
        int q = sl;
        if (q < tl && (q & 1)) {
            const int q2 = q >> 1;
            const uint32_t wv = smem[q2 * 64 + (lane ^ ((q2 & 3) << 4))];
            const float v = bf16_to_f(wv >> 16);
            sum += v; mx = fmaxf(mx, v); ++q;
        }
        for (; q + 1 < tl; q += 2) {
            const int q2 = q >> 1;
            const uint32_t wv = smem[q2 * 64 + (lane ^ ((q2 & 3) << 4))];
            const float v0 = bf16_to_f(wv & 0xffffu), v1 = bf16_to_f(wv >> 16);
            sum += v0 + v1; mx = fmaxf(mx, fmaxf(v0, v1));
        }
        if (q < tl) {
            const int q2 = q >> 1;
            const uint32_t wv = smem[q2 * 64 + (lane ^ ((q2 & 3) << 4))];
            const float v = bf16_to_f(wv & 0xffffu);
            sum += v; mx = fmaxf(mx, v);
        }
        float* sp = agg_sum  + (size_t)n * FMSG + lane;
        int*   mp = agg_maxb + (size_t)n * FMSG + lane;
        if (s0 >= e0 && t0 <= e1) {
            *sp = sum;
            *mp = __float_as_int(mx);
        } else {
            unsafeAtomicAdd(sp, sum);
            atomicMax(mp, __float_as_int(mx));
        }
    }
}

// ---------------------------------------------------------------------------
// MFMA node kernel: 1 wave = 64 nodes.
//   GEMM1: h = relu( Qc[n] + Qu[batch[n]] + [mean|max] @ W3mm )  K=128
//   GEMM2: out = relu( h @ W4 + b4 )                              [64x32]@[32x128]
// ---------------------------------------------------------------------------
__global__ __launch_bounds__(64) void node_mfma(
    const float* __restrict__ Qc, const float* __restrict__ Qu,
    const int*   __restrict__ batch,
    const uint32_t* __restrict__ PW3, const uint32_t* __restrict__ PW4,
    const float* __restrict__ b4,
    const float* __restrict__ agg_sum, const int* __restrict__ agg_maxb,
    const int*   __restrict__ offs,
    float* __restrict__ out, int N)
{
    __shared__ float Hl[64 * 34];
    const int lane = threadIdx.x;
    const int l15  = lane & 15;
    const int l4   = lane >> 4;
    const int n0   = blockIdx.x * 64;

    // ---- acc1 init = Qc + Qu[batch] (C-layout: row=node, col=j) ----
    f32x4 acc1[4][2];
#pragma unroll
    for (int mt = 0; mt < 4; ++mt)
#pragma unroll
        for (int r = 0; r < 4; ++r) {
            const int nc = min(n0 + mt * 16 + l4 * 4 + r, N - 1);
            const int g  = batch[nc];
#pragma unroll
            for (int nt = 0; nt < 2; ++nt)
                acc1[mt][nt][r] = Qc[(size_t)nc * HIDN + nt * 16 + l15]
                                + Qu[(size_t)g  * HIDN + nt * 16 + l15];
        }

    // ---- per-mt A-row node + inv(deg) ----
    int   arn[4];
    float ainv[4];
#pragma unroll
    for (int mt = 0; mt < 4; ++mt) {
        arn[mt] = min(n0 + mt * 16 + l15, N - 1);
        const int deg = offs[arn[mt] + 1] - offs[arn[mt]];
        ainv[mt] = (deg > 0) ? 1.0f / (float)deg : 0.0f;
    }

    // ---- B3 fragments ----
    Frag B3[2][4];
#pragma unroll
    for (int nt = 0; nt < 2; ++nt)
#pragma unroll
        for (int ks = 0; ks < 4; ++ks) {
            const uint4 q = *reinterpret_cast<const uint4*>(
                &PW3[(nt * 16 + l15) * 64 + ks * 16 + l4 * 4]);
            B3[nt][ks].u[0] = q.x; B3[nt][ks].u[1] = q.y;
            B3[nt][ks].u[2] = q.z; B3[nt][ks].u[3] = q.w;
        }

    // ---- GEMM1 over K=128: ks 0..1 mean (scaled), ks 2..3 max ----
#pragma unroll
    for (int ks = 0; ks < 4; ++ks) {
        Frag A[4];
        if (ks < 2) {
#pragma unroll
            for (int mt = 0; mt < 4; ++mt) {
                const float4* gp = reinterpret_cast<const float4*>(
                    agg_sum + (size_t)arn[mt] * FMSG + ks * 32 + l4 * 8);
                const float4 f0 = gp[0], f1 = gp[1];
                const float s = ainv[mt];
                A[mt].u[0] = packrn(f0.x * s, f0.y * s);
                A[mt].u[1] = packrn(f0.z * s, f0.w * s);
                A[mt].u[2] = packrn(f1.x * s, f1.y * s);
                A[mt].u[3] = packrn(f1.z * s, f1.w * s);
            }
        } else {
#pragma unroll
            for (int mt = 0; mt < 4; ++mt) {
                const uint4* gp = reinterpret_cast<const uint4*>(
                    agg_maxb + (size_t)arn[mt] * FMSG + (ks - 2) * 32 + l4 * 8);
                const uint4 u0 = gp[0], u1 = gp[1];
                A[mt].u[0] = packrn(__uint_as_float(u0.x), __uint_as_float(u0.y));
                A[mt].u[1] = packrn(__uint_as_float(u0.z), __uint_as_float(u0.w));
                A[mt].u[2] = packrn(__uint_as_float(u1.x), __uint_as_float(u1.y));
                A[mt].u[3] = packrn(__uint_as_float(u1.z), __uint_as_float(u1.w));
            }
        }
#pragma unroll
        for (int mt = 0; mt < 4; ++mt)
#pragma unroll
            for (int nt = 0; nt < 2; ++nt)
                acc1[mt][nt] = __builtin_amdgcn_mfma_f32_16x16x32_bf16(
                    A[mt].v, B3[nt][ks].v, acc1[mt][nt], 0, 0, 0);
    }

    // ---- h -> LDS (transpose node<->feature), relu ----
#pragma unroll
    for (int mt = 0; mt < 4; ++mt)
#pragma unroll
        for (int nt = 0; nt < 2; ++nt)
#pragma unroll
            for (int r = 0; r < 4; ++r) {
                const int rw = mt * 16 + l4 * 4 + r;
                Hl[rw * 34 + nt * 16 + l15] = fmaxf(acc1[mt][nt][r], 0.0f);
            }
    __syncthreads();

    Frag A2[4];
#pragma unroll
    for (int mt = 0; mt < 4; ++mt) {
        const float* hb = &Hl[(mt * 16 + l15) * 34 + l4 * 8];
        const float2 g0 = *reinterpret_cast<const float2*>(hb + 0);
        const float2 g1 = *reinterpret_cast<const float2*>(hb + 2);
        const float2 g2 = *reinterpret_cast<const float2*>(hb + 4);
        const float2 g3 = *reinterpret_cast<const float2*>(hb + 6);
        A2[mt].u[0] = packrn(g0.x, g0.y);
        A2[mt].u[1] = packrn(g1.x, g1.y);
        A2[mt].u[2] = packrn(g2.x, g2.y);
        A2[mt].u[3] = packrn(g3.x, g3.y);
    }

    // ---- GEMM2 per nt (acc live range = 16 regs) + store ----
#pragma unroll
    for (int nt = 0; nt < 8; ++nt) {
        Frag B4f;
        const uint4 q = *reinterpret_cast<const uint4*>(
            &PW4[(nt * 16 + l15) * 16 + l4 * 4]);
        B4f.u[0] = q.x; B4f.u[1] = q.y; B4f.u[2] = q.z; B4f.u[3] = q.w;
        const float b4v = b4[nt * 16 + l15];
        f32x4 t[4];
#pragma unroll
        for (int mt = 0; mt < 4; ++mt) {
            t[mt] = (f32x4){0.f, 0.f, 0.f, 0.f};
            t[mt] = __builtin_amdgcn_mfma_f32_16x16x32_bf16(
                A2[mt].v, B4f.v, t[mt], 0, 0, 0);
        }
#pragma unroll
        for (int mt = 0; mt < 4; ++mt)
#pragma unroll
            for (int r = 0; r < 4; ++r) {
                const int node = n0 + mt * 16 + l4 * 4 + r;
                if (node < N)
                    out[(size_t)node * FOUT + nt * 16 + l15] =
                        fmaxf(t[mt][r] + b4v, 0.0f);
            }
    }
}

// ===========================================================================
extern "C" void kernel_launch(void* const* d_in, const int* in_sizes, int n_in,
                              void* d_out, int out_size, void* d_ws, size_t ws_size,
                              hipStream_t stream)
{
    const float* x     = (const float*)d_in[0];
    const int*   ei    = (const int*)  d_in[1];
    const float* ea    = (const float*)d_in[2];
    const float* u     = (const float*)d_in[3];
    const int*   batch = (const int*)  d_in[4];
    const float* W1    = (const float*)d_in[5];
    const float* b1    = (const float*)d_in[6];
    const float* W2    = (const float*)d_in[7];
    const float* b2    = (const float*)d_in[8];
    const float* W3    = (const float*)d_in[9];
    const float* b3    = (const float*)d_in[10];
    const float* W4    = (const float*)d_in[11];
    const float* b4    = (const float*)d_in[12];
    float* out = (float*)d_out;

    const int N = in_sizes[0] / FN;   // 50000
    const int E = in_sizes[1] / 2;    // 800000
    const int G = in_sizes[3] / FN;   // 64

    char* wp = (char*)d_ws;
    auto take = [&](size_t bytes) -> void* {
        void* r = (void*)wp;
        wp += (bytes + 255) & ~(size_t)255;
        return r;
    };
    float*    agg_sum  = (float*)   take((size_t)N * FMSG * 4);
    int*      agg_maxb = (int*)     take((size_t)N * FMSG * 4);
    int*      cnt      = (int*)     take((size_t)N * 4);
    char*     zero_end = wp;                       // zero span: agg_sum..cnt
    int*      offs     = (int*)     take(((size_t)N + 1) * 4);
    int*      rank     = (int*)     take((size_t)E * 4);
    int4*     re4      = (int4*)    take((size_t)E * 16);
    float*    Pa       = (float*)   take((size_t)N * HIDN * 4);
    float*    Pb       = (float*)   take((size_t)N * HIDN * 4);
    float*    Qc       = (float*)   take((size_t)N * HIDN * 4);
    float*    Qu       = (float*)   take((size_t)G * HIDN * 4);
    uint32_t* PW1      = (uint32_t*)take(1024 * 4);
    uint32_t* PW2      = (uint32_t*)take(1024 * 4);
    uint32_t* PW3      = (uint32_t*)take(2048 * 4);
    uint32_t* PW4      = (uint32_t*)take(2048 * 4);
    int*      part     = (int*)     take(64 * 4);
    int*      partx    = (int*)     take(64 * 4);

    hipMemsetAsync(agg_sum, 0, (size_t)(zero_end - (char*)agg_sum), stream);

    const int BH = (E / 4 + 255) / 256;            // hist blocks
    const int BP = (N + 255) / 256;                // node_pre blocks
    const int NB = (N + 2047) / 2048;              // scan blocks

    prep_kernel   <<<BH + BP + 1, 256, 0, stream>>>(
        ei, cnt, rank, x, u, W1, b1, W2, W3, b3, W4,
        Pa, Pb, Qc, Qu, PW1, PW2, PW3, PW4, E, N, G, BH, BP);
    scanA_kernel  <<<NB, 256, 0, stream>>>(cnt, part, N);
    scanB_kernel  <<<1, 64, 0, stream>>>(part, partx, offs, NB, N);
    scanC_kernel  <<<NB, 256, 0, stream>>>(cnt, partx, offs, N);
    scatter_kernel<<<(E + 255) / 256, 256, 0, stream>>>(ei, offs, rank, re4, E);
    fused_edge_mfma<<<(E + 191) / 192, 192, 0, stream>>>(
        ea, PW1, PW2, b2, Pa, Pb, re4, offs, agg_sum, agg_maxb, N, E);
    node_mfma     <<<(N + 63) / 64, 64, 0, stream>>>(
        Qc, Qu, batch, PW3, PW4, b4, agg_sum, agg_maxb, offs, out, N);
}

// Round 7
// 237.436 us; speedup vs baseline: 20.4754x; 1.1487x over previous
//
#include <hip/hip_runtime.h>
#include <hip/hip_bf16.h>
#include <stdint.h>

constexpr int FN   = 64;
constexpr int HIDN = 32;
constexpr int FMSG = 64;
constexpr int FOUT = 128;

using short8 = __attribute__((ext_vector_type(8))) short;
using f32x4  = __attribute__((ext_vector_type(4))) float;

union Frag { short8 v; uint32_t u[4]; };

__device__ __forceinline__ uint32_t packrn(float a, float b) {
    union { __hip_bfloat162 h; uint32_t u; } cv;
    cv.h = __float22bfloat162_rn(make_float2(a, b));   // v_cvt_pk_bf16_f32
    return cv.u;
}
__device__ __forceinline__ float bf16_to_f(uint32_t h16) {
    return __uint_as_float(h16 << 16);
}

__device__ __forceinline__ int node_of(const int* __restrict__ offs, int N, int target) {
    int l = 0, r = N + 1;
    while (l + 1 < r) {
        const int m = (l + r) >> 1;
        if (offs[m] <= target) l = m; else r = m;
    }
    return l;
}

// ---------------------------------------------------------------------------
// prep: [0,BH) hist+rank | [BH,BH+BP) node_pre (Pa,Pb,Qc) | [BH+BP] pack + Qu
// ---------------------------------------------------------------------------
__global__ __launch_bounds__(256) void prep_kernel(
    const int* __restrict__ ei, int* __restrict__ cnt, int* __restrict__ rank,
    const float* __restrict__ x, const float* __restrict__ u,
    const float* __restrict__ W1, const float* __restrict__ b1,
    const float* __restrict__ W2,
    const float* __restrict__ W3, const float* __restrict__ b3,
    const float* __restrict__ W4,
    float* __restrict__ Pa, float* __restrict__ Pb, float* __restrict__ Qc,
    float* __restrict__ Qu,
    uint32_t* __restrict__ PW1, uint32_t* __restrict__ PW2,
    uint32_t* __restrict__ PW3, uint32_t* __restrict__ PW4,
    int E, int N, int G, int BH, int BP)
{
    const int b   = blockIdx.x;
    const int tid = threadIdx.x;

    if (b < BH) {
        const int e4 = (b * 256 + tid) * 4;
        if (e4 + 3 < E) {
            const int4 c = *reinterpret_cast<const int4*>(ei + E + e4);
            int4 r;
            r.x = atomicAdd(cnt + c.x, 1);
            r.y = atomicAdd(cnt + c.y, 1);
            r.z = atomicAdd(cnt + c.z, 1);
            r.w = atomicAdd(cnt + c.w, 1);
            *reinterpret_cast<int4*>(rank + e4) = r;
        } else {
            for (int e = e4; e < E; ++e) rank[e] = atomicAdd(cnt + ei[E + e], 1);
        }
        return;
    }
    if (b < BH + BP) {
        const int n = (b - BH) * 256 + tid;
        if (n >= N) return;
        float a[HIDN], bq[HIDN], c[HIDN];
#pragma unroll
        for (int j = 0; j < HIDN; ++j) { a[j] = b1[j]; bq[j] = 0.0f; c[j] = b3[j]; }
        const float* xr = x + (size_t)n * FN;
        const float* WA = W1;
        const float* WB = W1 + FN * HIDN;
        const float* WX = W3;                   // rows 0..63 of W3
#pragma unroll 2
        for (int k = 0; k < FN; k += 4) {
            const float4 v = *reinterpret_cast<const float4*>(xr + k);
            const float* wa = WA + k * HIDN;
            const float* wb = WB + k * HIDN;
            const float* wc = WX + k * HIDN;
#pragma unroll
            for (int j = 0; j < HIDN; ++j) {
                float aj = a[j], bj = bq[j], cj = c[j];
                aj = fmaf(v.x, wa[j], aj);            bj = fmaf(v.x, wb[j], bj);            cj = fmaf(v.x, wc[j], cj);
                aj = fmaf(v.y, wa[HIDN + j], aj);     bj = fmaf(v.y, wb[HIDN + j], bj);     cj = fmaf(v.y, wc[HIDN + j], cj);
                aj = fmaf(v.z, wa[2 * HIDN + j], aj); bj = fmaf(v.z, wb[2 * HIDN + j], bj); cj = fmaf(v.z, wc[2 * HIDN + j], cj);
                aj = fmaf(v.w, wa[3 * HIDN + j], aj); bj = fmaf(v.w, wb[3 * HIDN + j], bj); cj = fmaf(v.w, wc[3 * HIDN + j], cj);
                a[j] = aj; bq[j] = bj; c[j] = cj;
            }
        }
        float4* pa = reinterpret_cast<float4*>(Pa + (size_t)n * HIDN);
        float4* pb = reinterpret_cast<float4*>(Pb + (size_t)n * HIDN);
        float4* qc = reinterpret_cast<float4*>(Qc + (size_t)n * HIDN);
#pragma unroll
        for (int q = 0; q < HIDN / 4; ++q) {
            pa[q] = make_float4(a[4*q], a[4*q+1], a[4*q+2], a[4*q+3]);
            pb[q] = make_float4(bq[4*q], bq[4*q+1], bq[4*q+2], bq[4*q+3]);
            qc[q] = make_float4(c[4*q], c[4*q+1], c[4*q+2], c[4*q+3]);
        }
        return;
    }
    // ---- pack weights + Qu = u@W3d (per graph) ----
    const float* WC = W1 + 2 * FN * HIDN;
    for (int i = tid; i < 1024; i += 256) {          // PW1[j<32][k2<32]
        const int j = i >> 5, k2 = i & 31;
        PW1[i] = packrn(WC[(2 * k2) * HIDN + j], WC[(2 * k2 + 1) * HIDN + j]);
    }
    for (int i = tid; i < 1024; i += 256) {          // PW2[j<64][k2<16]
        const int j = i >> 4, k2 = i & 15;
        PW2[i] = packrn(W2[(2 * k2) * FMSG + j], W2[(2 * k2 + 1) * FMSG + j]);
    }
    const float* W3m = W3 + 64 * HIDN;               // rows 64..191 (mean|max)
    for (int i = tid; i < 2048; i += 256) {          // PW3[j<32][k2<64]
        const int j = i >> 6, k2 = i & 63;
        PW3[i] = packrn(W3m[(2 * k2) * HIDN + j], W3m[(2 * k2 + 1) * HIDN + j]);
    }
    for (int i = tid; i < 2048; i += 256) {          // PW4[j<128][k2<16]
        const int j = i >> 4, k2 = i & 15;
        PW4[i] = packrn(W4[(2 * k2) * FOUT + j], W4[(2 * k2 + 1) * FOUT + j]);
    }
    const float* W3u = W3 + 192 * HIDN;              // rows 192..255 (u part)
    for (int i = tid; i < G * HIDN; i += 256) {      // Qu[g][j]
        const int g = i >> 5, j = i & 31;
        const float* ur = u + (size_t)g * FN;
        float acc = 0.0f;
#pragma unroll 8
        for (int k = 0; k < FN; ++k) acc = fmaf(ur[k], W3u[k * HIDN + j], acc);
        Qu[i] = acc;
    }
}

// ---------------------------------------------------------------------------
// Multi-block scan over cnt[N] -> offs[N+1]
// ---------------------------------------------------------------------------
__global__ __launch_bounds__(256) void scanA_kernel(
    const int* __restrict__ cnt, int* __restrict__ part, int N)
{
    __shared__ int red[256];
    const int tid  = threadIdx.x;
    const int base = blockIdx.x * 2048 + tid * 8;
    int s = 0;
    if (base + 8 <= N) {
        const int4 a = *reinterpret_cast<const int4*>(cnt + base);
        const int4 b = *reinterpret_cast<const int4*>(cnt + base + 4);
        s = a.x + a.y + a.z + a.w + b.x + b.y + b.z + b.w;
    } else {
        for (int i = base; i < min(base + 8, N); ++i) s += cnt[i];
    }
    red[tid] = s;
    __syncthreads();
    for (int d = 128; d > 0; d >>= 1) {
        if (tid < d) red[tid] += red[tid + d];
        __syncthreads();
    }
    if (tid == 0) part[blockIdx.x] = red[0];
}

__global__ __launch_bounds__(64) void scanB_kernel(
    const int* __restrict__ part, int* __restrict__ partx,
    int* __restrict__ offs, int NB, int N)
{
    if (threadIdx.x == 0) {
        int run = 0;
        for (int i = 0; i < NB; ++i) { partx[i] = run; run += part[i]; }
        offs[N] = run;
    }
}

__global__ __launch_bounds__(256) void scanC_kernel(
    const int* __restrict__ cnt, const int* __restrict__ partx,
    int* __restrict__ offs, int N)
{
    __shared__ int sb[256];
    const int tid  = threadIdx.x;
    const int base = blockIdx.x * 2048 + tid * 8;
    int v[8];
    int tsum = 0;
#pragma unroll
    for (int q = 0; q < 8; ++q) {
        const int i = base + q;
        v[q] = (i < N) ? cnt[i] : 0;
        tsum += v[q];
    }
    sb[tid] = tsum;
    __syncthreads();
    for (int d = 1; d < 256; d <<= 1) {
        const int t = (tid >= d) ? sb[tid - d] : 0;
        __syncthreads();
        sb[tid] += t;
        __syncthreads();
    }
    int run = partx[blockIdx.x] + sb[tid] - tsum;
#pragma unroll
    for (int q = 0; q < 8; ++q) {
        const int i = base + q;
        if (i < N) offs[i] = run;
        run += v[q];
    }
}

// ---------------------------------------------------------------------------
// scatter (blocks [0,SB)) + ntile builder (blocks [SB, SB+TB))
// ntile[t] = (node containing edge t*64, node containing edge min(t*64+63,E-1))
// ---------------------------------------------------------------------------
__global__ __launch_bounds__(256) void scatter_ntile_kernel(
    const int* __restrict__ ei, const int* __restrict__ offs,
    const int* __restrict__ rank, int4* __restrict__ re4,
    int2* __restrict__ ntile, int E, int N, int NT, int SB)
{
    const int tid = threadIdx.x;
    if ((int)blockIdx.x < SB) {
        const int e = blockIdx.x * 256 + tid;
        if (e >= E) return;
        const int row = ei[e];
        const int col = ei[E + e];
        const int pos = offs[col] + rank[e];
        re4[pos] = make_int4(row, col, e, 0);
    } else {
        const int t = ((int)blockIdx.x - SB) * 256 + tid;
        if (t >= NT) return;
        const int a = node_of(offs, N, t * 64);
        const int b = node_of(offs, N, min(t * 64 + 63, E - 1));
        ntile[t] = make_int2(a, b);
    }
}

// ---------------------------------------------------------------------------
// Barrier-free MFMA fused edge kernel: 1 wave = 64 sorted edges.
// All LDS traffic stays within the wave's private 8.7 KB slice -> no
// __syncthreads anywhere; waves free-run (latency overlap across 18 waves/CU).
// ---------------------------------------------------------------------------
__global__ __launch_bounds__(128) void fused_edge_mfma(
    const float* __restrict__ ea,
    const uint32_t* __restrict__ PW1, const uint32_t* __restrict__ PW2,
    const float* __restrict__ b2,
    const float* __restrict__ Pa, const float* __restrict__ Pb,
    const int4* __restrict__ re4, const int* __restrict__ offs,
    const int2* __restrict__ ntile,
    float* __restrict__ agg_sum, int* __restrict__ agg_maxb,
    int N, int E, int NT)
{
    __shared__ uint32_t smem_all[2 * 64 * 34];
    const int w    = threadIdx.x >> 6;
    const int t    = blockIdx.x * 2 + w;
    if (t >= NT) return;
    uint32_t* smem = smem_all + w * (64 * 34);
    const int lane = threadIdx.x & 63;
    const int l15  = lane & 15;
    const int l4   = lane >> 4;
    const int e0   = t * 64;
    const int e1   = min(e0 + 64, E);
    const int2 nrange = ntile[t];

    // ---- Ppair = Pa[row]+Pb[col] -> own LDS row (f32, stride 34) ----
    const int p = e0 + lane;
    const int4 rce = re4[min(p, E - 1)];
    {
        const float2* pa = reinterpret_cast<const float2*>(Pa + (size_t)rce.x * HIDN);
        const float2* pb = reinterpret_cast<const float2*>(Pb + (size_t)rce.y * HIDN);
        float2* dst = reinterpret_cast<float2*>(&smem[lane * 34]);
#pragma unroll
        for (int q = 0; q < 16; ++q) {
            const float2 a = pa[q], b = pb[q];
            dst[q] = make_float2(a.x + b.x, a.y + b.y);
        }
    }

    // ---- B fragments (pre-packed) ----
    Frag B1[2][2];
#pragma unroll
    for (int nt = 0; nt < 2; ++nt)
#pragma unroll
        for (int ks = 0; ks < 2; ++ks) {
            const uint4 q = *reinterpret_cast<const uint4*>(
                &PW1[(nt * 16 + l15) * 32 + ks * 16 + l4 * 4]);
            B1[nt][ks].u[0] = q.x; B1[nt][ks].u[1] = q.y;
            B1[nt][ks].u[2] = q.z; B1[nt][ks].u[3] = q.w;
        }
    Frag B2f[4];
#pragma unroll
    for (int nt = 0; nt < 4; ++nt) {
        const uint4 q = *reinterpret_cast<const uint4*>(
            &PW2[(nt * 16 + l15) * 16 + l4 * 4]);
        B2f[nt].u[0] = q.x; B2f[nt].u[1] = q.y;
        B2f[nt].u[2] = q.z; B2f[nt].u[3] = q.w;
    }

    // ---- A1: gather ea rows (bf16) ----
    Frag A1[4][2];
#pragma unroll
    for (int mt = 0; mt < 4; ++mt) {
        const int eix = __shfl(rce.z, mt * 16 + l15, 64);
        const float* rp = ea + (size_t)eix * FN;
#pragma unroll
        for (int ks = 0; ks < 2; ++ks) {
            const float4* gp = reinterpret_cast<const float4*>(rp + ks * 32 + l4 * 8);
            const float4 f0 = gp[0], f1 = gp[1];
            A1[mt][ks].u[0] = packrn(f0.x, f0.y);
            A1[mt][ks].u[1] = packrn(f0.z, f0.w);
            A1[mt][ks].u[2] = packrn(f1.x, f1.y);
            A1[mt][ks].u[3] = packrn(f1.z, f1.w);
        }
    }

    // ---- acc1 init = Ppair (wave-local LDS transpose; compiler lgkmcnt) ----
    f32x4 acc1[4][2];
    const float* Pl = reinterpret_cast<const float*>(smem);
#pragma unroll
    for (int mt = 0; mt < 4; ++mt)
#pragma unroll
        for (int nt = 0; nt < 2; ++nt)
#pragma unroll
            for (int r = 0; r < 4; ++r) {
                const int et = mt * 16 + l4 * 4 + r;
                acc1[mt][nt][r] = Pl[et * 34 + nt * 16 + l15];
            }
#pragma unroll
    for (int mt = 0; mt < 4; ++mt)
#pragma unroll
        for (int nt = 0; nt < 2; ++nt)
#pragma unroll
            for (int ks = 0; ks < 2; ++ks)
                acc1[mt][nt] = __builtin_amdgcn_mfma_f32_16x16x32_bf16(
                    A1[mt][ks].v, B1[nt][ks].v, acc1[mt][nt], 0, 0, 0);

    // ---- h -> LDS (reuse region; wave-local WAR is in-order in DS pipe) ----
    float* Hl = reinterpret_cast<float*>(smem);
#pragma unroll
    for (int mt = 0; mt < 4; ++mt)
#pragma unroll
        for (int nt = 0; nt < 2; ++nt)
#pragma unroll
            for (int r = 0; r < 4; ++r) {
                const int et = mt * 16 + l4 * 4 + r;
                Hl[et * 34 + nt * 16 + l15] = fmaxf(acc1[mt][nt][r], 0.0f);
            }

    // ---- A2 from h (transpose read) ----
    Frag A2[4];
#pragma unroll
    for (int mt = 0; mt < 4; ++mt) {
        const float* hb = &Hl[(mt * 16 + l15) * 34 + l4 * 8];
        const float2 g0 = *reinterpret_cast<const float2*>(hb + 0);
        const float2 g1 = *reinterpret_cast<const float2*>(hb + 2);
        const float2 g2 = *reinterpret_cast<const float2*>(hb + 4);
        const float2 g3 = *reinterpret_cast<const float2*>(hb + 6);
        A2[mt].u[0] = packrn(g0.x, g0.y);
        A2[mt].u[1] = packrn(g1.x, g1.y);
        A2[mt].u[2] = packrn(g2.x, g2.y);
        A2[mt].u[3] = packrn(g3.x, g3.y);
    }

    // ---- GEMM2 per nt + immediate msg store (bf16 pairs along edge dim) ----
    // swizzle: col = j ^ (((q2>>1)&1)<<4) -> l4 parity lands in bank bit 4.
#pragma unroll
    for (int nt = 0; nt < 4; ++nt) {
        const float b2v = b2[nt * 16 + l15];
        f32x4 a2c[4];
#pragma unroll
        for (int mt = 0; mt < 4; ++mt) {
            a2c[mt] = (f32x4){0.f, 0.f, 0.f, 0.f};
            a2c[mt] = __builtin_amdgcn_mfma_f32_16x16x32_bf16(
                A2[mt].v, B2f[nt].v, a2c[mt], 0, 0, 0);
        }
        const int j = nt * 16 + l15;
#pragma unroll
        for (int mt = 0; mt < 4; ++mt)
#pragma unroll
            for (int rp2 = 0; rp2 < 2; ++rp2) {
                const int q2 = mt * 8 + l4 * 2 + rp2;
                const float v0 = fmaxf(a2c[mt][rp2 * 2]     + b2v, 0.0f);
                const float v1 = fmaxf(a2c[mt][rp2 * 2 + 1] + b2v, 0.0f);
                smem[q2 * 64 + (j ^ (((q2 >> 1) & 1) << 4))] = packrn(v0, v1);
            }
    }

    // ---- segmented mean/max over this wave's 64 edges (lane = feature) ----
    const int n0 = nrange.x, n1 = nrange.y;
    for (int n = n0; n <= n1; ++n) {
        const int s0 = offs[n], t0 = offs[n + 1];
        const int sl = max(s0, e0) - e0, tl = min(t0, e1) - e0;
        float sum = 0.0f, mx = 0.0f;
        int q = sl;
        if (q < tl && (q & 1)) {
            const int q2 = q >> 1;
            const uint32_t wv = smem[q2 * 64 + (lane ^ (((q2 >> 1) & 1) << 4))];
            const float v = bf16_to_f(wv >> 16);
            sum += v; mx = fmaxf(mx, v); ++q;
        }
        for (; q + 1 < tl; q += 2) {
            const int q2 = q >> 1;
            const uint32_t wv = smem[q2 * 64 + (lane ^ (((q2 >> 1) & 1) << 4))];
            const float v0 = bf16_to_f(wv & 0xffffu), v1 = bf16_to_f(wv >> 16);
            sum += v0 + v1; mx = fmaxf(mx, fmaxf(v0, v1));
        }
        if (q < tl) {
            const int q2 = q >> 1;
            const uint32_t wv = smem[q2 * 64 + (lane ^ (((q2 >> 1) & 1) << 4))];
            const float v = bf16_to_f(wv & 0xffffu);
            sum += v; mx = fmaxf(mx, v);
        }
        float* sp = agg_sum  + (size_t)n * FMSG + lane;
        int*   mp = agg_maxb + (size_t)n * FMSG + lane;
        if (s0 >= e0 && t0 <= e1) {
            *sp = sum;
            *mp = __float_as_int(mx);
        } else {
            unsafeAtomicAdd(sp, sum);
            atomicMax(mp, __float_as_int(mx));
        }
    }
}

// ---------------------------------------------------------------------------
// Barrier-free MFMA node kernel: 1 wave = 32 nodes, 4 waves/block.
// ---------------------------------------------------------------------------
__global__ __launch_bounds__(256) void node_mfma(
    const float* __restrict__ Qc, const float* __restrict__ Qu,
    const int*   __restrict__ batch,
    const uint32_t* __restrict__ PW3, const uint32_t* __restrict__ PW4,
    const float* __restrict__ b4,
    const float* __restrict__ agg_sum, const int* __restrict__ agg_maxb,
    const int*   __restrict__ offs,
    float* __restrict__ out, int N)
{
    __shared__ float Hl_all[4 * 32 * 34];
    const int w    = threadIdx.x >> 6;
    float* Hl      = Hl_all + w * (32 * 34);
    const int lane = threadIdx.x & 63;
    const int l15  = lane & 15;
    const int l4   = lane >> 4;
    const int n0   = blockIdx.x * 128 + w * 32;
    if (n0 >= N) return;

    // ---- acc1 init = Qc + Qu[batch] ----
    f32x4 acc1[2][2];
#pragma unroll
    for (int mt = 0; mt < 2; ++mt)
#pragma unroll
        for (int r = 0; r < 4; ++r) {
            const int nc = min(n0 + mt * 16 + l4 * 4 + r, N - 1);
            const int g  = batch[nc];
#pragma unroll
            for (int nt = 0; nt < 2; ++nt)
                acc1[mt][nt][r] = Qc[(size_t)nc * HIDN + nt * 16 + l15]
                                + Qu[(size_t)g  * HIDN + nt * 16 + l15];
        }

    int   arn[2];
    float ainv[2];
#pragma unroll
    for (int mt = 0; mt < 2; ++mt) {
        arn[mt] = min(n0 + mt * 16 + l15, N - 1);
        const int deg = offs[arn[mt] + 1] - offs[arn[mt]];
        ainv[mt] = (deg > 0) ? 1.0f / (float)deg : 0.0f;
    }

    Frag B3[2][4];
#pragma unroll
    for (int nt = 0; nt < 2; ++nt)
#pragma unroll
        for (int ks = 0; ks < 4; ++ks) {
            const uint4 q = *reinterpret_cast<const uint4*>(
                &PW3[(nt * 16 + l15) * 64 + ks * 16 + l4 * 4]);
            B3[nt][ks].u[0] = q.x; B3[nt][ks].u[1] = q.y;
            B3[nt][ks].u[2] = q.z; B3[nt][ks].u[3] = q.w;
        }

    // ---- GEMM1 over K=128: ks 0..1 mean (scaled), ks 2..3 max ----
#pragma unroll
    for (int ks = 0; ks < 4; ++ks) {
        Frag A[2];
        if (ks < 2) {
#pragma unroll
            for (int mt = 0; mt < 2; ++mt) {
                const float4* gp = reinterpret_cast<const float4*>(
                    agg_sum + (size_t)arn[mt] * FMSG + ks * 32 + l4 * 8);
                const float4 f0 = gp[0], f1 = gp[1];
                const float s = ainv[mt];
                A[mt].u[0] = packrn(f0.x * s, f0.y * s);
                A[mt].u[1] = packrn(f0.z * s, f0.w * s);
                A[mt].u[2] = packrn(f1.x * s, f1.y * s);
                A[mt].u[3] = packrn(f1.z * s, f1.w * s);
            }
        } else {
#pragma unroll
            for (int mt = 0; mt < 2; ++mt) {
                const uint4* gp = reinterpret_cast<const uint4*>(
                    agg_maxb + (size_t)arn[mt] * FMSG + (ks - 2) * 32 + l4 * 8);
                const uint4 u0 = gp[0], u1 = gp[1];
                A[mt].u[0] = packrn(__uint_as_float(u0.x), __uint_as_float(u0.y));
                A[mt].u[1] = packrn(__uint_as_float(u0.z), __uint_as_float(u0.w));
                A[mt].u[2] = packrn(__uint_as_float(u1.x), __uint_as_float(u1.y));
                A[mt].u[3] = packrn(__uint_as_float(u1.z), __uint_as_float(u1.w));
            }
        }
#pragma unroll
        for (int mt = 0; mt < 2; ++mt)
#pragma unroll
            for (int nt = 0; nt < 2; ++nt)
                acc1[mt][nt] = __builtin_amdgcn_mfma_f32_16x16x32_bf16(
                    A[mt].v, B3[nt][ks].v, acc1[mt][nt], 0, 0, 0);
    }

    // ---- h -> LDS (wave-local transpose), relu ----
#pragma unroll
    for (int mt = 0; mt < 2; ++mt)
#pragma unroll
        for (int nt = 0; nt < 2; ++nt)
#pragma unroll
            for (int r = 0; r < 4; ++r) {
                const int rw = mt * 16 + l4 * 4 + r;
                Hl[rw * 34 + nt * 16 + l15] = fmaxf(acc1[mt][nt][r], 0.0f);
            }

    Frag A2[2];
#pragma unroll
    for (int mt = 0; mt < 2; ++mt) {
        const float* hb = &Hl[(mt * 16 + l15) * 34 + l4 * 8];
        const float2 g0 = *reinterpret_cast<const float2*>(hb + 0);
        const float2 g1 = *reinterpret_cast<const float2*>(hb + 2);
        const float2 g2 = *reinterpret_cast<const float2*>(hb + 4);
        const float2 g3 = *reinterpret_cast<const float2*>(hb + 6);
        A2[mt].u[0] = packrn(g0.x, g0.y);
        A2[mt].u[1] = packrn(g1.x, g1.y);
        A2[mt].u[2] = packrn(g2.x, g2.y);
        A2[mt].u[3] = packrn(g3.x, g3.y);
    }

    // ---- GEMM2 per nt + store ----
#pragma unroll
    for (int nt = 0; nt < 8; ++nt) {
        Frag B4f;
        const uint4 q = *reinterpret_cast<const uint4*>(
            &PW4[(nt * 16 + l15) * 16 + l4 * 4]);
        B4f.u[0] = q.x; B4f.u[1] = q.y; B4f.u[2] = q.z; B4f.u[3] = q.w;
        const float b4v = b4[nt * 16 + l15];
        f32x4 tacc[2];
#pragma unroll
        for (int mt = 0; mt < 2; ++mt) {
            tacc[mt] = (f32x4){0.f, 0.f, 0.f, 0.f};
            tacc[mt] = __builtin_amdgcn_mfma_f32_16x16x32_bf16(
                A2[mt].v, B4f.v, tacc[mt], 0, 0, 0);
        }
#pragma unroll
        for (int mt = 0; mt < 2; ++mt)
#pragma unroll
            for (int r = 0; r < 4; ++r) {
                const int node = n0 + mt * 16 + l4 * 4 + r;
                if (node < N)
                    out[(size_t)node * FOUT + nt * 16 + l15] =
                        fmaxf(tacc[mt][r] + b4v, 0.0f);
            }
    }
}

// ===========================================================================
extern "C" void kernel_launch(void* const* d_in, const int* in_sizes, int n_in,
                              void* d_out, int out_size, void* d_ws, size_t ws_size,
                              hipStream_t stream)
{
    const float* x     = (const float*)d_in[0];
    const int*   ei    = (const int*)  d_in[1];
    const float* ea    = (const float*)d_in[2];
    const float* u     = (const float*)d_in[3];
    const int*   batch = (const int*)  d_in[4];
    const float* W1    = (const float*)d_in[5];
    const float* b1    = (const float*)d_in[6];
    const float* W2    = (const float*)d_in[7];
    const float* b2    = (const float*)d_in[8];
    const float* W3    = (const float*)d_in[9];
    const float* b3    = (const float*)d_in[10];
    const float* W4    = (const float*)d_in[11];
    const float* b4    = (const float*)d_in[12];
    float* out = (float*)d_out;

    const int N = in_sizes[0] / FN;   // 50000
    const int E = in_sizes[1] / 2;    // 800000
    const int G = in_sizes[3] / FN;   // 64
    const int NT = (E + 63) / 64;     // 64-edge tiles

    char* wp = (char*)d_ws;
    auto take = [&](size_t bytes) -> void* {
        void* r = (void*)wp;
        wp += (bytes + 255) & ~(size_t)255;
        return r;
    };
    float*    agg_sum  = (float*)   take((size_t)N * FMSG * 4);
    int*      agg_maxb = (int*)     take((size_t)N * FMSG * 4);
    int*      cnt      = (int*)     take((size_t)N * 4);
    char*     zero_end = wp;                       // zero span: agg_sum..cnt
    int*      offs     = (int*)     take(((size_t)N + 1) * 4);
    int*      rank     = (int*)     take((size_t)E * 4);
    int4*     re4      = (int4*)    take((size_t)E * 16);
    int2*     ntile    = (int2*)    take((size_t)NT * 8);
    float*    Pa       = (float*)   take((size_t)N * HIDN * 4);
    float*    Pb       = (float*)   take((size_t)N * HIDN * 4);
    float*    Qc       = (float*)   take((size_t)N * HIDN * 4);
    float*    Qu       = (float*)   take((size_t)G * HIDN * 4);
    uint32_t* PW1      = (uint32_t*)take(1024 * 4);
    uint32_t* PW2      = (uint32_t*)take(1024 * 4);
    uint32_t* PW3      = (uint32_t*)take(2048 * 4);
    uint32_t* PW4      = (uint32_t*)take(2048 * 4);
    int*      part     = (int*)     take(64 * 4);
    int*      partx    = (int*)     take(64 * 4);

    hipMemsetAsync(agg_sum, 0, (size_t)(zero_end - (char*)agg_sum), stream);

    const int BH = (E / 4 + 255) / 256;            // hist blocks
    const int BP = (N + 255) / 256;                // node_pre blocks
    const int NB = (N + 2047) / 2048;              // scan blocks
    const int SB = (E + 255) / 256;                // scatter blocks
    const int TB = (NT + 255) / 256;               // ntile blocks

    prep_kernel   <<<BH + BP + 1, 256, 0, stream>>>(
        ei, cnt, rank, x, u, W1, b1, W2, W3, b3, W4,
        Pa, Pb, Qc, Qu, PW1, PW2, PW3, PW4, E, N, G, BH, BP);
    scanA_kernel  <<<NB, 256, 0, stream>>>(cnt, part, N);
    scanB_kernel  <<<1, 64, 0, stream>>>(part, partx, offs, NB, N);
    scanC_kernel  <<<NB, 256, 0, stream>>>(cnt, partx, offs, N);
    scatter_ntile_kernel<<<SB + TB, 256, 0, stream>>>(
        ei, offs, rank, re4, ntile, E, N, NT, SB);
    fused_edge_mfma<<<(NT + 1) / 2, 128, 0, stream>>>(
        ea, PW1, PW2, b2, Pa, Pb, re4, offs, ntile, agg_sum, agg_maxb, N, E, NT);
    node_mfma     <<<(N + 127) / 128, 256, 0, stream>>>(
        Qc, Qu, batch, PW3, PW4, b4, agg_sum, agg_maxb, offs, out, N);
}

// Round 8
// 233.545 us; speedup vs baseline: 20.8165x; 1.0167x over previous
//
#include <hip/hip_runtime.h>
#include <hip/hip_bf16.h>
#include <stdint.h>

constexpr int FN   = 64;
constexpr int HIDN = 32;
constexpr int FMSG = 64;
constexpr int FOUT = 128;

using short8 = __attribute__((ext_vector_type(8))) short;
using f32x4  = __attribute__((ext_vector_type(4))) float;

union Frag { short8 v; uint32_t u[4]; };

__device__ __forceinline__ uint32_t packrn(float a, float b) {
    union { __hip_bfloat162 h; uint32_t u; } cv;
    cv.h = __float22bfloat162_rn(make_float2(a, b));   // v_cvt_pk_bf16_f32
    return cv.u;
}
__device__ __forceinline__ float bf16_to_f(uint32_t h16) {
    return __uint_as_float(h16 << 16);
}

__device__ __forceinline__ int node_of(const int* __restrict__ offs, int N, int target) {
    int l = 0, r = N + 1;
    while (l + 1 < r) {
        const int m = (l + r) >> 1;
        if (offs[m] <= target) l = m; else r = m;
    }
    return l;
}

// ---------------------------------------------------------------------------
// prep: [0,BH) hist+rank | [BH,BH+BP) node_pre | [BH+BP] pack + Qu
//       | [BH+BP+1, BH+BP+1+BZ) grid-stride zero of agg_sum/agg_maxb
// The zero blocks' write traffic overlaps the hist blocks' atomic latency.
// ---------------------------------------------------------------------------
__global__ __launch_bounds__(256) void prep_kernel(
    const int* __restrict__ ei, int* __restrict__ cnt, int* __restrict__ rank,
    const float* __restrict__ x, const float* __restrict__ u,
    const float* __restrict__ W1, const float* __restrict__ b1,
    const float* __restrict__ W2,
    const float* __restrict__ W3, const float* __restrict__ b3,
    const float* __restrict__ W4,
    float* __restrict__ Pa, float* __restrict__ Pb, float* __restrict__ Qc,
    float* __restrict__ Qu,
    uint32_t* __restrict__ PW1, uint32_t* __restrict__ PW2,
    uint32_t* __restrict__ PW3, uint32_t* __restrict__ PW4,
    uint4* __restrict__ zbase, size_t zquads,
    int E, int N, int G, int BH, int BP, int BZ)
{
    const int b   = blockIdx.x;
    const int tid = threadIdx.x;

    if (b < BH) {
        const int e4 = (b * 256 + tid) * 4;
        if (e4 + 3 < E) {
            const int4 c = *reinterpret_cast<const int4*>(ei + E + e4);
            int4 r;
            r.x = atomicAdd(cnt + c.x, 1);
            r.y = atomicAdd(cnt + c.y, 1);
            r.z = atomicAdd(cnt + c.z, 1);
            r.w = atomicAdd(cnt + c.w, 1);
            *reinterpret_cast<int4*>(rank + e4) = r;
        } else {
            for (int e = e4; e < E; ++e) rank[e] = atomicAdd(cnt + ei[E + e], 1);
        }
        return;
    }
    if (b < BH + BP) {
        const int n = (b - BH) * 256 + tid;
        if (n >= N) return;
        float a[HIDN], bq[HIDN], c[HIDN];
#pragma unroll
        for (int j = 0; j < HIDN; ++j) { a[j] = b1[j]; bq[j] = 0.0f; c[j] = b3[j]; }
        const float* xr = x + (size_t)n * FN;
        const float* WA = W1;
        const float* WB = W1 + FN * HIDN;
        const float* WX = W3;                   // rows 0..63 of W3
#pragma unroll 2
        for (int k = 0; k < FN; k += 4) {
            const float4 v = *reinterpret_cast<const float4*>(xr + k);
            const float* wa = WA + k * HIDN;
            const float* wb = WB + k * HIDN;
            const float* wc = WX + k * HIDN;
#pragma unroll
            for (int j = 0; j < HIDN; ++j) {
                float aj = a[j], bj = bq[j], cj = c[j];
                aj = fmaf(v.x, wa[j], aj);            bj = fmaf(v.x, wb[j], bj);            cj = fmaf(v.x, wc[j], cj);
                aj = fmaf(v.y, wa[HIDN + j], aj);     bj = fmaf(v.y, wb[HIDN + j], bj);     cj = fmaf(v.y, wc[HIDN + j], cj);
                aj = fmaf(v.z, wa[2 * HIDN + j], aj); bj = fmaf(v.z, wb[2 * HIDN + j], bj); cj = fmaf(v.z, wc[2 * HIDN + j], cj);
                aj = fmaf(v.w, wa[3 * HIDN + j], aj); bj = fmaf(v.w, wb[3 * HIDN + j], bj); cj = fmaf(v.w, wc[3 * HIDN + j], cj);
                a[j] = aj; bq[j] = bj; c[j] = cj;
            }
        }
        float4* pa = reinterpret_cast<float4*>(Pa + (size_t)n * HIDN);
        float4* pb = reinterpret_cast<float4*>(Pb + (size_t)n * HIDN);
        float4* qc = reinterpret_cast<float4*>(Qc + (size_t)n * HIDN);
#pragma unroll
        for (int q = 0; q < HIDN / 4; ++q) {
            pa[q] = make_float4(a[4*q], a[4*q+1], a[4*q+2], a[4*q+3]);
            pb[q] = make_float4(bq[4*q], bq[4*q+1], bq[4*q+2], bq[4*q+3]);
            qc[q] = make_float4(c[4*q], c[4*q+1], c[4*q+2], c[4*q+3]);
        }
        return;
    }
    if (b == BH + BP) {
        // ---- pack weights + Qu = u@W3d (per graph) ----
        const float* WC = W1 + 2 * FN * HIDN;
        for (int i = tid; i < 1024; i += 256) {          // PW1[j<32][k2<32]
            const int j = i >> 5, k2 = i & 31;
            PW1[i] = packrn(WC[(2 * k2) * HIDN + j], WC[(2 * k2 + 1) * HIDN + j]);
        }
        for (int i = tid; i < 1024; i += 256) {          // PW2[j<64][k2<16]
            const int j = i >> 4, k2 = i & 15;
            PW2[i] = packrn(W2[(2 * k2) * FMSG + j], W2[(2 * k2 + 1) * FMSG + j]);
        }
        const float* W3m = W3 + 64 * HIDN;               // rows 64..191 (mean|max)
        for (int i = tid; i < 2048; i += 256) {          // PW3[j<32][k2<64]
            const int j = i >> 6, k2 = i & 63;
            PW3[i] = packrn(W3m[(2 * k2) * HIDN + j], W3m[(2 * k2 + 1) * HIDN + j]);
        }
        for (int i = tid; i < 2048; i += 256) {          // PW4[j<128][k2<16]
            const int j = i >> 4, k2 = i & 15;
            PW4[i] = packrn(W4[(2 * k2) * FOUT + j], W4[(2 * k2 + 1) * FOUT + j]);
        }
        const float* W3u = W3 + 192 * HIDN;              // rows 192..255 (u part)
        for (int i = tid; i < G * HIDN; i += 256) {      // Qu[g][j]
            const int g = i >> 5, j = i & 31;
            const float* ur = u + (size_t)g * FN;
            float acc = 0.0f;
#pragma unroll 8
            for (int k = 0; k < FN; ++k) acc = fmaf(ur[k], W3u[k * HIDN + j], acc);
            Qu[i] = acc;
        }
        return;
    }
    // ---- zero agg_sum/agg_maxb (grid-stride uint4) ----
    const size_t stride = (size_t)BZ * 256;
    const uint4 z = make_uint4(0u, 0u, 0u, 0u);
    for (size_t i = (size_t)(b - BH - BP - 1) * 256 + tid; i < zquads; i += stride)
        zbase[i] = z;
}

// ---------------------------------------------------------------------------
// Multi-block scan over cnt[N] -> offs[N+1]
// ---------------------------------------------------------------------------
__global__ __launch_bounds__(256) void scanA_kernel(
    const int* __restrict__ cnt, int* __restrict__ part, int N)
{
    __shared__ int red[256];
    const int tid  = threadIdx.x;
    const int base = blockIdx.x * 2048 + tid * 8;
    int s = 0;
    if (base + 8 <= N) {
        const int4 a = *reinterpret_cast<const int4*>(cnt + base);
        const int4 b = *reinterpret_cast<const int4*>(cnt + base + 4);
        s = a.x + a.y + a.z + a.w + b.x + b.y + b.z + b.w;
    } else {
        for (int i = base; i < min(base + 8, N); ++i) s += cnt[i];
    }
    red[tid] = s;
    __syncthreads();
    for (int d = 128; d > 0; d >>= 1) {
        if (tid < d) red[tid] += red[tid + d];
        __syncthreads();
    }
    if (tid == 0) part[blockIdx.x] = red[0];
}

__global__ __launch_bounds__(64) void scanB_kernel(
    const int* __restrict__ part, int* __restrict__ partx,
    int* __restrict__ offs, int NB, int N)
{
    if (threadIdx.x == 0) {
        int run = 0;
        for (int i = 0; i < NB; ++i) { partx[i] = run; run += part[i]; }
        offs[N] = run;
    }
}

__global__ __launch_bounds__(256) void scanC_kernel(
    const int* __restrict__ cnt, const int* __restrict__ partx,
    int* __restrict__ offs, int N)
{
    __shared__ int sb[256];
    const int tid  = threadIdx.x;
    const int base = blockIdx.x * 2048 + tid * 8;
    int v[8];
    int tsum = 0;
#pragma unroll
    for (int q = 0; q < 8; ++q) {
        const int i = base + q;
        v[q] = (i < N) ? cnt[i] : 0;
        tsum += v[q];
    }
    sb[tid] = tsum;
    __syncthreads();
    for (int d = 1; d < 256; d <<= 1) {
        const int t = (tid >= d) ? sb[tid - d] : 0;
        __syncthreads();
        sb[tid] += t;
        __syncthreads();
    }
    int run = partx[blockIdx.x] + sb[tid] - tsum;
#pragma unroll
    for (int q = 0; q < 8; ++q) {
        const int i = base + q;
        if (i < N) offs[i] = run;
        run += v[q];
    }
}

// ---------------------------------------------------------------------------
// scatter (blocks [0,SB)) + ntile builder (blocks [SB, SB+TB))
// ---------------------------------------------------------------------------
__global__ __launch_bounds__(256) void scatter_ntile_kernel(
    const int* __restrict__ ei, const int* __restrict__ offs,
    const int* __restrict__ rank, int4* __restrict__ re4,
    int2* __restrict__ ntile, int E, int N, int NT, int SB)
{
    const int tid = threadIdx.x;
    if ((int)blockIdx.x < SB) {
        const int e = blockIdx.x * 256 + tid;
        if (e >= E) return;
        const int row = ei[e];
        const int col = ei[E + e];
        const int pos = offs[col] + rank[e];
        re4[pos] = make_int4(row, col, e, 0);
    } else {
        const int t = ((int)blockIdx.x - SB) * 256 + tid;
        if (t >= NT) return;
        const int a = node_of(offs, N, t * 64);
        const int b = node_of(offs, N, min(t * 64 + 63, E - 1));
        ntile[t] = make_int2(a, b);
    }
}

// ---------------------------------------------------------------------------
// Barrier-free MFMA fused edge kernel: 1 wave = 64 sorted edges (unchanged R7).
// ---------------------------------------------------------------------------
__global__ __launch_bounds__(128) void fused_edge_mfma(
    const float* __restrict__ ea,
    const uint32_t* __restrict__ PW1, const uint32_t* __restrict__ PW2,
    const float* __restrict__ b2,
    const float* __restrict__ Pa, const float* __restrict__ Pb,
    const int4* __restrict__ re4, const int* __restrict__ offs,
    const int2* __restrict__ ntile,
    float* __restrict__ agg_sum, int* __restrict__ agg_maxb,
    int N, int E, int NT)
{
    __shared__ uint32_t smem_all[2 * 64 * 34];
    const int w    = threadIdx.x >> 6;
    const int t    = blockIdx.x * 2 + w;
    if (t >= NT) return;
    uint32_t* smem = smem_all + w * (64 * 34);
    const int lane = threadIdx.x & 63;
    const int l15  = lane & 15;
    const int l4   = lane >> 4;
    const int e0   = t * 64;
    const int e1   = min(e0 + 64, E);
    const int2 nrange = ntile[t];

    const int p = e0 + lane;
    const int4 rce = re4[min(p, E - 1)];
    {
        const float2* pa = reinterpret_cast<const float2*>(Pa + (size_t)rce.x * HIDN);
        const float2* pb = reinterpret_cast<const float2*>(Pb + (size_t)rce.y * HIDN);
        float2* dst = reinterpret_cast<float2*>(&smem[lane * 34]);
#pragma unroll
        for (int q = 0; q < 16; ++q) {
            const float2 a = pa[q], b = pb[q];
            dst[q] = make_float2(a.x + b.x, a.y + b.y);
        }
    }

    Frag B1[2][2];
#pragma unroll
    for (int nt = 0; nt < 2; ++nt)
#pragma unroll
        for (int ks = 0; ks < 2; ++ks) {
            const uint4 q = *reinterpret_cast<const uint4*>(
                &PW1[(nt * 16 + l15) * 32 + ks * 16 + l4 * 4]);
            B1[nt][ks].u[0] = q.x; B1[nt][ks].u[1] = q.y;
            B1[nt][ks].u[2] = q.z; B1[nt][ks].u[3] = q.w;
        }
    Frag B2f[4];
#pragma unroll
    for (int nt = 0; nt < 4; ++nt) {
        const uint4 q = *reinterpret_cast<const uint4*>(
            &PW2[(nt * 16 + l15) * 16 + l4 * 4]);
        B2f[nt].u[0] = q.x; B2f[nt].u[1] = q.y;
        B2f[nt].u[2] = q.z; B2f[nt].u[3] = q.w;
    }

    Frag A1[4][2];
#pragma unroll
    for (int mt = 0; mt < 4; ++mt) {
        const int eix = __shfl(rce.z, mt * 16 + l15, 64);
        const float* rp = ea + (size_t)eix * FN;
#pragma unroll
        for (int ks = 0; ks < 2; ++ks) {
            const float4* gp = reinterpret_cast<const float4*>(rp + ks * 32 + l4 * 8);
            const float4 f0 = gp[0], f1 = gp[1];
            A1[mt][ks].u[0] = packrn(f0.x, f0.y);
            A1[mt][ks].u[1] = packrn(f0.z, f0.w);
            A1[mt][ks].u[2] = packrn(f1.x, f1.y);
            A1[mt][ks].u[3] = packrn(f1.z, f1.w);
        }
    }

    f32x4 acc1[4][2];
    const float* Pl = reinterpret_cast<const float*>(smem);
#pragma unroll
    for (int mt = 0; mt < 4; ++mt)
#pragma unroll
        for (int nt = 0; nt < 2; ++nt)
#pragma unroll
            for (int r = 0; r < 4; ++r) {
                const int et = mt * 16 + l4 * 4 + r;
                acc1[mt][nt][r] = Pl[et * 34 + nt * 16 + l15];
            }
#pragma unroll
    for (int mt = 0; mt < 4; ++mt)
#pragma unroll
        for (int nt = 0; nt < 2; ++nt)
#pragma unroll
            for (int ks = 0; ks < 2; ++ks)
                acc1[mt][nt] = __builtin_amdgcn_mfma_f32_16x16x32_bf16(
                    A1[mt][ks].v, B1[nt][ks].v, acc1[mt][nt], 0, 0, 0);

    float* Hl = reinterpret_cast<float*>(smem);
#pragma unroll
    for (int mt = 0; mt < 4; ++mt)
#pragma unroll
        for (int nt = 0; nt < 2; ++nt)
#pragma unroll
            for (int r = 0; r < 4; ++r) {
                const int et = mt * 16 + l4 * 4 + r;
                Hl[et * 34 + nt * 16 + l15] = fmaxf(acc1[mt][nt][r], 0.0f);
            }

    Frag A2[4];
#pragma unroll
    for (int mt = 0; mt < 4; ++mt) {
        const float* hb = &Hl[(mt * 16 + l15) * 34 + l4 * 8];
        const float2 g0 = *reinterpret_cast<const float2*>(hb + 0);
        const float2 g1 = *reinterpret_cast<const float2*>(hb + 2);
        const float2 g2 = *reinterpret_cast<const float2*>(hb + 4);
        const float2 g3 = *reinterpret_cast<const float2*>(hb + 6);
        A2[mt].u[0] = packrn(g0.x, g0.y);
        A2[mt].u[1] = packrn(g1.x, g1.y);
        A2[mt].u[2] = packrn(g2.x, g2.y);
        A2[mt].u[3] = packrn(g3.x, g3.y);
    }

#pragma unroll
    for (int nt = 0; nt < 4; ++nt) {
        const float b2v = b2[nt * 16 + l15];
        f32x4 a2c[4];
#pragma unroll
        for (int mt = 0; mt < 4; ++mt) {
            a2c[mt] = (f32x4){0.f, 0.f, 0.f, 0.f};
            a2c[mt] = __builtin_amdgcn_mfma_f32_16x16x32_bf16(
                A2[mt].v, B2f[nt].v, a2c[mt], 0, 0, 0);
        }
        const int j = nt * 16 + l15;
#pragma unroll
        for (int mt = 0; mt < 4; ++mt)
#pragma unroll
            for (int rp2 = 0; rp2 < 2; ++rp2) {
                const int q2 = mt * 8 + l4 * 2 + rp2;
                const float v0 = fmaxf(a2c[mt][rp2 * 2]     + b2v, 0.0f);
                const float v1 = fmaxf(a2c[mt][rp2 * 2 + 1] + b2v, 0.0f);
                smem[q2 * 64 + (j ^ (((q2 >> 1) & 1) << 4))] = packrn(v0, v1);
            }
    }

    const int n0 = nrange.x, n1 = nrange.y;
    for (int n = n0; n <= n1; ++n) {
        const int s0 = offs[n], t0 = offs[n + 1];
        const int sl = max(s0, e0) - e0, tl = min(t0, e1) - e0;
        float sum = 0.0f, mx = 0.0f;
        int q = sl;
        if (q < tl && (q & 1)) {
            const int q2 = q >> 1;
            const uint32_t wv = smem[q2 * 64 + (lane ^ (((q2 >> 1) & 1) << 4))];
            const float v = bf16_to_f(wv >> 16);
            sum += v; mx = fmaxf(mx, v); ++q;
        }
        for (; q + 1 < tl; q += 2) {
            const int q2 = q >> 1;
            const uint32_t wv = smem[q2 * 64 + (lane ^ (((q2 >> 1) & 1) << 4))];
            const float v0 = bf16_to_f(wv & 0xffffu), v1 = bf16_to_f(wv >> 16);
            sum += v0 + v1; mx = fmaxf(mx, fmaxf(v0, v1));
        }
        if (q < tl) {
            const int q2 = q >> 1;
            const uint32_t wv = smem[q2 * 64 + (lane ^ (((q2 >> 1) & 1) << 4))];
            const float v = bf16_to_f(wv & 0xffffu);
            sum += v; mx = fmaxf(mx, v);
        }
        float* sp = agg_sum  + (size_t)n * FMSG + lane;
        int*   mp = agg_maxb + (size_t)n * FMSG + lane;
        if (s0 >= e0 && t0 <= e1) {
            *sp = sum;
            *mp = __float_as_int(mx);
        } else {
            unsafeAtomicAdd(sp, sum);
            atomicMax(mp, __float_as_int(mx));
        }
    }
}

// ---------------------------------------------------------------------------
// Barrier-free MFMA node kernel: 1 wave = 32 nodes, 4 waves/block (unchanged).
// ---------------------------------------------------------------------------
__global__ __launch_bounds__(256) void node_mfma(
    const float* __restrict__ Qc, const float* __restrict__ Qu,
    const int*   __restrict__ batch,
    const uint32_t* __restrict__ PW3, const uint32_t* __restrict__ PW4,
    const float* __restrict__ b4,
    const float* __restrict__ agg_sum, const int* __restrict__ agg_maxb,
    const int*   __restrict__ offs,
    float* __restrict__ out, int N)
{
    __shared__ float Hl_all[4 * 32 * 34];
    const int w    = threadIdx.x >> 6;
    float* Hl      = Hl_all + w * (32 * 34);
    const int lane = threadIdx.x & 63;
    const int l15  = lane & 15;
    const int l4   = lane >> 4;
    const int n0   = blockIdx.x * 128 + w * 32;
    if (n0 >= N) return;

    f32x4 acc1[2][2];
#pragma unroll
    for (int mt = 0; mt < 2; ++mt)
#pragma unroll
        for (int r = 0; r < 4; ++r) {
            const int nc = min(n0 + mt * 16 + l4 * 4 + r, N - 1);
            const int g  = batch[nc];
#pragma unroll
            for (int nt = 0; nt < 2; ++nt)
                acc1[mt][nt][r] = Qc[(size_t)nc * HIDN + nt * 16 + l15]
                                + Qu[(size_t)g  * HIDN + nt * 16 + l15];
        }

    int   arn[2];
    float ainv[2];
#pragma unroll
    for (int mt = 0; mt < 2; ++mt) {
        arn[mt] = min(n0 + mt * 16 + l15, N - 1);
        const int deg = offs[arn[mt] + 1] - offs[arn[mt]];
        ainv[mt] = (deg > 0) ? 1.0f / (float)deg : 0.0f;
    }

    Frag B3[2][4];
#pragma unroll
    for (int nt = 0; nt < 2; ++nt)
#pragma unroll
        for (int ks = 0; ks < 4; ++ks) {
            const uint4 q = *reinterpret_cast<const uint4*>(
                &PW3[(nt * 16 + l15) * 64 + ks * 16 + l4 * 4]);
            B3[nt][ks].u[0] = q.x; B3[nt][ks].u[1] = q.y;
            B3[nt][ks].u[2] = q.z; B3[nt][ks].u[3] = q.w;
        }

#pragma unroll
    for (int ks = 0; ks < 4; ++ks) {
        Frag A[2];
        if (ks < 2) {
#pragma unroll
            for (int mt = 0; mt < 2; ++mt) {
                const float4* gp = reinterpret_cast<const float4*>(
                    agg_sum + (size_t)arn[mt] * FMSG + ks * 32 + l4 * 8);
                const float4 f0 = gp[0], f1 = gp[1];
                const float s = ainv[mt];
                A[mt].u[0] = packrn(f0.x * s, f0.y * s);
                A[mt].u[1] = packrn(f0.z * s, f0.w * s);
                A[mt].u[2] = packrn(f1.x * s, f1.y * s);
                A[mt].u[3] = packrn(f1.z * s, f1.w * s);
            }
        } else {
#pragma unroll
            for (int mt = 0; mt < 2; ++mt) {
                const uint4* gp = reinterpret_cast<const uint4*>(
                    agg_maxb + (size_t)arn[mt] * FMSG + (ks - 2) * 32 + l4 * 8);
                const uint4 u0 = gp[0], u1 = gp[1];
                A[mt].u[0] = packrn(__uint_as_float(u0.x), __uint_as_float(u0.y));
                A[mt].u[1] = packrn(__uint_as_float(u0.z), __uint_as_float(u0.w));
                A[mt].u[2] = packrn(__uint_as_float(u1.x), __uint_as_float(u1.y));
                A[mt].u[3] = packrn(__uint_as_float(u1.z), __uint_as_float(u1.w));
            }
        }
#pragma unroll
        for (int mt = 0; mt < 2; ++mt)
#pragma unroll
            for (int nt = 0; nt < 2; ++nt)
                acc1[mt][nt] = __builtin_amdgcn_mfma_f32_16x16x32_bf16(
                    A[mt].v, B3[nt][ks].v, acc1[mt][nt], 0, 0, 0);
    }

#pragma unroll
    for (int mt = 0; mt < 2; ++mt)
#pragma unroll
        for (int nt = 0; nt < 2; ++nt)
#pragma unroll
            for (int r = 0; r < 4; ++r) {
                const int rw = mt * 16 + l4 * 4 + r;
                Hl[rw * 34 + nt * 16 + l15] = fmaxf(acc1[mt][nt][r], 0.0f);
            }

    Frag A2[2];
#pragma unroll
    for (int mt = 0; mt < 2; ++mt) {
        const float* hb = &Hl[(mt * 16 + l15) * 34 + l4 * 8];
        const float2 g0 = *reinterpret_cast<const float2*>(hb + 0);
        const float2 g1 = *reinterpret_cast<const float2*>(hb + 2);
        const float2 g2 = *reinterpret_cast<const float2*>(hb + 4);
        const float2 g3 = *reinterpret_cast<const float2*>(hb + 6);
        A2[mt].u[0] = packrn(g0.x, g0.y);
        A2[mt].u[1] = packrn(g1.x, g1.y);
        A2[mt].u[2] = packrn(g2.x, g2.y);
        A2[mt].u[3] = packrn(g3.x, g3.y);
    }

#pragma unroll
    for (int nt = 0; nt < 8; ++nt) {
        Frag B4f;
        const uint4 q = *reinterpret_cast<const uint4*>(
            &PW4[(nt * 16 + l15) * 16 + l4 * 4]);
        B4f.u[0] = q.x; B4f.u[1] = q.y; B4f.u[2] = q.z; B4f.u[3] = q.w;
        const float b4v = b4[nt * 16 + l15];
        f32x4 tacc[2];
#pragma unroll
        for (int mt = 0; mt < 2; ++mt) {
            tacc[mt] = (f32x4){0.f, 0.f, 0.f, 0.f};
            tacc[mt] = __builtin_amdgcn_mfma_f32_16x16x32_bf16(
                A2[mt].v, B4f.v, tacc[mt], 0, 0, 0);
        }
#pragma unroll
        for (int mt = 0; mt < 2; ++mt)
#pragma unroll
            for (int r = 0; r < 4; ++r) {
                const int node = n0 + mt * 16 + l4 * 4 + r;
                if (node < N)
                    out[(size_t)node * FOUT + nt * 16 + l15] =
                        fmaxf(tacc[mt][r] + b4v, 0.0f);
            }
    }
}

// ===========================================================================
extern "C" void kernel_launch(void* const* d_in, const int* in_sizes, int n_in,
                              void* d_out, int out_size, void* d_ws, size_t ws_size,
                              hipStream_t stream)
{
    const float* x     = (const float*)d_in[0];
    const int*   ei    = (const int*)  d_in[1];
    const float* ea    = (const float*)d_in[2];
    const float* u     = (const float*)d_in[3];
    const int*   batch = (const int*)  d_in[4];
    const float* W1    = (const float*)d_in[5];
    const float* b1    = (const float*)d_in[6];
    const float* W2    = (const float*)d_in[7];
    const float* b2    = (const float*)d_in[8];
    const float* W3    = (const float*)d_in[9];
    const float* b3    = (const float*)d_in[10];
    const float* W4    = (const float*)d_in[11];
    const float* b4    = (const float*)d_in[12];
    float* out = (float*)d_out;

    const int N = in_sizes[0] / FN;   // 50000
    const int E = in_sizes[1] / 2;    // 800000
    const int G = in_sizes[3] / FN;   // 64
    const int NT = (E + 63) / 64;     // 64-edge tiles

    char* wp = (char*)d_ws;
    auto take = [&](size_t bytes) -> void* {
        void* r = (void*)wp;
        wp += (bytes + 255) & ~(size_t)255;
        return r;
    };
    float*    agg_sum  = (float*)   take((size_t)N * FMSG * 4);
    int*      agg_maxb = (int*)     take((size_t)N * FMSG * 4);
    char*     zero_end = wp;                       // agg zero span (in prep)
    int*      cnt      = (int*)     take((size_t)N * 4);
    int*      offs     = (int*)     take(((size_t)N + 1) * 4);
    int*      rank     = (int*)     take((size_t)E * 4);
    int4*     re4      = (int4*)    take((size_t)E * 16);
    int2*     ntile    = (int2*)    take((size_t)NT * 8);
    float*    Pa       = (float*)   take((size_t)N * HIDN * 4);
    float*    Pb       = (float*)   take((size_t)N * HIDN * 4);
    float*    Qc       = (float*)   take((size_t)N * HIDN * 4);
    float*    Qu       = (float*)   take((size_t)G * HIDN * 4);
    uint32_t* PW1      = (uint32_t*)take(1024 * 4);
    uint32_t* PW2      = (uint32_t*)take(1024 * 4);
    uint32_t* PW3      = (uint32_t*)take(2048 * 4);
    uint32_t* PW4      = (uint32_t*)take(2048 * 4);
    int*      part     = (int*)     take(64 * 4);
    int*      partx    = (int*)     take(64 * 4);

    // Only cnt needs zeroing before prep's hist atomics (200 KB).
    hipMemsetAsync(cnt, 0, (size_t)N * 4, stream);

    const int BH = (E / 4 + 255) / 256;            // hist blocks
    const int BP = (N + 255) / 256;                // node_pre blocks
    const int BZ = 256;                            // agg-zero blocks
    const int NB = (N + 2047) / 2048;              // scan blocks
    const int SB = (E + 255) / 256;                // scatter blocks
    const int TB = (NT + 255) / 256;               // ntile blocks
    const size_t zquads = (size_t)(zero_end - (char*)agg_sum) / 16;

    prep_kernel   <<<BH + BP + 1 + BZ, 256, 0, stream>>>(
        ei, cnt, rank, x, u, W1, b1, W2, W3, b3, W4,
        Pa, Pb, Qc, Qu, PW1, PW2, PW3, PW4,
        (uint4*)agg_sum, zquads, E, N, G, BH, BP, BZ);
    scanA_kernel  <<<NB, 256, 0, stream>>>(cnt, part, N);
    scanB_kernel  <<<1, 64, 0, stream>>>(part, partx, offs, NB, N);
    scanC_kernel  <<<NB, 256, 0, stream>>>(cnt, partx, offs, N);
    scatter_ntile_kernel<<<SB + TB, 256, 0, stream>>>(
        ei, offs, rank, re4, ntile, E, N, NT, SB);
    fused_edge_mfma<<<(NT + 1) / 2, 128, 0, stream>>>(
        ea, PW1, PW2, b2, Pa, Pb, re4, offs, ntile, agg_sum, agg_maxb, N, E, NT);
    node_mfma     <<<(N + 127) / 128, 256, 0, stream>>>(
        Qc, Qu, batch, PW3, PW4, b4, agg_sum, agg_maxb, offs, out, N);
}

// Round 9
// 225.565 us; speedup vs baseline: 21.5529x; 1.0354x over previous
//
#include <hip/hip_runtime.h>
#include <hip/hip_bf16.h>
#include <stdint.h>

constexpr int FN   = 64;
constexpr int HIDN = 32;
constexpr int FMSG = 64;
constexpr int FOUT = 128;

using short8 = __attribute__((ext_vector_type(8))) short;
using f32x4  = __attribute__((ext_vector_type(4))) float;

union Frag { short8 v; uint32_t u[4]; };

__device__ __forceinline__ uint32_t packrn(float a, float b) {
    union { __hip_bfloat162 h; uint32_t u; } cv;
    cv.h = __float22bfloat162_rn(make_float2(a, b));   // v_cvt_pk_bf16_f32
    return cv.u;
}
__device__ __forceinline__ float bf16_to_f(uint32_t h16) {
    return __uint_as_float(h16 << 16);
}

__device__ __forceinline__ int node_of(const int* __restrict__ offs, int N, int target) {
    int l = 0, r = N + 1;
    while (l + 1 < r) {
        const int m = (l + r) >> 1;
        if (offs[m] <= target) l = m; else r = m;
    }
    return l;
}

// ---------------------------------------------------------------------------
// hist: isolated so rocprof attributes its time exactly.
// 800k device-scope atomicAdd-with-return (rank = within-node arrival order).
// ---------------------------------------------------------------------------
__global__ __launch_bounds__(256) void hist_kernel(
    const int* __restrict__ ei, int* __restrict__ cnt, int* __restrict__ rank,
    int E)
{
    const int e4 = (blockIdx.x * 256 + threadIdx.x) * 4;
    if (e4 + 3 < E) {
        const int4 c = *reinterpret_cast<const int4*>(ei + E + e4);
        int4 r;
        r.x = atomicAdd(cnt + c.x, 1);
        r.y = atomicAdd(cnt + c.y, 1);
        r.z = atomicAdd(cnt + c.z, 1);
        r.w = atomicAdd(cnt + c.w, 1);
        *reinterpret_cast<int4*>(rank + e4) = r;
    } else {
        for (int e = e4; e < E; ++e) rank[e] = atomicAdd(cnt + ei[E + e], 1);
    }
}

// ---------------------------------------------------------------------------
// prep_rest: [0,BP) node_pre | [BP] pack + Qu | [BP+1, BP+1+BZ) agg zero
// ---------------------------------------------------------------------------
__global__ __launch_bounds__(256) void prep_rest_kernel(
    const float* __restrict__ x, const float* __restrict__ u,
    const float* __restrict__ W1, const float* __restrict__ b1,
    const float* __restrict__ W2,
    const float* __restrict__ W3, const float* __restrict__ b3,
    const float* __restrict__ W4,
    float* __restrict__ Pa, float* __restrict__ Pb, float* __restrict__ Qc,
    float* __restrict__ Qu,
    uint32_t* __restrict__ PW1, uint32_t* __restrict__ PW2,
    uint32_t* __restrict__ PW3, uint32_t* __restrict__ PW4,
    uint4* __restrict__ zbase, size_t zquads,
    int N, int G, int BP, int BZ)
{
    const int b   = blockIdx.x;
    const int tid = threadIdx.x;

    if (b < BP) {
        const int n = b * 256 + tid;
        if (n >= N) return;
        float a[HIDN], bq[HIDN], c[HIDN];
#pragma unroll
        for (int j = 0; j < HIDN; ++j) { a[j] = b1[j]; bq[j] = 0.0f; c[j] = b3[j]; }
        const float* xr = x + (size_t)n * FN;
        const float* WA = W1;
        const float* WB = W1 + FN * HIDN;
        const float* WX = W3;                   // rows 0..63 of W3
#pragma unroll 2
        for (int k = 0; k < FN; k += 4) {
            const float4 v = *reinterpret_cast<const float4*>(xr + k);
            const float* wa = WA + k * HIDN;
            const float* wb = WB + k * HIDN;
            const float* wc = WX + k * HIDN;
#pragma unroll
            for (int j = 0; j < HIDN; ++j) {
                float aj = a[j], bj = bq[j], cj = c[j];
                aj = fmaf(v.x, wa[j], aj);            bj = fmaf(v.x, wb[j], bj);            cj = fmaf(v.x, wc[j], cj);
                aj = fmaf(v.y, wa[HIDN + j], aj);     bj = fmaf(v.y, wb[HIDN + j], bj);     cj = fmaf(v.y, wc[HIDN + j], cj);
                aj = fmaf(v.z, wa[2 * HIDN + j], aj); bj = fmaf(v.z, wb[2 * HIDN + j], bj); cj = fmaf(v.z, wc[2 * HIDN + j], cj);
                aj = fmaf(v.w, wa[3 * HIDN + j], aj); bj = fmaf(v.w, wb[3 * HIDN + j], bj); cj = fmaf(v.w, wc[3 * HIDN + j], cj);
                a[j] = aj; bq[j] = bj; c[j] = cj;
            }
        }
        float4* pa = reinterpret_cast<float4*>(Pa + (size_t)n * HIDN);
        float4* pb = reinterpret_cast<float4*>(Pb + (size_t)n * HIDN);
        float4* qc = reinterpret_cast<float4*>(Qc + (size_t)n * HIDN);
#pragma unroll
        for (int q = 0; q < HIDN / 4; ++q) {
            pa[q] = make_float4(a[4*q], a[4*q+1], a[4*q+2], a[4*q+3]);
            pb[q] = make_float4(bq[4*q], bq[4*q+1], bq[4*q+2], bq[4*q+3]);
            qc[q] = make_float4(c[4*q], c[4*q+1], c[4*q+2], c[4*q+3]);
        }
        return;
    }
    if (b == BP) {
        // ---- pack weights + Qu = u@W3d (per graph) ----
        const float* WC = W1 + 2 * FN * HIDN;
        for (int i = tid; i < 1024; i += 256) {          // PW1[j<32][k2<32]
            const int j = i >> 5, k2 = i & 31;
            PW1[i] = packrn(WC[(2 * k2) * HIDN + j], WC[(2 * k2 + 1) * HIDN + j]);
        }
        for (int i = tid; i < 1024; i += 256) {          // PW2[j<64][k2<16]
            const int j = i >> 4, k2 = i & 15;
            PW2[i] = packrn(W2[(2 * k2) * FMSG + j], W2[(2 * k2 + 1) * FMSG + j]);
        }
        const float* W3m = W3 + 64 * HIDN;               // rows 64..191 (mean|max)
        for (int i = tid; i < 2048; i += 256) {          // PW3[j<32][k2<64]
            const int j = i >> 6, k2 = i & 63;
            PW3[i] = packrn(W3m[(2 * k2) * HIDN + j], W3m[(2 * k2 + 1) * HIDN + j]);
        }
        for (int i = tid; i < 2048; i += 256) {          // PW4[j<128][k2<16]
            const int j = i >> 4, k2 = i & 15;
            PW4[i] = packrn(W4[(2 * k2) * FOUT + j], W4[(2 * k2 + 1) * FOUT + j]);
        }
        const float* W3u = W3 + 192 * HIDN;              // rows 192..255 (u part)
        for (int i = tid; i < G * HIDN; i += 256) {      // Qu[g][j]
            const int g = i >> 5, j = i & 31;
            const float* ur = u + (size_t)g * FN;
            float acc = 0.0f;
#pragma unroll 8
            for (int k = 0; k < FN; ++k) acc = fmaf(ur[k], W3u[k * HIDN + j], acc);
            Qu[i] = acc;
        }
        return;
    }
    // ---- zero agg_sum/agg_maxb (grid-stride uint4) ----
    const size_t stride = (size_t)BZ * 256;
    const uint4 z = make_uint4(0u, 0u, 0u, 0u);
    for (size_t i = (size_t)(b - BP - 1) * 256 + tid; i < zquads; i += stride)
        zbase[i] = z;
}

// ---------------------------------------------------------------------------
// Multi-block scan over cnt[N] -> offs[N+1]
// ---------------------------------------------------------------------------
__global__ __launch_bounds__(256) void scanA_kernel(
    const int* __restrict__ cnt, int* __restrict__ part, int N)
{
    __shared__ int red[256];
    const int tid  = threadIdx.x;
    const int base = blockIdx.x * 2048 + tid * 8;
    int s = 0;
    if (base + 8 <= N) {
        const int4 a = *reinterpret_cast<const int4*>(cnt + base);
        const int4 b = *reinterpret_cast<const int4*>(cnt + base + 4);
        s = a.x + a.y + a.z + a.w + b.x + b.y + b.z + b.w;
    } else {
        for (int i = base; i < min(base + 8, N); ++i) s += cnt[i];
    }
    red[tid] = s;
    __syncthreads();
    for (int d = 128; d > 0; d >>= 1) {
        if (tid < d) red[tid] += red[tid + d];
        __syncthreads();
    }
    if (tid == 0) part[blockIdx.x] = red[0];
}

__global__ __launch_bounds__(64) void scanB_kernel(
    const int* __restrict__ part, int* __restrict__ partx,
    int* __restrict__ offs, int NB, int N)
{
    if (threadIdx.x == 0) {
        int run = 0;
        for (int i = 0; i < NB; ++i) { partx[i] = run; run += part[i]; }
        offs[N] = run;
    }
}

__global__ __launch_bounds__(256) void scanC_kernel(
    const int* __restrict__ cnt, const int* __restrict__ partx,
    int* __restrict__ offs, int N)
{
    __shared__ int sb[256];
    const int tid  = threadIdx.x;
    const int base = blockIdx.x * 2048 + tid * 8;
    int v[8];
    int tsum = 0;
#pragma unroll
    for (int q = 0; q < 8; ++q) {
        const int i = base + q;
        v[q] = (i < N) ? cnt[i] : 0;
        tsum += v[q];
    }
    sb[tid] = tsum;
    __syncthreads();
    for (int d = 1; d < 256; d <<= 1) {
        const int t = (tid >= d) ? sb[tid - d] : 0;
        __syncthreads();
        sb[tid] += t;
        __syncthreads();
    }
    int run = partx[blockIdx.x] + sb[tid] - tsum;
#pragma unroll
    for (int q = 0; q < 8; ++q) {
        const int i = base + q;
        if (i < N) offs[i] = run;
        run += v[q];
    }
}

// ---------------------------------------------------------------------------
// scatter (blocks [0,SB)) + ntile builder (blocks [SB, SB+TB))
// ---------------------------------------------------------------------------
__global__ __launch_bounds__(256) void scatter_ntile_kernel(
    const int* __restrict__ ei, const int* __restrict__ offs,
    const int* __restrict__ rank, int4* __restrict__ re4,
    int2* __restrict__ ntile, int E, int N, int NT, int SB)
{
    const int tid = threadIdx.x;
    if ((int)blockIdx.x < SB) {
        const int e = blockIdx.x * 256 + tid;
        if (e >= E) return;
        const int row = ei[e];
        const int col = ei[E + e];
        const int pos = offs[col] + rank[e];
        re4[pos] = make_int4(row, col, e, 0);
    } else {
        const int t = ((int)blockIdx.x - SB) * 256 + tid;
        if (t >= NT) return;
        const int a = node_of(offs, N, t * 64);
        const int b = node_of(offs, N, min(t * 64 + 63, E - 1));
        ntile[t] = make_int2(a, b);
    }
}

// ---------------------------------------------------------------------------
// Barrier-free MFMA fused edge kernel: 1 wave = 64 sorted edges (unchanged).
// ---------------------------------------------------------------------------
__global__ __launch_bounds__(128) void fused_edge_mfma(
    const float* __restrict__ ea,
    const uint32_t* __restrict__ PW1, const uint32_t* __restrict__ PW2,
    const float* __restrict__ b2,
    const float* __restrict__ Pa, const float* __restrict__ Pb,
    const int4* __restrict__ re4, const int* __restrict__ offs,
    const int2* __restrict__ ntile,
    float* __restrict__ agg_sum, int* __restrict__ agg_maxb,
    int N, int E, int NT)
{
    __shared__ uint32_t smem_all[2 * 64 * 34];
    const int w    = threadIdx.x >> 6;
    const int t    = blockIdx.x * 2 + w;
    if (t >= NT) return;
    uint32_t* smem = smem_all + w * (64 * 34);
    const int lane = threadIdx.x & 63;
    const int l15  = lane & 15;
    const int l4   = lane >> 4;
    const int e0   = t * 64;
    const int e1   = min(e0 + 64, E);
    const int2 nrange = ntile[t];

    const int p = e0 + lane;
    const int4 rce = re4[min(p, E - 1)];
    {
        const float2* pa = reinterpret_cast<const float2*>(Pa + (size_t)rce.x * HIDN);
        const float2* pb = reinterpret_cast<const float2*>(Pb + (size_t)rce.y * HIDN);
        float2* dst = reinterpret_cast<float2*>(&smem[lane * 34]);
#pragma unroll
        for (int q = 0; q < 16; ++q) {
            const float2 a = pa[q], b = pb[q];
            dst[q] = make_float2(a.x + b.x, a.y + b.y);
        }
    }

    Frag B1[2][2];
#pragma unroll
    for (int nt = 0; nt < 2; ++nt)
#pragma unroll
        for (int ks = 0; ks < 2; ++ks) {
            const uint4 q = *reinterpret_cast<const uint4*>(
                &PW1[(nt * 16 + l15) * 32 + ks * 16 + l4 * 4]);
            B1[nt][ks].u[0] = q.x; B1[nt][ks].u[1] = q.y;
            B1[nt][ks].u[2] = q.z; B1[nt][ks].u[3] = q.w;
        }
    Frag B2f[4];
#pragma unroll
    for (int nt = 0; nt < 4; ++nt) {
        const uint4 q = *reinterpret_cast<const uint4*>(
            &PW2[(nt * 16 + l15) * 16 + l4 * 4]);
        B2f[nt].u[0] = q.x; B2f[nt].u[1] = q.y;
        B2f[nt].u[2] = q.z; B2f[nt].u[3] = q.w;
    }

    Frag A1[4][2];
#pragma unroll
    for (int mt = 0; mt < 4; ++mt) {
        const int eix = __shfl(rce.z, mt * 16 + l15, 64);
        const float* rp = ea + (size_t)eix * FN;
#pragma unroll
        for (int ks = 0; ks < 2; ++ks) {
            const float4* gp = reinterpret_cast<const float4*>(rp + ks * 32 + l4 * 8);
            const float4 f0 = gp[0], f1 = gp[1];
            A1[mt][ks].u[0] = packrn(f0.x, f0.y);
            A1[mt][ks].u[1] = packrn(f0.z, f0.w);
            A1[mt][ks].u[2] = packrn(f1.x, f1.y);
            A1[mt][ks].u[3] = packrn(f1.z, f1.w);
        }
    }

    f32x4 acc1[4][2];
    const float* Pl = reinterpret_cast<const float*>(smem);
#pragma unroll
    for (int mt = 0; mt < 4; ++mt)
#pragma unroll
        for (int nt = 0; nt < 2; ++nt)
#pragma unroll
            for (int r = 0; r < 4; ++r) {
                const int et = mt * 16 + l4 * 4 + r;
                acc1[mt][nt][r] = Pl[et * 34 + nt * 16 + l15];
            }
#pragma unroll
    for (int mt = 0; mt < 4; ++mt)
#pragma unroll
        for (int nt = 0; nt < 2; ++nt)
#pragma unroll
            for (int ks = 0; ks < 2; ++ks)
                acc1[mt][nt] = __builtin_amdgcn_mfma_f32_16x16x32_bf16(
                    A1[mt][ks].v, B1[nt][ks].v, acc1[mt][nt], 0, 0, 0);

    float* Hl = reinterpret_cast<float*>(smem);
#pragma unroll
    for (int mt = 0; mt < 4; ++mt)
#pragma unroll
        for (int nt = 0; nt < 2; ++nt)
#pragma unroll
            for (int r = 0; r < 4; ++r) {
                const int et = mt * 16 + l4 * 4 + r;
                Hl[et * 34 + nt * 16 + l15] = fmaxf(acc1[mt][nt][r], 0.0f);
            }

    Frag A2[4];
#pragma unroll
    for (int mt = 0; mt < 4; ++mt) {
        const float* hb = &Hl[(mt * 16 + l15) * 34 + l4 * 8];
        const float2 g0 = *reinterpret_cast<const float2*>(hb + 0);
        const float2 g1 = *reinterpret_cast<const float2*>(hb + 2);
        const float2 g2 = *reinterpret_cast<const float2*>(hb + 4);
        const float2 g3 = *reinterpret_cast<const float2*>(hb + 6);
        A2[mt].u[0] = packrn(g0.x, g0.y);
        A2[mt].u[1] = packrn(g1.x, g1.y);
        A2[mt].u[2] = packrn(g2.x, g2.y);
        A2[mt].u[3] = packrn(g3.x, g3.y);
    }

#pragma unroll
    for (int nt = 0; nt < 4; ++nt) {
        const float b2v = b2[nt * 16 + l15];
        f32x4 a2c[4];
#pragma unroll
        for (int mt = 0; mt < 4; ++mt) {
            a2c[mt] = (f32x4){0.f, 0.f, 0.f, 0.f};
            a2c[mt] = __builtin_amdgcn_mfma_f32_16x16x32_bf16(
                A2[mt].v, B2f[nt].v, a2c[mt], 0, 0, 0);
        }
        const int j = nt * 16 + l15;
#pragma unroll
        for (int mt = 0; mt < 4; ++mt)
#pragma unroll
            for (int rp2 = 0; rp2 < 2; ++rp2) {
                const int q2 = mt * 8 + l4 * 2 + rp2;
                const float v0 = fmaxf(a2c[mt][rp2 * 2]     + b2v, 0.0f);
                const float v1 = fmaxf(a2c[mt][rp2 * 2 + 1] + b2v, 0.0f);
                smem[q2 * 64 + (j ^ (((q2 >> 1) & 1) << 4))] = packrn(v0, v1);
            }
    }

    const int n0 = nrange.x, n1 = nrange.y;
    for (int n = n0; n <= n1; ++n) {
        const int s0 = offs[n], t0 = offs[n + 1];
        const int sl = max(s0, e0) - e0, tl = min(t0, e1) - e0;
        float sum = 0.0f, mx = 0.0f;
        int q = sl;
        if (q < tl && (q & 1)) {
            const int q2 = q >> 1;
            const uint32_t wv = smem[q2 * 64 + (lane ^ (((q2 >> 1) & 1) << 4))];
            const float v = bf16_to_f(wv >> 16);
            sum += v; mx = fmaxf(mx, v); ++q;
        }
        for (; q + 1 < tl; q += 2) {
            const int q2 = q >> 1;
            const uint32_t wv = smem[q2 * 64 + (lane ^ (((q2 >> 1) & 1) << 4))];
            const float v0 = bf16_to_f(wv & 0xffffu), v1 = bf16_to_f(wv >> 16);
            sum += v0 + v1; mx = fmaxf(mx, fmaxf(v0, v1));
        }
        if (q < tl) {
            const int q2 = q >> 1;
            const uint32_t wv = smem[q2 * 64 + (lane ^ (((q2 >> 1) & 1) << 4))];
            const float v = bf16_to_f(wv & 0xffffu);
            sum += v; mx = fmaxf(mx, v);
        }
        float* sp = agg_sum  + (size_t)n * FMSG + lane;
        int*   mp = agg_maxb + (size_t)n * FMSG + lane;
        if (s0 >= e0 && t0 <= e1) {
            *sp = sum;
            *mp = __float_as_int(mx);
        } else {
            unsafeAtomicAdd(sp, sum);
            atomicMax(mp, __float_as_int(mx));
        }
    }
}

// ---------------------------------------------------------------------------
// Barrier-free MFMA node kernel: 1 wave = 32 nodes, 4 waves/block (unchanged).
// ---------------------------------------------------------------------------
__global__ __launch_bounds__(256) void node_mfma(
    const float* __restrict__ Qc, const float* __restrict__ Qu,
    const int*   __restrict__ batch,
    const uint32_t* __restrict__ PW3, const uint32_t* __restrict__ PW4,
    const float* __restrict__ b4,
    const float* __restrict__ agg_sum, const int* __restrict__ agg_maxb,
    const int*   __restrict__ offs,
    float* __restrict__ out, int N)
{
    __shared__ float Hl_all[4 * 32 * 34];
    const int w    = threadIdx.x >> 6;
    float* Hl      = Hl_all + w * (32 * 34);
    const int lane = threadIdx.x & 63;
    const int l15  = lane & 15;
    const int l4   = lane >> 4;
    const int n0   = blockIdx.x * 128 + w * 32;
    if (n0 >= N) return;

    f32x4 acc1[2][2];
#pragma unroll
    for (int mt = 0; mt < 2; ++mt)
#pragma unroll
        for (int r = 0; r < 4; ++r) {
            const int nc = min(n0 + mt * 16 + l4 * 4 + r, N - 1);
            const int g  = batch[nc];
#pragma unroll
            for (int nt = 0; nt < 2; ++nt)
                acc1[mt][nt][r] = Qc[(size_t)nc * HIDN + nt * 16 + l15]
                                + Qu[(size_t)g  * HIDN + nt * 16 + l15];
        }

    int   arn[2];
    float ainv[2];
#pragma unroll
    for (int mt = 0; mt < 2; ++mt) {
        arn[mt] = min(n0 + mt * 16 + l15, N - 1);
        const int deg = offs[arn[mt] + 1] - offs[arn[mt]];
        ainv[mt] = (deg > 0) ? 1.0f / (float)deg : 0.0f;
    }

    Frag B3[2][4];
#pragma unroll
    for (int nt = 0; nt < 2; ++nt)
#pragma unroll
        for (int ks = 0; ks < 4; ++ks) {
            const uint4 q = *reinterpret_cast<const uint4*>(
                &PW3[(nt * 16 + l15) * 64 + ks * 16 + l4 * 4]);
            B3[nt][ks].u[0] = q.x; B3[nt][ks].u[1] = q.y;
            B3[nt][ks].u[2] = q.z; B3[nt][ks].u[3] = q.w;
        }

#pragma unroll
    for (int ks = 0; ks < 4; ++ks) {
        Frag A[2];
        if (ks < 2) {
#pragma unroll
            for (int mt = 0; mt < 2; ++mt) {
                const float4* gp = reinterpret_cast<const float4*>(
                    agg_sum + (size_t)arn[mt] * FMSG + ks * 32 + l4 * 8);
                const float4 f0 = gp[0], f1 = gp[1];
                const float s = ainv[mt];
                A[mt].u[0] = packrn(f0.x * s, f0.y * s);
                A[mt].u[1] = packrn(f0.z * s, f0.w * s);
                A[mt].u[2] = packrn(f1.x * s, f1.y * s);
                A[mt].u[3] = packrn(f1.z * s, f1.w * s);
            }
        } else {
#pragma unroll
            for (int mt = 0; mt < 2; ++mt) {
                const uint4* gp = reinterpret_cast<const uint4*>(
                    agg_maxb + (size_t)arn[mt] * FMSG + (ks - 2) * 32 + l4 * 8);
                const uint4 u0 = gp[0], u1 = gp[1];
                A[mt].u[0] = packrn(__uint_as_float(u0.x), __uint_as_float(u0.y));
                A[mt].u[1] = packrn(__uint_as_float(u0.z), __uint_as_float(u0.w));
                A[mt].u[2] = packrn(__uint_as_float(u1.x), __uint_as_float(u1.y));
                A[mt].u[3] = packrn(__uint_as_float(u1.z), __uint_as_float(u1.w));
            }
        }
#pragma unroll
        for (int mt = 0; mt < 2; ++mt)
#pragma unroll
            for (int nt = 0; nt < 2; ++nt)
                acc1[mt][nt] = __builtin_amdgcn_mfma_f32_16x16x32_bf16(
                    A[mt].v, B3[nt][ks].v, acc1[mt][nt], 0, 0, 0);
    }

#pragma unroll
    for (int mt = 0; mt < 2; ++mt)
#pragma unroll
        for (int nt = 0; nt < 2; ++nt)
#pragma unroll
            for (int r = 0; r < 4; ++r) {
                const int rw = mt * 16 + l4 * 4 + r;
                Hl[rw * 34 + nt * 16 + l15] = fmaxf(acc1[mt][nt][r], 0.0f);
            }

    Frag A2[2];
#pragma unroll
    for (int mt = 0; mt < 2; ++mt) {
        const float* hb = &Hl[(mt * 16 + l15) * 34 + l4 * 8];
        const float2 g0 = *reinterpret_cast<const float2*>(hb + 0);
        const float2 g1 = *reinterpret_cast<const float2*>(hb + 2);
        const float2 g2 = *reinterpret_cast<const float2*>(hb + 4);
        const float2 g3 = *reinterpret_cast<const float2*>(hb + 6);
        A2[mt].u[0] = packrn(g0.x, g0.y);
        A2[mt].u[1] = packrn(g1.x, g1.y);
        A2[mt].u[2] = packrn(g2.x, g2.y);
        A2[mt].u[3] = packrn(g3.x, g3.y);
    }

#pragma unroll
    for (int nt = 0; nt < 8; ++nt) {
        Frag B4f;
        const uint4 q = *reinterpret_cast<const uint4*>(
            &PW4[(nt * 16 + l15) * 16 + l4 * 4]);
        B4f.u[0] = q.x; B4f.u[1] = q.y; B4f.u[2] = q.z; B4f.u[3] = q.w;
        const float b4v = b4[nt * 16 + l15];
        f32x4 tacc[2];
#pragma unroll
        for (int mt = 0; mt < 2; ++mt) {
            tacc[mt] = (f32x4){0.f, 0.f, 0.f, 0.f};
            tacc[mt] = __builtin_amdgcn_mfma_f32_16x16x32_bf16(
                A2[mt].v, B4f.v, tacc[mt], 0, 0, 0);
        }
#pragma unroll
        for (int mt = 0; mt < 2; ++mt)
#pragma unroll
            for (int r = 0; r < 4; ++r) {
                const int node = n0 + mt * 16 + l4 * 4 + r;
                if (node < N)
                    out[(size_t)node * FOUT + nt * 16 + l15] =
                        fmaxf(tacc[mt][r] + b4v, 0.0f);
            }
    }
}

// ===========================================================================
extern "C" void kernel_launch(void* const* d_in, const int* in_sizes, int n_in,
                              void* d_out, int out_size, void* d_ws, size_t ws_size,
                              hipStream_t stream)
{
    const float* x     = (const float*)d_in[0];
    const int*   ei    = (const int*)  d_in[1];
    const float* ea    = (const float*)d_in[2];
    const float* u     = (const float*)d_in[3];
    const int*   batch = (const int*)  d_in[4];
    const float* W1    = (const float*)d_in[5];
    const float* b1    = (const float*)d_in[6];
    const float* W2    = (const float*)d_in[7];
    const float* b2    = (const float*)d_in[8];
    const float* W3    = (const float*)d_in[9];
    const float* b3    = (const float*)d_in[10];
    const float* W4    = (const float*)d_in[11];
    const float* b4    = (const float*)d_in[12];
    float* out = (float*)d_out;

    const int N = in_sizes[0] / FN;   // 50000
    const int E = in_sizes[1] / 2;    // 800000
    const int G = in_sizes[3] / FN;   // 64
    const int NT = (E + 63) / 64;     // 64-edge tiles

    char* wp = (char*)d_ws;
    auto take = [&](size_t bytes) -> void* {
        void* r = (void*)wp;
        wp += (bytes + 255) & ~(size_t)255;
        return r;
    };
    float*    agg_sum  = (float*)   take((size_t)N * FMSG * 4);
    int*      agg_maxb = (int*)     take((size_t)N * FMSG * 4);
    char*     zero_end = wp;                       // agg zero span (in prep_rest)
    int*      cnt      = (int*)     take((size_t)N * 4);
    int*      offs     = (int*)     take(((size_t)N + 1) * 4);
    int*      rank     = (int*)     take((size_t)E * 4);
    int4*     re4      = (int4*)    take((size_t)E * 16);
    int2*     ntile    = (int2*)    take((size_t)NT * 8);
    float*    Pa       = (float*)   take((size_t)N * HIDN * 4);
    float*    Pb       = (float*)   take((size_t)N * HIDN * 4);
    float*    Qc       = (float*)   take((size_t)N * HIDN * 4);
    float*    Qu       = (float*)   take((size_t)G * HIDN * 4);
    uint32_t* PW1      = (uint32_t*)take(1024 * 4);
    uint32_t* PW2      = (uint32_t*)take(1024 * 4);
    uint32_t* PW3      = (uint32_t*)take(2048 * 4);
    uint32_t* PW4      = (uint32_t*)take(2048 * 4);
    int*      part     = (int*)     take(64 * 4);
    int*      partx    = (int*)     take(64 * 4);

    hipMemsetAsync(cnt, 0, (size_t)N * 4, stream);

    const int BH = (E / 4 + 255) / 256;            // hist blocks
    const int BP = (N + 255) / 256;                // node_pre blocks
    const int BZ = 256;                            // agg-zero blocks
    const int NB = (N + 2047) / 2048;              // scan blocks
    const int SB = (E + 255) / 256;                // scatter blocks
    const int TB = (NT + 255) / 256;               // ntile blocks
    const size_t zquads = (size_t)(zero_end - (char*)agg_sum) / 16;

    hist_kernel   <<<BH, 256, 0, stream>>>(ei, cnt, rank, E);
    prep_rest_kernel<<<BP + 1 + BZ, 256, 0, stream>>>(
        x, u, W1, b1, W2, W3, b3, W4,
        Pa, Pb, Qc, Qu, PW1, PW2, PW3, PW4,
        (uint4*)agg_sum, zquads, N, G, BP, BZ);
    scanA_kernel  <<<NB, 256, 0, stream>>>(cnt, part, N);
    scanB_kernel  <<<1, 64, 0, stream>>>(part, partx, offs, NB, N);
    scanC_kernel  <<<NB, 256, 0, stream>>>(cnt, partx, offs, N);
    scatter_ntile_kernel<<<SB + TB, 256, 0, stream>>>(
        ei, offs, rank, re4, ntile, E, N, NT, SB);
    fused_edge_mfma<<<(NT + 1) / 2, 128, 0, stream>>>(
        ea, PW1, PW2, b2, Pa, Pb, re4, offs, ntile, agg_sum, agg_maxb, N, E, NT);
    node_mfma     <<<(N + 127) / 128, 256, 0, stream>>>(
        Qc, Qu, batch, PW3, PW4, b4, agg_sum, agg_maxb, offs, out, N);
}